// Round 1
// baseline (5488.977 us; speedup 1.0000x reference)
//
#include <hip/hip_runtime.h>
#include <hip/hip_bf16.h>

#define D_MODEL 768
#define N_HEADS 12
#define D_HEAD  64
#define D_FF    3072
#define N_LAYERS 4
#define VOCAB   32000
#define BATCH   4
#define SEQ     1024
#define NROWS   (BATCH*SEQ)      // 4096
#define NEGV    -1000000000.0f
#define LN_EPS  1e-5f

// ---------- helpers ----------

__device__ __forceinline__ float block_reduce_sum(float v, float* sbuf) {
#pragma unroll
  for (int off = 32; off > 0; off >>= 1) v += __shfl_down(v, off, 64);
  int lane = threadIdx.x & 63, wid = threadIdx.x >> 6;
  if (lane == 0) sbuf[wid] = v;
  __syncthreads();
  if (threadIdx.x == 0) sbuf[4] = sbuf[0] + sbuf[1] + sbuf[2] + sbuf[3];
  __syncthreads();
  return sbuf[4];
}

__device__ __forceinline__ float gelu_f(float x) {
  float c = x + 0.044715f * x * x * x;
  return x * (0.5f * (1.0f + tanhf(0.7978845608f * c)));
}

// ---------- embedding + positional encoding ----------
// x[b,s,d] = embedding[d, tok] + PE(s,d). One block per token row.
__global__ __launch_bounds__(256) void embed_kernel(
    const int* __restrict__ tokens, const float* __restrict__ emb,
    float* __restrict__ x)
{
  int bs = blockIdx.x;
  int s = bs & (SEQ - 1);
  int tok = tokens[bs];
  for (int d = threadIdx.x; d < D_MODEL; d += 256) {
    float ev = emb[(size_t)d * VOCAB + tok];
    int dpair = d & ~1;
    float expo = (float)dpair * (1.0f / (float)D_MODEL);
    float ang = (float)s / powf(10000.0f, expo);
    float pe = (d & 1) ? cosf(ang) : sinf(ang);
    x[(size_t)bs * D_MODEL + d] = ev + pe;
  }
}

// ---------- layer norm over rows of 768 ----------
__global__ __launch_bounds__(256) void ln_kernel(
    const float* __restrict__ in, float* __restrict__ out,
    const float* __restrict__ g, const float* __restrict__ bb)
{
  __shared__ float sbuf[8];
  size_t row = blockIdx.x;
  const float* rp = in + row * D_MODEL;
  int t = threadIdx.x;
  float x0 = rp[t], x1 = rp[t + 256], x2 = rp[t + 512];
  float mean = block_reduce_sum(x0 + x1 + x2, sbuf) * (1.0f / (float)D_MODEL);
  float d0 = x0 - mean, d1 = x1 - mean, d2 = x2 - mean;
  float var = block_reduce_sum(d0*d0 + d1*d1 + d2*d2, sbuf) * (1.0f / (float)D_MODEL);
  float rstd = rsqrtf(var + LN_EPS);
  float* op = out + row * D_MODEL;
  op[t]       = g[t]       * (d0 * rstd) + bb[t];
  op[t + 256] = g[t + 256] * (d1 * rstd) + bb[t + 256];
  op[t + 512] = g[t + 512] * (d2 * rstd) + bb[t + 512];
}

// final LN on the selected rows x[b, predict_idx, :]
__global__ __launch_bounds__(256) void final_ln_kernel(
    const float* __restrict__ x, const int* __restrict__ pidx,
    const float* __restrict__ g, const float* __restrict__ bb,
    float* __restrict__ out)
{
  __shared__ float sbuf[8];
  int p = pidx[0];
  const float* rp = x + ((size_t)blockIdx.x * SEQ + p) * D_MODEL;
  int t = threadIdx.x;
  float x0 = rp[t], x1 = rp[t + 256], x2 = rp[t + 512];
  float mean = block_reduce_sum(x0 + x1 + x2, sbuf) * (1.0f / (float)D_MODEL);
  float d0 = x0 - mean, d1 = x1 - mean, d2 = x2 - mean;
  float var = block_reduce_sum(d0*d0 + d1*d1 + d2*d2, sbuf) * (1.0f / (float)D_MODEL);
  float rstd = rsqrtf(var + LN_EPS);
  float* op = out + (size_t)blockIdx.x * D_MODEL;
  op[t]       = g[t]       * (d0 * rstd) + bb[t];
  op[t + 256] = g[t + 256] * (d1 * rstd) + bb[t + 256];
  op[t + 512] = g[t + 512] * (d2 * rstd) + bb[t + 512];
}

// ---------- generic NT GEMM: C[m,n] = sum_k A[m,k] * W[n,k] ----------
// M fixed = 4096 via grid.y*64. BM=64, BN=128, BK=16, 256 threads, 4x8/thread.
// Optional residual add and GELU epilogue.
__global__ __launch_bounds__(256) void gemm_nt_kernel(
    const float* __restrict__ A, const float* __restrict__ W,
    float* __restrict__ C, const float* __restrict__ resid,
    int N, int K, int act)
{
  __shared__ __align__(16) float As[16][68];
  __shared__ __align__(16) float Bs[16][132];
  const int tid = threadIdx.x;
  const int bm = blockIdx.y * 64;
  const int bn = blockIdx.x * 128;
  const int tx = tid & 15, ty = tid >> 4;
  const int am = tid >> 2, ak = (tid & 3) << 2;
  const int wn = tid >> 1, wk = (tid & 1) << 3;
  const float* Ap = A + (size_t)(bm + am) * K + ak;
  const float* Wp = W + (size_t)(bn + wn) * K + wk;
  float acc[4][8];
#pragma unroll
  for (int i = 0; i < 4; ++i)
#pragma unroll
    for (int j = 0; j < 8; ++j) acc[i][j] = 0.f;

  for (int k0 = 0; k0 < K; k0 += 16) {
    float4 av = *(const float4*)(Ap + k0);
    float4 w0 = *(const float4*)(Wp + k0);
    float4 w1 = *(const float4*)(Wp + k0 + 4);
    __syncthreads();
    As[ak+0][am] = av.x; As[ak+1][am] = av.y; As[ak+2][am] = av.z; As[ak+3][am] = av.w;
    Bs[wk+0][wn] = w0.x; Bs[wk+1][wn] = w0.y; Bs[wk+2][wn] = w0.z; Bs[wk+3][wn] = w0.w;
    Bs[wk+4][wn] = w1.x; Bs[wk+5][wn] = w1.y; Bs[wk+6][wn] = w1.z; Bs[wk+7][wn] = w1.w;
    __syncthreads();
#pragma unroll
    for (int kk = 0; kk < 16; ++kk) {
      float4 a4 = *(const float4*)&As[kk][ty << 2];
      float4 b0 = *(const float4*)&Bs[kk][tx << 3];
      float4 b1 = *(const float4*)&Bs[kk][(tx << 3) + 4];
      float a[4] = {a4.x, a4.y, a4.z, a4.w};
      float b[8] = {b0.x, b0.y, b0.z, b0.w, b1.x, b1.y, b1.z, b1.w};
#pragma unroll
      for (int i = 0; i < 4; ++i)
#pragma unroll
        for (int j = 0; j < 8; ++j) acc[i][j] = fmaf(a[i], b[j], acc[i][j]);
    }
  }

#pragma unroll
  for (int i = 0; i < 4; ++i) {
    int row = bm + (ty << 2) + i;
    size_t off = (size_t)row * N + bn + (tx << 3);
    float r[8];
#pragma unroll
    for (int j = 0; j < 8; ++j) r[j] = acc[i][j];
    if (resid) {
      float4 q0 = *(const float4*)(resid + off);
      float4 q1 = *(const float4*)(resid + off + 4);
      r[0] += q0.x; r[1] += q0.y; r[2] += q0.z; r[3] += q0.w;
      r[4] += q1.x; r[5] += q1.y; r[6] += q1.z; r[7] += q1.w;
    }
    if (act) {
#pragma unroll
      for (int j = 0; j < 8; ++j) r[j] = gelu_f(r[j]);
    }
    float4 s0 = {r[0], r[1], r[2], r[3]};
    float4 s1 = {r[4], r[5], r[6], r[7]};
    *(float4*)(C + off) = s0;
    *(float4*)(C + off + 4) = s1;
  }
}

// ---------- attention scores (per batch): sc[h,s,t] = mask(scale * q.k) ----------
// grid (t_tile=16, s_tile=16, h=12), 64x64 tile, K=64.
__global__ __launch_bounds__(256) void attn_scores_kernel(
    const float* __restrict__ q, const float* __restrict__ k,
    float* __restrict__ sc, int b)
{
  const int h = blockIdx.z;
  const int s0 = blockIdx.y * 64;
  const int t0 = blockIdx.x * 64;
  const int tid = threadIdx.x;
  const int tx = tid & 15, ty = tid >> 4;

  if (t0 > s0 + 63) {           // fully masked tile
    float4 negv = {NEGV, NEGV, NEGV, NEGV};
#pragma unroll
    for (int i = 0; i < 4; ++i) {
      int s = s0 + (ty << 2) + i;
      *(float4*)(sc + ((size_t)h * SEQ + s) * SEQ + t0 + (tx << 2)) = negv;
    }
    return;
  }

  __shared__ __align__(16) float Qs[64][68];
  __shared__ __align__(16) float Ks[64][68];
  const int m = tid >> 2, eb = (tid & 3) << 4;
  const float* qp = q + ((size_t)(b * SEQ + s0 + m)) * D_MODEL + h * D_HEAD + eb;
  const float* kp = k + ((size_t)(b * SEQ + t0 + m)) * D_MODEL + h * D_HEAD + eb;
#pragma unroll
  for (int c = 0; c < 4; ++c) {
    float4 qv = *(const float4*)(qp + c * 4);
    float4 kv = *(const float4*)(kp + c * 4);
    Qs[eb + c*4 + 0][m] = qv.x; Qs[eb + c*4 + 1][m] = qv.y;
    Qs[eb + c*4 + 2][m] = qv.z; Qs[eb + c*4 + 3][m] = qv.w;
    Ks[eb + c*4 + 0][m] = kv.x; Ks[eb + c*4 + 1][m] = kv.y;
    Ks[eb + c*4 + 2][m] = kv.z; Ks[eb + c*4 + 3][m] = kv.w;
  }
  __syncthreads();

  float acc[4][4];
#pragma unroll
  for (int i = 0; i < 4; ++i)
#pragma unroll
    for (int j = 0; j < 4; ++j) acc[i][j] = 0.f;

#pragma unroll 8
  for (int kk = 0; kk < 64; ++kk) {
    float4 a4 = *(const float4*)&Qs[kk][ty << 2];
    float4 b4 = *(const float4*)&Ks[kk][tx << 2];
    float a[4] = {a4.x, a4.y, a4.z, a4.w};
    float bb[4] = {b4.x, b4.y, b4.z, b4.w};
#pragma unroll
    for (int i = 0; i < 4; ++i)
#pragma unroll
      for (int j = 0; j < 4; ++j) acc[i][j] = fmaf(a[i], bb[j], acc[i][j]);
  }

  const float scale = 0.125f;
#pragma unroll
  for (int i = 0; i < 4; ++i) {
    int s = s0 + (ty << 2) + i;
    int t = t0 + (tx << 2);
    float4 r;
    r.x = (t + 0 > s) ? NEGV : acc[i][0] * scale;
    r.y = (t + 1 > s) ? NEGV : acc[i][1] * scale;
    r.z = (t + 2 > s) ? NEGV : acc[i][2] * scale;
    r.w = (t + 3 > s) ? NEGV : acc[i][3] * scale;
    *(float4*)(sc + ((size_t)h * SEQ + s) * SEQ + t) = r;
  }
}

// ---------- row softmax over 1024 (in-place) ----------
__global__ __launch_bounds__(256) void softmax_kernel(float* __restrict__ sc)
{
  __shared__ float sbuf[8];
  size_t row = blockIdx.x;
  float4* rp = (float4*)(sc + row * SEQ);
  float4 v = rp[threadIdx.x];
  float m = fmaxf(fmaxf(v.x, v.y), fmaxf(v.z, v.w));
#pragma unroll
  for (int off = 32; off > 0; off >>= 1) m = fmaxf(m, __shfl_down(m, off, 64));
  int lane = threadIdx.x & 63, wid = threadIdx.x >> 6;
  if (lane == 0) sbuf[wid] = m;
  __syncthreads();
  if (threadIdx.x == 0) sbuf[4] = fmaxf(fmaxf(sbuf[0], sbuf[1]), fmaxf(sbuf[2], sbuf[3]));
  __syncthreads();
  float rowmax = sbuf[4];
  float e0 = expf(v.x - rowmax), e1 = expf(v.y - rowmax);
  float e2 = expf(v.z - rowmax), e3 = expf(v.w - rowmax);
  float total = block_reduce_sum(e0 + e1 + e2 + e3, sbuf);
  float inv = 1.0f / total;
  float4 o = {e0 * inv, e1 * inv, e2 * inv, e3 * inv};
  rp[threadIdx.x] = o;
}

// ---------- PV: out[b,s,h,e] = sum_t w[h,s,t] * v[b,t,h,e] ----------
// grid (s_tile=16, h=12). BM=64 (s), BN=64 (e), BK=16. Causal K truncation.
__global__ __launch_bounds__(256) void attn_v_kernel(
    const float* __restrict__ sc, const float* __restrict__ v,
    float* __restrict__ out, int b)
{
  const int h = blockIdx.y;
  const int s0 = blockIdx.x * 64;
  const int tid = threadIdx.x;
  const int tx = tid & 15, ty = tid >> 4;

  __shared__ __align__(16) float Ws[16][68];
  __shared__ __align__(16) float Vs[16][68];

  const int wm = tid >> 2, wkk = (tid & 3) << 2;
  const int vt = tid >> 4, ve = (tid & 15) << 2;
  const float* wp = sc + ((size_t)h * SEQ + s0 + wm) * SEQ + wkk;
  const float* vp = v + ((size_t)(b * SEQ + vt)) * D_MODEL + h * D_HEAD + ve;

  float acc[4][4];
#pragma unroll
  for (int i = 0; i < 4; ++i)
#pragma unroll
    for (int j = 0; j < 4; ++j) acc[i][j] = 0.f;

  for (int k0 = 0; k0 < s0 + 64; k0 += 16) {
    float4 wv = *(const float4*)(wp + k0);
    float4 vv = *(const float4*)(vp + (size_t)k0 * D_MODEL);
    __syncthreads();
    Ws[wkk+0][wm] = wv.x; Ws[wkk+1][wm] = wv.y; Ws[wkk+2][wm] = wv.z; Ws[wkk+3][wm] = wv.w;
    *(float4*)&Vs[vt][ve] = vv;
    __syncthreads();
#pragma unroll
    for (int kk = 0; kk < 16; ++kk) {
      float4 a4 = *(const float4*)&Ws[kk][ty << 2];
      float4 b4 = *(const float4*)&Vs[kk][tx << 2];
      float a[4] = {a4.x, a4.y, a4.z, a4.w};
      float bb[4] = {b4.x, b4.y, b4.z, b4.w};
#pragma unroll
      for (int i = 0; i < 4; ++i)
#pragma unroll
        for (int j = 0; j < 4; ++j) acc[i][j] = fmaf(a[i], bb[j], acc[i][j]);
    }
  }

#pragma unroll
  for (int i = 0; i < 4; ++i) {
    int s = s0 + (ty << 2) + i;
    float4 r = {acc[i][0], acc[i][1], acc[i][2], acc[i][3]};
    *(float4*)(out + ((size_t)(b * SEQ + s)) * D_MODEL + h * D_HEAD + (tx << 2)) = r;
  }
}

// ---------- logits: out[b, v] = dot(normed[b,:], unembed[v,:]) ----------
// grid = 125 blocks of 256 threads; each thread does one vocab entry for all 4 b.
__global__ __launch_bounds__(256) void logits_kernel(
    const float* __restrict__ normed, const float* __restrict__ unemb,
    float* __restrict__ out)
{
  __shared__ __align__(16) float ns[BATCH][D_MODEL];
  for (int d = threadIdx.x; d < BATCH * D_MODEL; d += 256)
    ((float*)ns)[d] = normed[d];
  __syncthreads();
  int vout = blockIdx.x * 256 + threadIdx.x;
  const float4* up = (const float4*)(unemb + (size_t)vout * D_MODEL);
  float s0 = 0.f, s1 = 0.f, s2 = 0.f, s3 = 0.f;
#pragma unroll 4
  for (int i = 0; i < D_MODEL / 4; ++i) {
    float4 u = up[i];
    float4 n0 = *(const float4*)&ns[0][i * 4];
    float4 n1 = *(const float4*)&ns[1][i * 4];
    float4 n2 = *(const float4*)&ns[2][i * 4];
    float4 n3 = *(const float4*)&ns[3][i * 4];
    s0 += u.x*n0.x + u.y*n0.y + u.z*n0.z + u.w*n0.w;
    s1 += u.x*n1.x + u.y*n1.y + u.z*n1.z + u.w*n1.w;
    s2 += u.x*n2.x + u.y*n2.y + u.z*n2.z + u.w*n2.w;
    s3 += u.x*n3.x + u.y*n3.y + u.z*n3.z + u.w*n3.w;
  }
  out[(size_t)0 * VOCAB + vout] = s0;
  out[(size_t)1 * VOCAB + vout] = s1;
  out[(size_t)2 * VOCAB + vout] = s2;
  out[(size_t)3 * VOCAB + vout] = s3;
}

// ---------- launcher ----------
extern "C" void kernel_launch(void* const* d_in, const int* in_sizes, int n_in,
                              void* d_out, int out_size, void* d_ws, size_t ws_size,
                              hipStream_t stream) {
  const int*   tokens = (const int*)d_in[0];
  const int*   pidx   = (const int*)d_in[1];
  const float* emb    = (const float*)d_in[2];
  const float* ln1_g  = (const float*)d_in[3];
  const float* ln1_b  = (const float*)d_in[4];
  const float* wq     = (const float*)d_in[5];
  const float* wk     = (const float*)d_in[6];
  const float* wv     = (const float*)d_in[7];
  const float* wo     = (const float*)d_in[8];
  const float* ln2_g  = (const float*)d_in[9];
  const float* ln2_b  = (const float*)d_in[10];
  const float* fc1    = (const float*)d_in[11];
  const float* fc2    = (const float*)d_in[12];
  const float* lnf_g  = (const float*)d_in[13];
  const float* lnf_b  = (const float*)d_in[14];
  const float* unemb  = (const float*)d_in[15];
  float* out = (float*)d_out;
  float* ws  = (float*)d_ws;

  const size_t NX = (size_t)NROWS * D_MODEL;            // 3,145,728 floats
  const size_t NSC = (size_t)N_HEADS * SEQ * SEQ;       // 12,582,912 floats
  float* x    = ws;
  float* hbuf = ws + NX;
  float* attn = ws + 2 * NX;
  float* big  = ws + 3 * NX;
  float* qb = big;
  float* kb = big + NX;
  float* vb = big + 2 * NX;
  float* scb = big + 3 * NX;       // per-batch scores, reused
  float* ffn = big;                // reused after attention (needs 12.58M floats)
  float* normed = big + 3 * NX + NSC;

  embed_kernel<<<NROWS, 256, 0, stream>>>(tokens, emb, x);

  for (int l = 0; l < N_LAYERS; ++l) {
    const size_t wofs  = (size_t)l * D_MODEL * D_MODEL;     // 589824
    const size_t fofs  = (size_t)l * D_FF * D_MODEL;        // 2359296

    ln_kernel<<<NROWS, 256, 0, stream>>>(x, hbuf, ln1_g + l * D_MODEL, ln1_b + l * D_MODEL);

    gemm_nt_kernel<<<dim3(D_MODEL/128, NROWS/64), 256, 0, stream>>>(
        hbuf, wq + wofs, qb, nullptr, D_MODEL, D_MODEL, 0);
    gemm_nt_kernel<<<dim3(D_MODEL/128, NROWS/64), 256, 0, stream>>>(
        hbuf, wk + wofs, kb, nullptr, D_MODEL, D_MODEL, 0);
    gemm_nt_kernel<<<dim3(D_MODEL/128, NROWS/64), 256, 0, stream>>>(
        hbuf, wv + wofs, vb, nullptr, D_MODEL, D_MODEL, 0);

    for (int b = 0; b < BATCH; ++b) {
      attn_scores_kernel<<<dim3(SEQ/64, SEQ/64, N_HEADS), 256, 0, stream>>>(qb, kb, scb, b);
      softmax_kernel<<<N_HEADS * SEQ, 256, 0, stream>>>(scb);
      attn_v_kernel<<<dim3(SEQ/64, N_HEADS), 256, 0, stream>>>(scb, vb, attn, b);
    }

    gemm_nt_kernel<<<dim3(D_MODEL/128, NROWS/64), 256, 0, stream>>>(
        attn, wo + wofs, x, x, D_MODEL, D_MODEL, 0);

    ln_kernel<<<NROWS, 256, 0, stream>>>(x, hbuf, ln2_g + l * D_MODEL, ln2_b + l * D_MODEL);

    gemm_nt_kernel<<<dim3(D_FF/128, NROWS/64), 256, 0, stream>>>(
        hbuf, fc1 + fofs, ffn, nullptr, D_FF, D_MODEL, 1 /*gelu*/);
    gemm_nt_kernel<<<dim3(D_MODEL/128, NROWS/64), 256, 0, stream>>>(
        ffn, fc2 + fofs, x, x, D_MODEL, D_FF, 0);
  }

  final_ln_kernel<<<BATCH, 256, 0, stream>>>(x, pidx, lnf_g, lnf_b, normed);
  logits_kernel<<<VOCAB/256, 256, 0, stream>>>(normed, unemb, out);
}

// Round 2
// 1747.759 us; speedup vs baseline: 3.1406x; 3.1406x over previous
//
#include <hip/hip_runtime.h>
#include <hip/hip_bf16.h>

#define D_MODEL 768
#define N_HEADS 12
#define D_HEAD  64
#define D_FF    3072
#define N_LAYERS 4
#define VOCAB   32000
#define BATCH   4
#define SEQ     1024
#define NROWS   (BATCH*SEQ)      // 4096
#define NEGV    -1000000000.0f
#define LN_EPS  1e-5f

typedef __attribute__((ext_vector_type(8))) short bf16x8;
typedef __attribute__((ext_vector_type(4))) float f32x4;
typedef __attribute__((ext_vector_type(8))) unsigned short u16x8;

typedef __attribute__((address_space(1))) const unsigned int g_u32;
typedef __attribute__((address_space(3))) unsigned int l_u32;

__device__ __forceinline__ float bf2f(unsigned short u) {
  return __uint_as_float(((unsigned int)u) << 16);
}

__device__ __forceinline__ float block_reduce_sum(float v, float* sbuf) {
#pragma unroll
  for (int off = 32; off > 0; off >>= 1) v += __shfl_down(v, off, 64);
  int lane = threadIdx.x & 63, wid = threadIdx.x >> 6;
  if (lane == 0) sbuf[wid] = v;
  __syncthreads();
  if (threadIdx.x == 0) sbuf[4] = sbuf[0] + sbuf[1] + sbuf[2] + sbuf[3];
  __syncthreads();
  return sbuf[4];
}

__device__ __forceinline__ float gelu_f(float x) {
  float c = x + 0.044715f * x * x * x;
  return x * (0.5f * (1.0f + tanhf(0.7978845608f * c)));
}

// ---------- fp32 -> bf16 weight conversion (8 elems / thread) ----------
__global__ __launch_bounds__(256) void convert_kernel(
    const float* __restrict__ src, __hip_bfloat16* __restrict__ dst, int n)
{
  int i = (blockIdx.x * 256 + threadIdx.x) * 8;
  if (i >= n) return;
  float4 a = *(const float4*)(src + i);
  float4 b = *(const float4*)(src + i + 4);
  struct bf8 { __hip_bfloat16 h[8]; } r;
  r.h[0] = __float2bfloat16(a.x); r.h[1] = __float2bfloat16(a.y);
  r.h[2] = __float2bfloat16(a.z); r.h[3] = __float2bfloat16(a.w);
  r.h[4] = __float2bfloat16(b.x); r.h[5] = __float2bfloat16(b.y);
  r.h[6] = __float2bfloat16(b.z); r.h[7] = __float2bfloat16(b.w);
  *(bf8*)(dst + i) = r;
}

// ---------- embedding + positional encoding ----------
__global__ __launch_bounds__(256) void embed_kernel(
    const int* __restrict__ tokens, const float* __restrict__ emb,
    float* __restrict__ x)
{
  int bs = blockIdx.x;
  int s = bs & (SEQ - 1);
  int tok = tokens[bs];
  for (int d = threadIdx.x; d < D_MODEL; d += 256) {
    float ev = emb[(size_t)d * VOCAB + tok];
    int dpair = d & ~1;
    float expo = (float)dpair * (1.0f / (float)D_MODEL);
    float ang = (float)s / powf(10000.0f, expo);
    float pe = (d & 1) ? cosf(ang) : sinf(ang);
    x[(size_t)bs * D_MODEL + d] = ev + pe;
  }
}

// ---------- layer norm (fp32 in, bf16 out) ----------
__global__ __launch_bounds__(256) void ln_kernel(
    const float* __restrict__ in, __hip_bfloat16* __restrict__ out,
    const float* __restrict__ g, const float* __restrict__ bb)
{
  __shared__ float sbuf[8];
  size_t row = blockIdx.x;
  const float* rp = in + row * D_MODEL;
  int t = threadIdx.x;
  float x0 = rp[t], x1 = rp[t + 256], x2 = rp[t + 512];
  float mean = block_reduce_sum(x0 + x1 + x2, sbuf) * (1.0f / (float)D_MODEL);
  float d0 = x0 - mean, d1 = x1 - mean, d2 = x2 - mean;
  float var = block_reduce_sum(d0*d0 + d1*d1 + d2*d2, sbuf) * (1.0f / (float)D_MODEL);
  float rstd = rsqrtf(var + LN_EPS);
  __hip_bfloat16* op = out + row * D_MODEL;
  op[t]       = __float2bfloat16(g[t]       * (d0 * rstd) + bb[t]);
  op[t + 256] = __float2bfloat16(g[t + 256] * (d1 * rstd) + bb[t + 256]);
  op[t + 512] = __float2bfloat16(g[t + 512] * (d2 * rstd) + bb[t + 512]);
}

// final LN on x[b, predict_idx, :] (fp32 out)
__global__ __launch_bounds__(256) void final_ln_kernel(
    const float* __restrict__ x, const int* __restrict__ pidx,
    const float* __restrict__ g, const float* __restrict__ bb,
    float* __restrict__ out)
{
  __shared__ float sbuf[8];
  int p = pidx[0];
  const float* rp = x + ((size_t)blockIdx.x * SEQ + p) * D_MODEL;
  int t = threadIdx.x;
  float x0 = rp[t], x1 = rp[t + 256], x2 = rp[t + 512];
  float mean = block_reduce_sum(x0 + x1 + x2, sbuf) * (1.0f / (float)D_MODEL);
  float d0 = x0 - mean, d1 = x1 - mean, d2 = x2 - mean;
  float var = block_reduce_sum(d0*d0 + d1*d1 + d2*d2, sbuf) * (1.0f / (float)D_MODEL);
  float rstd = rsqrtf(var + LN_EPS);
  float* op = out + (size_t)blockIdx.x * D_MODEL;
  op[t]       = g[t]       * (d0 * rstd) + bb[t];
  op[t + 256] = g[t + 256] * (d1 * rstd) + bb[t + 256];
  op[t + 512] = g[t + 512] * (d2 * rstd) + bb[t + 512];
}

// ---------- bf16 MFMA NT GEMM: C[m,n] = sum_k A[m,k] * W[n,k] ----------
// 128x128 tile, BK=32, 256 threads (4 waves, 2x2 wave grid, 64x64 each),
// global_load_lds width-16 staging, mfma_f32_16x16x32_bf16, fp32 accum.
// mode: 0 = fp32 out, 1 = fp32 + resid, 2 = bf16 out, 3 = bf16 + gelu
__global__ __launch_bounds__(256) void gemm_bf16_kernel(
    const __hip_bfloat16* __restrict__ A, const __hip_bfloat16* __restrict__ W,
    void* __restrict__ Cv, const float* __restrict__ resid,
    int N, int K, int mode)
{
  __shared__ __hip_bfloat16 As[128 * 32];   // 8 KB, linear [row][k]
  __shared__ __hip_bfloat16 Bs[128 * 32];   // 8 KB
  const int tid = threadIdx.x;
  const int wv = tid >> 6, ln = tid & 63;
  const int l15 = ln & 15, l4 = ln >> 4;
  const int bm = blockIdx.y * 128, bn = blockIdx.x * 128;
  const int wr = wv >> 1, wc = wv & 1;      // wave tile origin (wr*64, wc*64)

  f32x4 acc[4][4];
#pragma unroll
  for (int m = 0; m < 4; ++m)
#pragma unroll
    for (int n = 0; n < 4; ++n) acc[m][n] = (f32x4){0.f, 0.f, 0.f, 0.f};

  for (int k0 = 0; k0 < K; k0 += 32) {
    __syncthreads();  // all waves done reading LDS from previous step
#pragma unroll
    for (int r = 0; r < 2; ++r) {
      int slot = r * 256 + tid;                 // 0..511
      int row = slot >> 2, col = (slot & 3) * 8;
      const __hip_bfloat16* ga = A + (size_t)(bm + row) * K + k0 + col;
      const __hip_bfloat16* gb = W + (size_t)(bn + row) * K + k0 + col;
      // wave-uniform LDS base; HW adds lane*16 bytes
      __hip_bfloat16* la = As + (size_t)(r * 256 + wv * 64) * 8;
      __hip_bfloat16* lb = Bs + (size_t)(r * 256 + wv * 64) * 8;
      __builtin_amdgcn_global_load_lds((g_u32*)ga, (l_u32*)la, 16, 0, 0);
      __builtin_amdgcn_global_load_lds((g_u32*)gb, (l_u32*)lb, 16, 0, 0);
    }
    __syncthreads();  // barrier drains vmcnt -> LDS tiles ready

    bf16x8 af[4], bfr[4];
#pragma unroll
    for (int m = 0; m < 4; ++m)
      af[m] = *(const bf16x8*)(As + (size_t)(wr * 64 + m * 16 + l15) * 32 + l4 * 8);
#pragma unroll
    for (int n = 0; n < 4; ++n)
      bfr[n] = *(const bf16x8*)(Bs + (size_t)(wc * 64 + n * 16 + l15) * 32 + l4 * 8);
#pragma unroll
    for (int m = 0; m < 4; ++m)
#pragma unroll
      for (int n = 0; n < 4; ++n)
        acc[m][n] = __builtin_amdgcn_mfma_f32_16x16x32_bf16(af[m], bfr[n], acc[m][n], 0, 0, 0);
  }

  // epilogue: C/D layout col = lane&15, row = (lane>>4)*4 + reg
  float* Cf = (float*)Cv;
  __hip_bfloat16* Cb = (__hip_bfloat16*)Cv;
#pragma unroll
  for (int m = 0; m < 4; ++m) {
#pragma unroll
    for (int n = 0; n < 4; ++n) {
#pragma unroll
      for (int r = 0; r < 4; ++r) {
        int row = bm + wr * 64 + m * 16 + l4 * 4 + r;
        int col = bn + wc * 64 + n * 16 + l15;
        size_t off = (size_t)row * N + col;
        float v = acc[m][n][r];
        if (mode == 0)      Cf[off] = v;
        else if (mode == 1) Cf[off] = v + resid[off];
        else if (mode == 2) Cb[off] = __float2bfloat16(v);
        else                Cb[off] = __float2bfloat16(gelu_f(v));
      }
    }
  }
}

// ---------- flash attention (fp32 compute, bf16 in/out) ----------
// qkv [4096][2304] bf16 (q|k|v each 768 = h*64+e). out attn [4096][768] bf16.
// grid (s_tile=16, h=12, b=4); 64 q-rows per block; online softmax.
__global__ __launch_bounds__(256) void flash_attn_kernel(
    const __hip_bfloat16* __restrict__ qkv, __hip_bfloat16* __restrict__ attn)
{
  const int s0 = blockIdx.x * 64;
  const int h  = blockIdx.y;
  const int b  = blockIdx.z;
  const int tid = threadIdx.x;
  const int tx = tid & 15, ty = tid >> 4;

  __shared__ float Qs[64][68];    // transposed: Qs[e][s]
  __shared__ float KPs[64][68];   // K phase: KPs[e][t]; P phase: KPs[t][s]
  __shared__ float Vs[64][68];    // Vs[t][e]

  // load Q tile (transposed): thread -> row m, 16 elems starting at ec
  {
    int m = tid >> 2, ec = (tid & 3) * 16;
    const u16x8* qp = (const u16x8*)(qkv + (size_t)(b * SEQ + s0 + m) * 2304 + h * D_HEAD + ec);
    u16x8 q0 = qp[0], q1 = qp[1];
#pragma unroll
    for (int j = 0; j < 8; ++j) {
      Qs[ec + j][m]     = bf2f(q0[j]);
      Qs[ec + 8 + j][m] = bf2f(q1[j]);
    }
  }

  float mrow[4], lrow[4], o[4][4];
#pragma unroll
  for (int i = 0; i < 4; ++i) {
    mrow[i] = -1e30f; lrow[i] = 0.f;
#pragma unroll
    for (int j = 0; j < 4; ++j) o[i][j] = 0.f;
  }

  for (int t0 = 0; t0 <= s0; t0 += 64) {
    __syncthreads();  // previous PV reads done
    // load K (transposed) and V tiles
    {
      int m = tid >> 2, ec = (tid & 3) * 16;
      const u16x8* kp = (const u16x8*)(qkv + (size_t)(b * SEQ + t0 + m) * 2304 + 768 + h * D_HEAD + ec);
      const u16x8* vp = (const u16x8*)(qkv + (size_t)(b * SEQ + t0 + m) * 2304 + 1536 + h * D_HEAD + ec);
      u16x8 k0v = kp[0], k1v = kp[1];
      u16x8 v0v = vp[0], v1v = vp[1];
#pragma unroll
      for (int j = 0; j < 8; ++j) {
        KPs[ec + j][m]     = bf2f(k0v[j]);
        KPs[ec + 8 + j][m] = bf2f(k1v[j]);
        Vs[m][ec + j]      = bf2f(v0v[j]);
        Vs[m][ec + 8 + j]  = bf2f(v1v[j]);
      }
    }
    __syncthreads();

    // S = scale * Q K^T  (64x64 tile, 4x4 per thread)
    float s[4][4];
#pragma unroll
    for (int i = 0; i < 4; ++i)
#pragma unroll
      for (int j = 0; j < 4; ++j) s[i][j] = 0.f;
#pragma unroll 8
    for (int kk = 0; kk < 64; ++kk) {
      float4 a4 = *(const float4*)&Qs[kk][ty << 2];
      float4 b4 = *(const float4*)&KPs[kk][tx << 2];
      float a[4] = {a4.x, a4.y, a4.z, a4.w};
      float bv[4] = {b4.x, b4.y, b4.z, b4.w};
#pragma unroll
      for (int i = 0; i < 4; ++i)
#pragma unroll
        for (int j = 0; j < 4; ++j) s[i][j] = fmaf(a[i], bv[j], s[i][j]);
    }
    const float scale = 0.125f;
    bool diag = (t0 == s0);
#pragma unroll
    for (int i = 0; i < 4; ++i)
#pragma unroll
      for (int j = 0; j < 4; ++j) {
        s[i][j] *= scale;
        if (diag && (tx * 4 + j > ty * 4 + i)) s[i][j] = NEGV;
      }

    // online softmax (row groups = 16 consecutive lanes)
    float p[4][4];
#pragma unroll
    for (int i = 0; i < 4; ++i) {
      float rmax = fmaxf(fmaxf(s[i][0], s[i][1]), fmaxf(s[i][2], s[i][3]));
#pragma unroll
      for (int msk = 1; msk < 16; msk <<= 1) rmax = fmaxf(rmax, __shfl_xor(rmax, msk, 64));
      float mnew = fmaxf(mrow[i], rmax);
      float alpha = __expf(mrow[i] - mnew);
      float rsum = 0.f;
#pragma unroll
      for (int j = 0; j < 4; ++j) { p[i][j] = __expf(s[i][j] - mnew); rsum += p[i][j]; }
#pragma unroll
      for (int msk = 1; msk < 16; msk <<= 1) rsum += __shfl_xor(rsum, msk, 64);
      lrow[i] = lrow[i] * alpha + rsum;
#pragma unroll
      for (int j = 0; j < 4; ++j) o[i][j] *= alpha;
      mrow[i] = mnew;
    }

    __syncthreads();  // all S reads of KPs done -> safe to overwrite with P
#pragma unroll
    for (int i = 0; i < 4; ++i)
#pragma unroll
      for (int j = 0; j < 4; ++j) KPs[tx * 4 + j][ty * 4 + i] = p[i][j];
    __syncthreads();

    // O += P V
#pragma unroll 8
    for (int t = 0; t < 64; ++t) {
      float4 pv = *(const float4*)&KPs[t][ty << 2];
      float4 vv = *(const float4*)&Vs[t][tx << 2];
      float pa[4] = {pv.x, pv.y, pv.z, pv.w};
      float vb[4] = {vv.x, vv.y, vv.z, vv.w};
#pragma unroll
      for (int i = 0; i < 4; ++i)
#pragma unroll
        for (int j = 0; j < 4; ++j) o[i][j] = fmaf(pa[i], vb[j], o[i][j]);
    }
  }

  // write out: attn[b*S + s0 + ty*4+i][h*64 + tx*4+j] = o/l
#pragma unroll
  for (int i = 0; i < 4; ++i) {
    float inv = 1.0f / lrow[i];
    size_t base = (size_t)(b * SEQ + s0 + ty * 4 + i) * D_MODEL + h * D_HEAD + tx * 4;
#pragma unroll
    for (int j = 0; j < 4; ++j) attn[base + j] = __float2bfloat16(o[i][j] * inv);
  }
}

// ---------- logits: out[b,v] = dot(normed[b,:], unembed[v,:]) ----------
// 16 threads cooperate per vocab row (coalesced float4 reads); 16 rows/block.
__global__ __launch_bounds__(256) void logits_kernel(
    const float* __restrict__ normed, const float* __restrict__ unemb,
    float* __restrict__ out)
{
  __shared__ __align__(16) float ns[BATCH][D_MODEL];
  for (int d = threadIdx.x; d < BATCH * D_MODEL; d += 256)
    ((float*)ns)[d] = normed[d];
  __syncthreads();
  int g = threadIdx.x >> 4, li = threadIdx.x & 15;
  int v = blockIdx.x * 16 + g;
  const float* up = unemb + (size_t)v * D_MODEL;
  float s0 = 0.f, s1 = 0.f, s2 = 0.f, s3 = 0.f;
#pragma unroll
  for (int it = 0; it < D_MODEL / 64; ++it) {
    int e = it * 64 + li * 4;
    float4 u = *(const float4*)(up + e);
    float4 n0 = *(const float4*)&ns[0][e];
    float4 n1 = *(const float4*)&ns[1][e];
    float4 n2 = *(const float4*)&ns[2][e];
    float4 n3 = *(const float4*)&ns[3][e];
    s0 += u.x*n0.x + u.y*n0.y + u.z*n0.z + u.w*n0.w;
    s1 += u.x*n1.x + u.y*n1.y + u.z*n1.z + u.w*n1.w;
    s2 += u.x*n2.x + u.y*n2.y + u.z*n2.z + u.w*n2.w;
    s3 += u.x*n3.x + u.y*n3.y + u.z*n3.z + u.w*n3.w;
  }
#pragma unroll
  for (int msk = 1; msk < 16; msk <<= 1) {
    s0 += __shfl_xor(s0, msk, 64); s1 += __shfl_xor(s1, msk, 64);
    s2 += __shfl_xor(s2, msk, 64); s3 += __shfl_xor(s3, msk, 64);
  }
  if (li == 0) {
    out[(size_t)0 * VOCAB + v] = s0;
    out[(size_t)1 * VOCAB + v] = s1;
    out[(size_t)2 * VOCAB + v] = s2;
    out[(size_t)3 * VOCAB + v] = s3;
  }
}

// ---------- launcher ----------
extern "C" void kernel_launch(void* const* d_in, const int* in_sizes, int n_in,
                              void* d_out, int out_size, void* d_ws, size_t ws_size,
                              hipStream_t stream) {
  const int*   tokens = (const int*)d_in[0];
  const int*   pidx   = (const int*)d_in[1];
  const float* emb    = (const float*)d_in[2];
  const float* ln1_g  = (const float*)d_in[3];
  const float* ln1_b  = (const float*)d_in[4];
  const float* wq     = (const float*)d_in[5];
  const float* wk     = (const float*)d_in[6];
  const float* wv     = (const float*)d_in[7];
  const float* wo     = (const float*)d_in[8];
  const float* ln2_g  = (const float*)d_in[9];
  const float* ln2_b  = (const float*)d_in[10];
  const float* fc1    = (const float*)d_in[11];
  const float* fc2    = (const float*)d_in[12];
  const float* lnf_g  = (const float*)d_in[13];
  const float* lnf_b  = (const float*)d_in[14];
  const float* unemb  = (const float*)d_in[15];
  float* out = (float*)d_out;

  char* wp = (char*)d_ws;
  const size_t NX = (size_t)NROWS * D_MODEL;        // 3,145,728
  float* x = (float*)wp;                  wp += NX * 4;                      // 12.58 MB
  float* normed = (float*)wp;             wp += BATCH * D_MODEL * 4;
  __hip_bfloat16* h    = (__hip_bfloat16*)wp; wp += NX * 2;                  // 6.29 MB
  __hip_bfloat16* attn = (__hip_bfloat16*)wp; wp += NX * 2;                  // 6.29 MB
  __hip_bfloat16* qkvb = (__hip_bfloat16*)wp; wp += (size_t)NROWS * 2304 * 2; // 18.87 MB
  __hip_bfloat16* ffn  = (__hip_bfloat16*)wp; wp += (size_t)NROWS * D_FF * 2; // 25.17 MB
  __hip_bfloat16* wqkvb = (__hip_bfloat16*)wp; wp += (size_t)N_LAYERS * 2304 * D_MODEL * 2; // 14.16 MB
  __hip_bfloat16* wob   = (__hip_bfloat16*)wp; wp += (size_t)N_LAYERS * D_MODEL * D_MODEL * 2;
  __hip_bfloat16* fc1b  = (__hip_bfloat16*)wp; wp += (size_t)N_LAYERS * D_FF * D_MODEL * 2;
  __hip_bfloat16* fc2b  = (__hip_bfloat16*)wp; wp += (size_t)N_LAYERS * D_MODEL * D_FF * 2;

  const int WMAT = D_MODEL * D_MODEL;     // 589824
  const int FMAT = D_FF * D_MODEL;        // 2359296

  // weight conversion (packed QKV per layer: rows [q(768) | k(768) | v(768)])
  for (int l = 0; l < N_LAYERS; ++l) {
    convert_kernel<<<WMAT / 2048, 256, 0, stream>>>(wq + (size_t)l * WMAT, wqkvb + (size_t)l * 3 * WMAT,            WMAT);
    convert_kernel<<<WMAT / 2048, 256, 0, stream>>>(wk + (size_t)l * WMAT, wqkvb + (size_t)l * 3 * WMAT + WMAT,     WMAT);
    convert_kernel<<<WMAT / 2048, 256, 0, stream>>>(wv + (size_t)l * WMAT, wqkvb + (size_t)l * 3 * WMAT + 2 * WMAT, WMAT);
  }
  convert_kernel<<<N_LAYERS * WMAT / 2048, 256, 0, stream>>>(wo,  wob,  N_LAYERS * WMAT);
  convert_kernel<<<N_LAYERS * FMAT / 2048, 256, 0, stream>>>(fc1, fc1b, N_LAYERS * FMAT);
  convert_kernel<<<N_LAYERS * FMAT / 2048, 256, 0, stream>>>(fc2, fc2b, N_LAYERS * FMAT);

  embed_kernel<<<NROWS, 256, 0, stream>>>(tokens, emb, x);

  for (int l = 0; l < N_LAYERS; ++l) {
    const size_t qofs = (size_t)l * 3 * WMAT;
    const size_t wofs = (size_t)l * WMAT;
    const size_t fofs = (size_t)l * FMAT;

    ln_kernel<<<NROWS, 256, 0, stream>>>(x, h, ln1_g + l * D_MODEL, ln1_b + l * D_MODEL);

    // fused QKV: [4096 x 2304] bf16 out
    gemm_bf16_kernel<<<dim3(2304 / 128, NROWS / 128), 256, 0, stream>>>(
        h, wqkvb + qofs, qkvb, nullptr, 2304, D_MODEL, 2);

    flash_attn_kernel<<<dim3(SEQ / 64, N_HEADS, BATCH), 256, 0, stream>>>(qkvb, attn);

    // x += attn @ wo^T
    gemm_bf16_kernel<<<dim3(D_MODEL / 128, NROWS / 128), 256, 0, stream>>>(
        attn, wob + wofs, x, x, D_MODEL, D_MODEL, 1);

    ln_kernel<<<NROWS, 256, 0, stream>>>(x, h, ln2_g + l * D_MODEL, ln2_b + l * D_MODEL);

    // ffn = gelu(h @ fc1^T) (bf16)
    gemm_bf16_kernel<<<dim3(D_FF / 128, NROWS / 128), 256, 0, stream>>>(
        h, fc1b + fofs, ffn, nullptr, D_FF, D_MODEL, 3);

    // x += ffn @ fc2^T
    gemm_bf16_kernel<<<dim3(D_MODEL / 128, NROWS / 128), 256, 0, stream>>>(
        ffn, fc2b + fofs, x, x, D_MODEL, D_FF, 1);
  }

  final_ln_kernel<<<BATCH, 256, 0, stream>>>(x, pidx, lnf_g, lnf_b, normed);
  logits_kernel<<<VOCAB / 16, 256, 0, stream>>>(normed, unemb, out);
}

// Round 3
// 1227.345 us; speedup vs baseline: 4.4722x; 1.4240x over previous
//
#include <hip/hip_runtime.h>
#include <hip/hip_bf16.h>

#define D_MODEL 768
#define N_HEADS 12
#define D_HEAD  64
#define D_FF    3072
#define N_LAYERS 4
#define VOCAB   32000
#define BATCH   4
#define SEQ     1024
#define NROWS   (BATCH*SEQ)      // 4096
#define NEGV    -1000000000.0f
#define LN_EPS  1e-5f

typedef __attribute__((ext_vector_type(8))) short bf16x8;
typedef __attribute__((ext_vector_type(4))) float f32x4;
typedef __attribute__((ext_vector_type(8))) unsigned short u16x8;

typedef __attribute__((address_space(1))) const unsigned int g_u32;
typedef __attribute__((address_space(3))) unsigned int l_u32;

__device__ __forceinline__ float bf2f(unsigned short u) {
  return __uint_as_float(((unsigned int)u) << 16);
}
__device__ __forceinline__ unsigned short f2bf(float f) {
  __hip_bfloat16 h = __float2bfloat16(f);
  return *reinterpret_cast<unsigned short*>(&h);
}

__device__ __forceinline__ float block_reduce_sum(float v, float* sbuf) {
#pragma unroll
  for (int off = 32; off > 0; off >>= 1) v += __shfl_down(v, off, 64);
  int lane = threadIdx.x & 63, wid = threadIdx.x >> 6;
  if (lane == 0) sbuf[wid] = v;
  __syncthreads();
  if (threadIdx.x == 0) sbuf[4] = sbuf[0] + sbuf[1] + sbuf[2] + sbuf[3];
  __syncthreads();
  return sbuf[4];
}

__device__ __forceinline__ float gelu_f(float x) {
  float c = x + 0.044715f * x * x * x;
  return x * (0.5f * (1.0f + tanhf(0.7978845608f * c)));
}

// ---------- fp32 -> bf16 weight conversion (8 elems / thread) ----------
__global__ __launch_bounds__(256) void convert_kernel(
    const float* __restrict__ src, __hip_bfloat16* __restrict__ dst, int n)
{
  int i = (blockIdx.x * 256 + threadIdx.x) * 8;
  if (i >= n) return;
  float4 a = *(const float4*)(src + i);
  float4 b = *(const float4*)(src + i + 4);
  struct bf8 { __hip_bfloat16 h[8]; } r;
  r.h[0] = __float2bfloat16(a.x); r.h[1] = __float2bfloat16(a.y);
  r.h[2] = __float2bfloat16(a.z); r.h[3] = __float2bfloat16(a.w);
  r.h[4] = __float2bfloat16(b.x); r.h[5] = __float2bfloat16(b.y);
  r.h[6] = __float2bfloat16(b.z); r.h[7] = __float2bfloat16(b.w);
  *(bf8*)(dst + i) = r;
}

// ---------- embedding + positional encoding ----------
__global__ __launch_bounds__(256) void embed_kernel(
    const int* __restrict__ tokens, const float* __restrict__ emb,
    float* __restrict__ x)
{
  int bs = blockIdx.x;
  int s = bs & (SEQ - 1);
  int tok = tokens[bs];
  for (int d = threadIdx.x; d < D_MODEL; d += 256) {
    float ev = emb[(size_t)d * VOCAB + tok];
    int dpair = d & ~1;
    float expo = (float)dpair * (1.0f / (float)D_MODEL);
    float ang = (float)s / powf(10000.0f, expo);
    float pe = (d & 1) ? cosf(ang) : sinf(ang);
    x[(size_t)bs * D_MODEL + d] = ev + pe;
  }
}

// ---------- layer norm (fp32 in, bf16 out) ----------
__global__ __launch_bounds__(256) void ln_kernel(
    const float* __restrict__ in, __hip_bfloat16* __restrict__ out,
    const float* __restrict__ g, const float* __restrict__ bb)
{
  __shared__ float sbuf[8];
  size_t row = blockIdx.x;
  const float* rp = in + row * D_MODEL;
  int t = threadIdx.x;
  float x0 = rp[t], x1 = rp[t + 256], x2 = rp[t + 512];
  float mean = block_reduce_sum(x0 + x1 + x2, sbuf) * (1.0f / (float)D_MODEL);
  float d0 = x0 - mean, d1 = x1 - mean, d2 = x2 - mean;
  float var = block_reduce_sum(d0*d0 + d1*d1 + d2*d2, sbuf) * (1.0f / (float)D_MODEL);
  float rstd = rsqrtf(var + LN_EPS);
  __hip_bfloat16* op = out + row * D_MODEL;
  op[t]       = __float2bfloat16(g[t]       * (d0 * rstd) + bb[t]);
  op[t + 256] = __float2bfloat16(g[t + 256] * (d1 * rstd) + bb[t + 256]);
  op[t + 512] = __float2bfloat16(g[t + 512] * (d2 * rstd) + bb[t + 512]);
}

// final LN on x[b, predict_idx, :] (fp32 out)
__global__ __launch_bounds__(256) void final_ln_kernel(
    const float* __restrict__ x, const int* __restrict__ pidx,
    const float* __restrict__ g, const float* __restrict__ bb,
    float* __restrict__ out)
{
  __shared__ float sbuf[8];
  int p = pidx[0];
  const float* rp = x + ((size_t)blockIdx.x * SEQ + p) * D_MODEL;
  int t = threadIdx.x;
  float x0 = rp[t], x1 = rp[t + 256], x2 = rp[t + 512];
  float mean = block_reduce_sum(x0 + x1 + x2, sbuf) * (1.0f / (float)D_MODEL);
  float d0 = x0 - mean, d1 = x1 - mean, d2 = x2 - mean;
  float var = block_reduce_sum(d0*d0 + d1*d1 + d2*d2, sbuf) * (1.0f / (float)D_MODEL);
  float rstd = rsqrtf(var + LN_EPS);
  float* op = out + (size_t)blockIdx.x * D_MODEL;
  op[t]       = g[t]       * (d0 * rstd) + bb[t];
  op[t + 256] = g[t + 256] * (d1 * rstd) + bb[t + 256];
  op[t + 512] = g[t + 512] * (d2 * rstd) + bb[t + 512];
}

// ---------- bf16 MFMA NT GEMM: C[m,n] = sum_k A[m,k] * W[n,k] ----------
// 128x128 tile, BK=32, 256 threads (4 waves, 2x2 wave grid, 64x64 each),
// global_load_lds width-16 staging, mfma_f32_16x16x32_bf16, fp32 accum.
// mode: 0 = fp32 out, 1 = fp32 + resid, 2 = bf16 out, 3 = bf16 + gelu
__global__ __launch_bounds__(256) void gemm_bf16_kernel(
    const __hip_bfloat16* __restrict__ A, const __hip_bfloat16* __restrict__ W,
    void* __restrict__ Cv, const float* __restrict__ resid,
    int N, int K, int mode)
{
  __shared__ __hip_bfloat16 As[128 * 32];   // 8 KB, linear [row][k]
  __shared__ __hip_bfloat16 Bs[128 * 32];   // 8 KB
  const int tid = threadIdx.x;
  const int wv = tid >> 6, ln = tid & 63;
  const int l15 = ln & 15, l4 = ln >> 4;
  const int bm = blockIdx.y * 128, bn = blockIdx.x * 128;
  const int wr = wv >> 1, wc = wv & 1;      // wave tile origin (wr*64, wc*64)

  f32x4 acc[4][4];
#pragma unroll
  for (int m = 0; m < 4; ++m)
#pragma unroll
    for (int n = 0; n < 4; ++n) acc[m][n] = (f32x4){0.f, 0.f, 0.f, 0.f};

  for (int k0 = 0; k0 < K; k0 += 32) {
    __syncthreads();  // all waves done reading LDS from previous step
#pragma unroll
    for (int r = 0; r < 2; ++r) {
      int slot = r * 256 + tid;                 // 0..511
      int row = slot >> 2, col = (slot & 3) * 8;
      const __hip_bfloat16* ga = A + (size_t)(bm + row) * K + k0 + col;
      const __hip_bfloat16* gb = W + (size_t)(bn + row) * K + k0 + col;
      // wave-uniform LDS base; HW adds lane*16 bytes
      __hip_bfloat16* la = As + (size_t)(r * 256 + wv * 64) * 8;
      __hip_bfloat16* lb = Bs + (size_t)(r * 256 + wv * 64) * 8;
      __builtin_amdgcn_global_load_lds((g_u32*)ga, (l_u32*)la, 16, 0, 0);
      __builtin_amdgcn_global_load_lds((g_u32*)gb, (l_u32*)lb, 16, 0, 0);
    }
    __syncthreads();  // barrier drains vmcnt -> LDS tiles ready

    bf16x8 af[4], bfr[4];
#pragma unroll
    for (int m = 0; m < 4; ++m)
      af[m] = *(const bf16x8*)(As + (size_t)(wr * 64 + m * 16 + l15) * 32 + l4 * 8);
#pragma unroll
    for (int n = 0; n < 4; ++n)
      bfr[n] = *(const bf16x8*)(Bs + (size_t)(wc * 64 + n * 16 + l15) * 32 + l4 * 8);
#pragma unroll
    for (int m = 0; m < 4; ++m)
#pragma unroll
      for (int n = 0; n < 4; ++n)
        acc[m][n] = __builtin_amdgcn_mfma_f32_16x16x32_bf16(af[m], bfr[n], acc[m][n], 0, 0, 0);
  }

  // epilogue: C/D layout col = lane&15, row = (lane>>4)*4 + reg
  float* Cf = (float*)Cv;
  __hip_bfloat16* Cb = (__hip_bfloat16*)Cv;
#pragma unroll
  for (int m = 0; m < 4; ++m) {
#pragma unroll
    for (int n = 0; n < 4; ++n) {
#pragma unroll
      for (int r = 0; r < 4; ++r) {
        int row = bm + wr * 64 + m * 16 + l4 * 4 + r;
        int col = bn + wc * 64 + n * 16 + l15;
        size_t off = (size_t)row * N + col;
        float v = acc[m][n][r];
        if (mode == 0)      Cf[off] = v;
        else if (mode == 1) Cf[off] = v + resid[off];
        else if (mode == 2) Cb[off] = __float2bfloat16(v);
        else                Cb[off] = __float2bfloat16(gelu_f(v));
      }
    }
  }
}

// ---------- MFMA flash attention (bf16 MFMA, fp32 softmax/accum) ----------
// qkv [4096][2304] bf16 (q|k|v, each 768 = h*64+e). out attn [4096][768] bf16.
// Block: 64 q-rows (4 waves x 16), KV tiles of 64. grid (16, 12, 4).
// K: global_load_lds into XOR-swizzled LDS (pre-swizzled global source).
// V: reg-staged, transposed+swizzled. P: per-wave swizzled LDS buffer.
// Swizzle: element (row, c) at elem-offset row*64 + ((c/8)^(row&7))*8 + c%8.
__global__ __launch_bounds__(256) void flash_attn_kernel(
    const __hip_bfloat16* __restrict__ qkv_, __hip_bfloat16* __restrict__ attn_)
{
  const unsigned short* qkv = (const unsigned short*)qkv_;
  unsigned short* attn = (unsigned short*)attn_;
  const int s0 = blockIdx.x * 64;
  const int h  = blockIdx.y;
  const int b  = blockIdx.z;
  const int tid = threadIdx.x;
  const int wq = tid >> 6, ln = tid & 63;
  const int l15 = ln & 15, l4 = ln >> 4;

  __shared__ unsigned short Ks[64 * 64];      // 8 KB
  __shared__ unsigned short Vt[64 * 64];      // 8 KB (transposed: [e][t])
  __shared__ unsigned short Pw[4][16 * 64];   // 8 KB (per-wave P)

  // Q fragments in registers, pre-scaled by 1/sqrt(64)=0.125 (exact in bf16)
  bf16x8 qf[2];
  {
    const size_t qbase = (size_t)(b * SEQ + s0 + wq * 16 + l15) * 2304 + h * 64;
#pragma unroll
    for (int ks = 0; ks < 2; ++ks) {
      u16x8 raw = *(const u16x8*)(qkv + qbase + ks * 32 + l4 * 8);
      bf16x8 q;
#pragma unroll
      for (int j = 0; j < 8; ++j) q[j] = (short)f2bf(bf2f(raw[j]) * 0.125f);
      qf[ks] = q;
    }
  }

  float mrow[4], lrow[4];
  f32x4 o[4];
#pragma unroll
  for (int r = 0; r < 4; ++r) { mrow[r] = -1e30f; lrow[r] = 0.f; }
#pragma unroll
  for (int n = 0; n < 4; ++n) o[n] = (f32x4){0.f, 0.f, 0.f, 0.f};

  for (int t0 = 0; t0 <= s0; t0 += 64) {
    __syncthreads();  // all waves done reading Ks/Vt of previous tile

    // ---- K tile -> LDS, swizzled via pre-swizzled global source ----
    // LDS slot (t, blk) holds K element block (t, blk ^ (t&7)). Lane ln of
    // chunk o128 writes LDS offset o128*1024 + ln*16 => t = o128*8 + ln/8,
    // blk = ln&7 => source d-block = (ln&7) ^ (ln>>3).
#pragma unroll
    for (int r = 0; r < 2; ++r) {
      int o128 = wq * 2 + r;
      int t = o128 * 8 + (ln >> 3);
      int db = (ln & 7) ^ (ln >> 3);
      const unsigned short* gk =
          qkv + (size_t)(b * SEQ + t0 + t) * 2304 + 768 + h * 64 + db * 8;
      __builtin_amdgcn_global_load_lds((g_u32*)gk, (l_u32*)(Ks + o128 * 512), 16, 0, 0);
    }

    // ---- V tile -> regs -> LDS transposed + swizzled: Vt[e][t] ----
    {
      int vt = tid >> 2, ec = (tid & 3) * 16;
      const unsigned short* gv =
          qkv + (size_t)(b * SEQ + t0 + vt) * 2304 + 1536 + h * 64 + ec;
      u16x8 v0 = *(const u16x8*)gv;
      u16x8 v1 = *(const u16x8*)(gv + 8);
      int tb = vt >> 3, tr = vt & 7;
#pragma unroll
      for (int j = 0; j < 8; ++j) {
        int e0 = ec + j, e1 = ec + 8 + j;
        Vt[e0 * 64 + ((tb ^ (e0 & 7)) << 3) + tr] = (unsigned short)v0[j];
        Vt[e1 * 64 + ((tb ^ (e1 & 7)) << 3) + tr] = (unsigned short)v1[j];
      }
    }
    __syncthreads();  // drains vmcnt (K) + lgkmcnt (Vt writes)

    // ---- S = Q K^T ----
    f32x4 sf[4];
#pragma unroll
    for (int n = 0; n < 4; ++n) sf[n] = (f32x4){0.f, 0.f, 0.f, 0.f};
#pragma unroll
    for (int ks = 0; ks < 2; ++ks) {
#pragma unroll
      for (int n = 0; n < 4; ++n) {
        int t = n * 16 + l15;
        bf16x8 kf = *(const bf16x8*)(Ks + t * 64 + (((ks * 4 + l4) ^ (t & 7)) << 3));
        sf[n] = __builtin_amdgcn_mfma_f32_16x16x32_bf16(qf[ks], kf, sf[n], 0, 0, 0);
      }
    }

    // causal mask on diagonal tile: t_local > q_local (wave covers q wq*16+..)
    if (t0 == s0) {
#pragma unroll
      for (int n = 0; n < 4; ++n) {
        int t = n * 16 + l15;
#pragma unroll
        for (int r = 0; r < 4; ++r) {
          int q = wq * 16 + l4 * 4 + r;
          if (t > q) sf[n][r] = NEGV;
        }
      }
    }

    // ---- online softmax (rows = l4*4+r, cols across 16 lanes x 4 frags) ----
    float pbuf[4][4];
#pragma unroll
    for (int r = 0; r < 4; ++r) {
      float rmax = fmaxf(fmaxf(sf[0][r], sf[1][r]), fmaxf(sf[2][r], sf[3][r]));
#pragma unroll
      for (int m = 1; m < 16; m <<= 1) rmax = fmaxf(rmax, __shfl_xor(rmax, m, 64));
      float mnew = fmaxf(mrow[r], rmax);
      float alpha = __expf(mrow[r] - mnew);
      float part = 0.f;
#pragma unroll
      for (int n = 0; n < 4; ++n) {
        float p = __expf(sf[n][r] - mnew);
        pbuf[n][r] = p;
        part += p;
      }
#pragma unroll
      for (int m = 1; m < 16; m <<= 1) part += __shfl_xor(part, m, 64);
      lrow[r] = lrow[r] * alpha + part;
      mrow[r] = mnew;
#pragma unroll
      for (int n = 0; n < 4; ++n) o[n][r] *= alpha;
    }

    // ---- P -> per-wave LDS (A-operand layout, swizzled) ----
    unsigned short* Pme = Pw[wq];
#pragma unroll
    for (int n = 0; n < 4; ++n) {
      int tb = (n * 16 + l15) >> 3, tr = l15 & 7;
#pragma unroll
      for (int r = 0; r < 4; ++r) {
        int q = l4 * 4 + r;
        Pme[q * 64 + ((tb ^ (q & 7)) << 3) + tr] = f2bf(pbuf[n][r]);
      }
    }
    // in-wave ds_write -> ds_read dependency: compiler inserts lgkmcnt waits

    // ---- O += P V ----
#pragma unroll
    for (int ks = 0; ks < 2; ++ks) {
      bf16x8 pf = *(const bf16x8*)(Pme + l15 * 64 + (((ks * 4 + l4) ^ (l15 & 7)) << 3));
#pragma unroll
      for (int n = 0; n < 4; ++n) {
        int e = n * 16 + l15;
        bf16x8 vf = *(const bf16x8*)(Vt + e * 64 + (((ks * 4 + l4) ^ (e & 7)) << 3));
        o[n] = __builtin_amdgcn_mfma_f32_16x16x32_bf16(pf, vf, o[n], 0, 0, 0);
      }
    }
  }

  // ---- write O / l ----
#pragma unroll
  for (int r = 0; r < 4; ++r) {
    float inv = 1.0f / lrow[r];
    size_t base = (size_t)(b * SEQ + s0 + wq * 16 + l4 * 4 + r) * D_MODEL + h * 64;
#pragma unroll
    for (int n = 0; n < 4; ++n)
      attn[base + n * 16 + l15] = f2bf(o[n][r] * inv);
  }
}

// ---------- logits: out[b,v] = dot(normed[b,:], unembed[v,:]) ----------
__global__ __launch_bounds__(256) void logits_kernel(
    const float* __restrict__ normed, const float* __restrict__ unemb,
    float* __restrict__ out)
{
  __shared__ __align__(16) float ns[BATCH][D_MODEL];
  for (int d = threadIdx.x; d < BATCH * D_MODEL; d += 256)
    ((float*)ns)[d] = normed[d];
  __syncthreads();
  int g = threadIdx.x >> 4, li = threadIdx.x & 15;
  int v = blockIdx.x * 16 + g;
  const float* up = unemb + (size_t)v * D_MODEL;
  float s0 = 0.f, s1 = 0.f, s2 = 0.f, s3 = 0.f;
#pragma unroll
  for (int it = 0; it < D_MODEL / 64; ++it) {
    int e = it * 64 + li * 4;
    float4 u = *(const float4*)(up + e);
    float4 n0 = *(const float4*)&ns[0][e];
    float4 n1 = *(const float4*)&ns[1][e];
    float4 n2 = *(const float4*)&ns[2][e];
    float4 n3 = *(const float4*)&ns[3][e];
    s0 += u.x*n0.x + u.y*n0.y + u.z*n0.z + u.w*n0.w;
    s1 += u.x*n1.x + u.y*n1.y + u.z*n1.z + u.w*n1.w;
    s2 += u.x*n2.x + u.y*n2.y + u.z*n2.z + u.w*n2.w;
    s3 += u.x*n3.x + u.y*n3.y + u.z*n3.z + u.w*n3.w;
  }
#pragma unroll
  for (int msk = 1; msk < 16; msk <<= 1) {
    s0 += __shfl_xor(s0, msk, 64); s1 += __shfl_xor(s1, msk, 64);
    s2 += __shfl_xor(s2, msk, 64); s3 += __shfl_xor(s3, msk, 64);
  }
  if (li == 0) {
    out[(size_t)0 * VOCAB + v] = s0;
    out[(size_t)1 * VOCAB + v] = s1;
    out[(size_t)2 * VOCAB + v] = s2;
    out[(size_t)3 * VOCAB + v] = s3;
  }
}

// ---------- launcher ----------
extern "C" void kernel_launch(void* const* d_in, const int* in_sizes, int n_in,
                              void* d_out, int out_size, void* d_ws, size_t ws_size,
                              hipStream_t stream) {
  const int*   tokens = (const int*)d_in[0];
  const int*   pidx   = (const int*)d_in[1];
  const float* emb    = (const float*)d_in[2];
  const float* ln1_g  = (const float*)d_in[3];
  const float* ln1_b  = (const float*)d_in[4];
  const float* wq     = (const float*)d_in[5];
  const float* wk     = (const float*)d_in[6];
  const float* wv     = (const float*)d_in[7];
  const float* wo     = (const float*)d_in[8];
  const float* ln2_g  = (const float*)d_in[9];
  const float* ln2_b  = (const float*)d_in[10];
  const float* fc1    = (const float*)d_in[11];
  const float* fc2    = (const float*)d_in[12];
  const float* lnf_g  = (const float*)d_in[13];
  const float* lnf_b  = (const float*)d_in[14];
  const float* unemb  = (const float*)d_in[15];
  float* out = (float*)d_out;

  char* wp = (char*)d_ws;
  const size_t NX = (size_t)NROWS * D_MODEL;        // 3,145,728
  float* x = (float*)wp;                  wp += NX * 4;                      // 12.58 MB
  float* normed = (float*)wp;             wp += BATCH * D_MODEL * 4;
  __hip_bfloat16* h    = (__hip_bfloat16*)wp; wp += NX * 2;                  // 6.29 MB
  __hip_bfloat16* attn = (__hip_bfloat16*)wp; wp += NX * 2;                  // 6.29 MB
  __hip_bfloat16* qkvb = (__hip_bfloat16*)wp; wp += (size_t)NROWS * 2304 * 2; // 18.87 MB
  __hip_bfloat16* ffn  = (__hip_bfloat16*)wp; wp += (size_t)NROWS * D_FF * 2; // 25.17 MB
  __hip_bfloat16* wqkvb = (__hip_bfloat16*)wp; wp += (size_t)N_LAYERS * 2304 * D_MODEL * 2; // 14.16 MB
  __hip_bfloat16* wob   = (__hip_bfloat16*)wp; wp += (size_t)N_LAYERS * D_MODEL * D_MODEL * 2;
  __hip_bfloat16* fc1b  = (__hip_bfloat16*)wp; wp += (size_t)N_LAYERS * D_FF * D_MODEL * 2;
  __hip_bfloat16* fc2b  = (__hip_bfloat16*)wp; wp += (size_t)N_LAYERS * D_MODEL * D_FF * 2;

  const int WMAT = D_MODEL * D_MODEL;     // 589824
  const int FMAT = D_FF * D_MODEL;        // 2359296

  // weight conversion (packed QKV per layer: rows [q(768) | k(768) | v(768)])
  for (int l = 0; l < N_LAYERS; ++l) {
    convert_kernel<<<WMAT / 2048, 256, 0, stream>>>(wq + (size_t)l * WMAT, wqkvb + (size_t)l * 3 * WMAT,            WMAT);
    convert_kernel<<<WMAT / 2048, 256, 0, stream>>>(wk + (size_t)l * WMAT, wqkvb + (size_t)l * 3 * WMAT + WMAT,     WMAT);
    convert_kernel<<<WMAT / 2048, 256, 0, stream>>>(wv + (size_t)l * WMAT, wqkvb + (size_t)l * 3 * WMAT + 2 * WMAT, WMAT);
  }
  convert_kernel<<<N_LAYERS * WMAT / 2048, 256, 0, stream>>>(wo,  wob,  N_LAYERS * WMAT);
  convert_kernel<<<N_LAYERS * FMAT / 2048, 256, 0, stream>>>(fc1, fc1b, N_LAYERS * FMAT);
  convert_kernel<<<N_LAYERS * FMAT / 2048, 256, 0, stream>>>(fc2, fc2b, N_LAYERS * FMAT);

  embed_kernel<<<NROWS, 256, 0, stream>>>(tokens, emb, x);

  for (int l = 0; l < N_LAYERS; ++l) {
    const size_t qofs = (size_t)l * 3 * WMAT;
    const size_t wofs = (size_t)l * WMAT;
    const size_t fofs = (size_t)l * FMAT;

    ln_kernel<<<NROWS, 256, 0, stream>>>(x, h, ln1_g + l * D_MODEL, ln1_b + l * D_MODEL);

    // fused QKV: [4096 x 2304] bf16 out
    gemm_bf16_kernel<<<dim3(2304 / 128, NROWS / 128), 256, 0, stream>>>(
        h, wqkvb + qofs, qkvb, nullptr, 2304, D_MODEL, 2);

    flash_attn_kernel<<<dim3(SEQ / 64, N_HEADS, BATCH), 256, 0, stream>>>(qkvb, attn);

    // x += attn @ wo^T
    gemm_bf16_kernel<<<dim3(D_MODEL / 128, NROWS / 128), 256, 0, stream>>>(
        attn, wob + wofs, x, x, D_MODEL, D_MODEL, 1);

    ln_kernel<<<NROWS, 256, 0, stream>>>(x, h, ln2_g + l * D_MODEL, ln2_b + l * D_MODEL);

    // ffn = gelu(h @ fc1^T) (bf16)
    gemm_bf16_kernel<<<dim3(D_FF / 128, NROWS / 128), 256, 0, stream>>>(
        h, fc1b + fofs, ffn, nullptr, D_FF, D_MODEL, 3);

    // x += ffn @ fc2^T
    gemm_bf16_kernel<<<dim3(D_MODEL / 128, NROWS / 128), 256, 0, stream>>>(
        ffn, fc2b + fofs, x, x, D_MODEL, D_FF, 1);
  }

  final_ln_kernel<<<BATCH, 256, 0, stream>>>(x, pidx, lnf_g, lnf_b, normed);
  logits_kernel<<<VOCAB / 16, 256, 0, stream>>>(normed, unemb, out);
}

// Round 4
// 996.068 us; speedup vs baseline: 5.5106x; 1.2322x over previous
//
#include <hip/hip_runtime.h>
#include <hip/hip_bf16.h>

#define D_MODEL 768
#define N_HEADS 12
#define D_HEAD  64
#define D_FF    3072
#define N_LAYERS 4
#define VOCAB   32000
#define BATCH   4
#define SEQ     1024
#define NROWS   (BATCH*SEQ)      // 4096
#define NEGV    -1000000000.0f
#define LN_EPS  1e-5f

typedef __attribute__((ext_vector_type(8))) short bf16x8;
typedef __attribute__((ext_vector_type(4))) float f32x4;
typedef __attribute__((ext_vector_type(8))) unsigned short u16x8;

typedef __attribute__((address_space(1))) const unsigned int g_u32;
typedef __attribute__((address_space(3))) unsigned int l_u32;

__device__ __forceinline__ float bf2f(unsigned short u) {
  return __uint_as_float(((unsigned int)u) << 16);
}
__device__ __forceinline__ unsigned short f2bf(float f) {
  __hip_bfloat16 h = __float2bfloat16(f);
  return *reinterpret_cast<unsigned short*>(&h);
}

__device__ __forceinline__ float block_reduce_sum(float v, float* sbuf) {
#pragma unroll
  for (int off = 32; off > 0; off >>= 1) v += __shfl_down(v, off, 64);
  int lane = threadIdx.x & 63, wid = threadIdx.x >> 6;
  if (lane == 0) sbuf[wid] = v;
  __syncthreads();
  if (threadIdx.x == 0) sbuf[4] = sbuf[0] + sbuf[1] + sbuf[2] + sbuf[3];
  __syncthreads();
  return sbuf[4];
}

__device__ __forceinline__ float gelu_f(float x) {
  float c = x + 0.044715f * x * x * x;
  return x * (0.5f * (1.0f + tanhf(0.7978845608f * c)));
}

// ---------- fp32 -> bf16 weight conversion (8 elems / thread) ----------
__global__ __launch_bounds__(256) void convert_kernel(
    const float* __restrict__ src, __hip_bfloat16* __restrict__ dst, int n)
{
  int i = (blockIdx.x * 256 + threadIdx.x) * 8;
  if (i >= n) return;
  float4 a = *(const float4*)(src + i);
  float4 b = *(const float4*)(src + i + 4);
  struct bf8 { __hip_bfloat16 h[8]; } r;
  r.h[0] = __float2bfloat16(a.x); r.h[1] = __float2bfloat16(a.y);
  r.h[2] = __float2bfloat16(a.z); r.h[3] = __float2bfloat16(a.w);
  r.h[4] = __float2bfloat16(b.x); r.h[5] = __float2bfloat16(b.y);
  r.h[6] = __float2bfloat16(b.z); r.h[7] = __float2bfloat16(b.w);
  *(bf8*)(dst + i) = r;
}

// pack wq|wk|wv of all layers into wqkvb [l][3*WMAT] in one launch
__global__ __launch_bounds__(256) void qkv_pack_kernel(
    const float* __restrict__ wq, const float* __restrict__ wk,
    const float* __restrict__ wv, __hip_bfloat16* __restrict__ dst)
{
  const int WMAT = D_MODEL * D_MODEL;
  long long i = (long long)(blockIdx.x * 256 + threadIdx.x) * 8;
  long long l = i / (3LL * WMAT);
  long long rem = i - l * 3LL * WMAT;
  int which = (int)(rem / WMAT);
  long long off = rem - (long long)which * WMAT;
  const float* src = (which == 0 ? wq : which == 1 ? wk : wv) + l * WMAT + off;
  float4 a = *(const float4*)src;
  float4 b = *(const float4*)(src + 4);
  struct bf8 { __hip_bfloat16 h[8]; } r;
  r.h[0] = __float2bfloat16(a.x); r.h[1] = __float2bfloat16(a.y);
  r.h[2] = __float2bfloat16(a.z); r.h[3] = __float2bfloat16(a.w);
  r.h[4] = __float2bfloat16(b.x); r.h[5] = __float2bfloat16(b.y);
  r.h[6] = __float2bfloat16(b.z); r.h[7] = __float2bfloat16(b.w);
  *(bf8*)(dst + i) = r;
}

// ---------- embedding + positional encoding ----------
__global__ __launch_bounds__(256) void embed_kernel(
    const int* __restrict__ tokens, const float* __restrict__ emb,
    float* __restrict__ x)
{
  int bs = blockIdx.x;
  int s = bs & (SEQ - 1);
  int tok = tokens[bs];
  for (int d = threadIdx.x; d < D_MODEL; d += 256) {
    float ev = emb[(size_t)d * VOCAB + tok];
    int dpair = d & ~1;
    float expo = (float)dpair * (1.0f / (float)D_MODEL);
    float ang = (float)s / powf(10000.0f, expo);
    float pe = (d & 1) ? cosf(ang) : sinf(ang);
    x[(size_t)bs * D_MODEL + d] = ev + pe;
  }
}

// ---------- layer norm (fp32 in, bf16 out) ----------
__global__ __launch_bounds__(256) void ln_kernel(
    const float* __restrict__ in, __hip_bfloat16* __restrict__ out,
    const float* __restrict__ g, const float* __restrict__ bb)
{
  __shared__ float sbuf[8];
  size_t row = blockIdx.x;
  const float* rp = in + row * D_MODEL;
  int t = threadIdx.x;
  float x0 = rp[t], x1 = rp[t + 256], x2 = rp[t + 512];
  float mean = block_reduce_sum(x0 + x1 + x2, sbuf) * (1.0f / (float)D_MODEL);
  float d0 = x0 - mean, d1 = x1 - mean, d2 = x2 - mean;
  float var = block_reduce_sum(d0*d0 + d1*d1 + d2*d2, sbuf) * (1.0f / (float)D_MODEL);
  float rstd = rsqrtf(var + LN_EPS);
  __hip_bfloat16* op = out + row * D_MODEL;
  op[t]       = __float2bfloat16(g[t]       * (d0 * rstd) + bb[t]);
  op[t + 256] = __float2bfloat16(g[t + 256] * (d1 * rstd) + bb[t + 256]);
  op[t + 512] = __float2bfloat16(g[t + 512] * (d2 * rstd) + bb[t + 512]);
}

// final LN on x[b, predict_idx, :] (fp32 out)
__global__ __launch_bounds__(256) void final_ln_kernel(
    const float* __restrict__ x, const int* __restrict__ pidx,
    const float* __restrict__ g, const float* __restrict__ bb,
    float* __restrict__ out)
{
  __shared__ float sbuf[8];
  int p = pidx[0];
  const float* rp = x + ((size_t)blockIdx.x * SEQ + p) * D_MODEL;
  int t = threadIdx.x;
  float x0 = rp[t], x1 = rp[t + 256], x2 = rp[t + 512];
  float mean = block_reduce_sum(x0 + x1 + x2, sbuf) * (1.0f / (float)D_MODEL);
  float d0 = x0 - mean, d1 = x1 - mean, d2 = x2 - mean;
  float var = block_reduce_sum(d0*d0 + d1*d1 + d2*d2, sbuf) * (1.0f / (float)D_MODEL);
  float rstd = rsqrtf(var + LN_EPS);
  float* op = out + (size_t)blockIdx.x * D_MODEL;
  op[t]       = g[t]       * (d0 * rstd) + bb[t];
  op[t + 256] = g[t + 256] * (d1 * rstd) + bb[t + 256];
  op[t + 512] = g[t + 512] * (d2 * rstd) + bb[t + 512];
}

// XCD-chunked bijective block swizzle (nwg % 8 == 0 for all our grids):
// contiguous logical tiles land on one XCD -> A row-panels fetched once/XCD.
__device__ __forceinline__ int2 xcd_tile(int gx, int gy) {
  int flat = blockIdx.y * gx + blockIdx.x;
  int cpx = (gx * gy) >> 3;
  int logical = (flat & 7) * cpx + (flat >> 3);
  return make_int2(logical % gx, logical / gx);   // (col, row)
}

// ---------- bf16 MFMA NT GEMM: C[m,n] = sum_k A[m,k] * W[n,k] ----------
// 128x128 tile, BK=64, 256 threads (2x2 waves of 64x64), XOR-swizzled LDS
// (chunk c of row r at c^(r&7); staged via pre-swizzled global source),
// global_load_lds width-16, mfma_f32_16x16x32_bf16, fp32 accum.
// mode: 0 = fp32 out, 1 = fp32 + resid, 2 = bf16 out, 3 = bf16 + gelu
__global__ __launch_bounds__(256) void gemm_bf16_kernel(
    const __hip_bfloat16* __restrict__ A, const __hip_bfloat16* __restrict__ W,
    void* __restrict__ Cv, const float* __restrict__ resid,
    int N, int K, int mode)
{
  __shared__ __align__(16) unsigned short As[128 * 64];   // 16 KB
  __shared__ __align__(16) unsigned short Bs[128 * 64];   // 16 KB
  const unsigned short* Au = (const unsigned short*)A;
  const unsigned short* Wu = (const unsigned short*)W;
  const int tid = threadIdx.x;
  const int wv = tid >> 6, ln = tid & 63;
  const int l15 = ln & 15, l4 = ln >> 4;
  int2 tc = xcd_tile(N >> 7, gridDim.y);
  const int bm = tc.y * 128, bn = tc.x * 128;
  const int wr = wv >> 1, wc = wv & 1;

  // staging geometry: slot s = r*256+tid -> row s/8 (= r*32 + wv*8 + ln/8),
  // LDS chunk ln&7; source chunk = (ln&7) ^ (ln>>3)  [row&7 == ln>>3]
  const int srow = wv * 8 + (ln >> 3);
  const int scg  = (ln & 7) ^ (ln >> 3);

  f32x4 acc[4][4];
#pragma unroll
  for (int m = 0; m < 4; ++m)
#pragma unroll
    for (int n = 0; n < 4; ++n) acc[m][n] = (f32x4){0.f, 0.f, 0.f, 0.f};

  for (int k0 = 0; k0 < K; k0 += 64) {
    __syncthreads();
#pragma unroll
    for (int r = 0; r < 4; ++r) {
      int row = r * 32 + srow;
      const unsigned short* ga = Au + (size_t)(bm + row) * K + k0 + scg * 8;
      const unsigned short* gb = Wu + (size_t)(bn + row) * K + k0 + scg * 8;
      unsigned short* la = As + (size_t)(r * 256 + wv * 64) * 8;
      unsigned short* lb = Bs + (size_t)(r * 256 + wv * 64) * 8;
      __builtin_amdgcn_global_load_lds((g_u32*)ga, (l_u32*)la, 16, 0, 0);
      __builtin_amdgcn_global_load_lds((g_u32*)gb, (l_u32*)lb, 16, 0, 0);
    }
    __syncthreads();

#pragma unroll
    for (int ks = 0; ks < 2; ++ks) {
      const int cl = (ks * 4 + l4) ^ (l15 & 7);
      bf16x8 af[4], bfr[4];
#pragma unroll
      for (int m = 0; m < 4; ++m)
        af[m] = *(const bf16x8*)(As + (size_t)(wr * 64 + m * 16 + l15) * 64 + cl * 8);
#pragma unroll
      for (int n = 0; n < 4; ++n)
        bfr[n] = *(const bf16x8*)(Bs + (size_t)(wc * 64 + n * 16 + l15) * 64 + cl * 8);
#pragma unroll
      for (int m = 0; m < 4; ++m)
#pragma unroll
        for (int n = 0; n < 4; ++n)
          acc[m][n] = __builtin_amdgcn_mfma_f32_16x16x32_bf16(af[m], bfr[n], acc[m][n], 0, 0, 0);
    }
  }

  float* Cf = (float*)Cv;
  __hip_bfloat16* Cb = (__hip_bfloat16*)Cv;
#pragma unroll
  for (int m = 0; m < 4; ++m) {
#pragma unroll
    for (int n = 0; n < 4; ++n) {
#pragma unroll
      for (int r = 0; r < 4; ++r) {
        int row = bm + wr * 64 + m * 16 + l4 * 4 + r;
        int col = bn + wc * 64 + n * 16 + l15;
        size_t off = (size_t)row * N + col;
        float v = acc[m][n][r];
        if (mode == 0)      Cf[off] = v;
        else if (mode == 1) Cf[off] = v + resid[off];
        else if (mode == 2) Cb[off] = __float2bfloat16(v);
        else                Cb[off] = __float2bfloat16(gelu_f(v));
      }
    }
  }
}

// ---------- 64x64-tile variant (for N=768 GEMMs: wo, fc2) ----------
// grid (N/64, M/64) = 768 blocks -> 3 blocks/CU. 2x2 waves of 32x32.
__global__ __launch_bounds__(256) void gemm64_bf16_kernel(
    const __hip_bfloat16* __restrict__ A, const __hip_bfloat16* __restrict__ W,
    void* __restrict__ Cv, const float* __restrict__ resid,
    int N, int K, int mode)
{
  __shared__ __align__(16) unsigned short As[64 * 64];   // 8 KB
  __shared__ __align__(16) unsigned short Bs[64 * 64];   // 8 KB
  const unsigned short* Au = (const unsigned short*)A;
  const unsigned short* Wu = (const unsigned short*)W;
  const int tid = threadIdx.x;
  const int wv = tid >> 6, ln = tid & 63;
  const int l15 = ln & 15, l4 = ln >> 4;
  int2 tc = xcd_tile(N >> 6, gridDim.y);
  const int bm = tc.y * 64, bn = tc.x * 64;
  const int wr = wv >> 1, wc = wv & 1;

  const int srow = wv * 8 + (ln >> 3);
  const int scg  = (ln & 7) ^ (ln >> 3);

  f32x4 acc[2][2];
#pragma unroll
  for (int m = 0; m < 2; ++m)
#pragma unroll
    for (int n = 0; n < 2; ++n) acc[m][n] = (f32x4){0.f, 0.f, 0.f, 0.f};

  for (int k0 = 0; k0 < K; k0 += 64) {
    __syncthreads();
#pragma unroll
    for (int r = 0; r < 2; ++r) {
      int row = r * 32 + srow;
      const unsigned short* ga = Au + (size_t)(bm + row) * K + k0 + scg * 8;
      const unsigned short* gb = Wu + (size_t)(bn + row) * K + k0 + scg * 8;
      unsigned short* la = As + (size_t)(r * 256 + wv * 64) * 8;
      unsigned short* lb = Bs + (size_t)(r * 256 + wv * 64) * 8;
      __builtin_amdgcn_global_load_lds((g_u32*)ga, (l_u32*)la, 16, 0, 0);
      __builtin_amdgcn_global_load_lds((g_u32*)gb, (l_u32*)lb, 16, 0, 0);
    }
    __syncthreads();

#pragma unroll
    for (int ks = 0; ks < 2; ++ks) {
      const int cl = (ks * 4 + l4) ^ (l15 & 7);
      bf16x8 af[2], bfr[2];
#pragma unroll
      for (int m = 0; m < 2; ++m)
        af[m] = *(const bf16x8*)(As + (size_t)(wr * 32 + m * 16 + l15) * 64 + cl * 8);
#pragma unroll
      for (int n = 0; n < 2; ++n)
        bfr[n] = *(const bf16x8*)(Bs + (size_t)(wc * 32 + n * 16 + l15) * 64 + cl * 8);
#pragma unroll
      for (int m = 0; m < 2; ++m)
#pragma unroll
        for (int n = 0; n < 2; ++n)
          acc[m][n] = __builtin_amdgcn_mfma_f32_16x16x32_bf16(af[m], bfr[n], acc[m][n], 0, 0, 0);
    }
  }

  float* Cf = (float*)Cv;
  __hip_bfloat16* Cb = (__hip_bfloat16*)Cv;
#pragma unroll
  for (int m = 0; m < 2; ++m) {
#pragma unroll
    for (int n = 0; n < 2; ++n) {
#pragma unroll
      for (int r = 0; r < 4; ++r) {
        int row = bm + wr * 32 + m * 16 + l4 * 4 + r;
        int col = bn + wc * 32 + n * 16 + l15;
        size_t off = (size_t)row * N + col;
        float v = acc[m][n][r];
        if (mode == 0)      Cf[off] = v;
        else if (mode == 1) Cf[off] = v + resid[off];
        else if (mode == 2) Cb[off] = __float2bfloat16(v);
        else                Cb[off] = __float2bfloat16(gelu_f(v));
      }
    }
  }
}

// ---------- MFMA flash attention (bf16 MFMA, fp32 softmax/accum) ----------
__global__ __launch_bounds__(256) void flash_attn_kernel(
    const __hip_bfloat16* __restrict__ qkv_, __hip_bfloat16* __restrict__ attn_)
{
  const unsigned short* qkv = (const unsigned short*)qkv_;
  unsigned short* attn = (unsigned short*)attn_;
  const int s0 = blockIdx.x * 64;
  const int h  = blockIdx.y;
  const int b  = blockIdx.z;
  const int tid = threadIdx.x;
  const int wq = tid >> 6, ln = tid & 63;
  const int l15 = ln & 15, l4 = ln >> 4;

  __shared__ unsigned short Ks[64 * 64];      // 8 KB
  __shared__ unsigned short Vt[64 * 64];      // 8 KB (transposed: [e][t])
  __shared__ unsigned short Pw[4][16 * 64];   // 8 KB (per-wave P)

  bf16x8 qf[2];
  {
    const size_t qbase = (size_t)(b * SEQ + s0 + wq * 16 + l15) * 2304 + h * 64;
#pragma unroll
    for (int ks = 0; ks < 2; ++ks) {
      u16x8 raw = *(const u16x8*)(qkv + qbase + ks * 32 + l4 * 8);
      bf16x8 q;
#pragma unroll
      for (int j = 0; j < 8; ++j) q[j] = (short)f2bf(bf2f(raw[j]) * 0.125f);
      qf[ks] = q;
    }
  }

  float mrow[4], lrow[4];
  f32x4 o[4];
#pragma unroll
  for (int r = 0; r < 4; ++r) { mrow[r] = -1e30f; lrow[r] = 0.f; }
#pragma unroll
  for (int n = 0; n < 4; ++n) o[n] = (f32x4){0.f, 0.f, 0.f, 0.f};

  for (int t0 = 0; t0 <= s0; t0 += 64) {
    __syncthreads();

#pragma unroll
    for (int r = 0; r < 2; ++r) {
      int o128 = wq * 2 + r;
      int t = o128 * 8 + (ln >> 3);
      int db = (ln & 7) ^ (ln >> 3);
      const unsigned short* gk =
          qkv + (size_t)(b * SEQ + t0 + t) * 2304 + 768 + h * 64 + db * 8;
      __builtin_amdgcn_global_load_lds((g_u32*)gk, (l_u32*)(Ks + o128 * 512), 16, 0, 0);
    }

    {
      int vt = tid >> 2, ec = (tid & 3) * 16;
      const unsigned short* gv =
          qkv + (size_t)(b * SEQ + t0 + vt) * 2304 + 1536 + h * 64 + ec;
      u16x8 v0 = *(const u16x8*)gv;
      u16x8 v1 = *(const u16x8*)(gv + 8);
      int tb = vt >> 3, tr = vt & 7;
#pragma unroll
      for (int j = 0; j < 8; ++j) {
        int e0 = ec + j, e1 = ec + 8 + j;
        Vt[e0 * 64 + ((tb ^ (e0 & 7)) << 3) + tr] = (unsigned short)v0[j];
        Vt[e1 * 64 + ((tb ^ (e1 & 7)) << 3) + tr] = (unsigned short)v1[j];
      }
    }
    __syncthreads();

    f32x4 sf[4];
#pragma unroll
    for (int n = 0; n < 4; ++n) sf[n] = (f32x4){0.f, 0.f, 0.f, 0.f};
#pragma unroll
    for (int ks = 0; ks < 2; ++ks) {
#pragma unroll
      for (int n = 0; n < 4; ++n) {
        int t = n * 16 + l15;
        bf16x8 kf = *(const bf16x8*)(Ks + t * 64 + (((ks * 4 + l4) ^ (t & 7)) << 3));
        sf[n] = __builtin_amdgcn_mfma_f32_16x16x32_bf16(qf[ks], kf, sf[n], 0, 0, 0);
      }
    }

    if (t0 == s0) {
#pragma unroll
      for (int n = 0; n < 4; ++n) {
        int t = n * 16 + l15;
#pragma unroll
        for (int r = 0; r < 4; ++r) {
          int q = wq * 16 + l4 * 4 + r;
          if (t > q) sf[n][r] = NEGV;
        }
      }
    }

    float pbuf[4][4];
#pragma unroll
    for (int r = 0; r < 4; ++r) {
      float rmax = fmaxf(fmaxf(sf[0][r], sf[1][r]), fmaxf(sf[2][r], sf[3][r]));
#pragma unroll
      for (int m = 1; m < 16; m <<= 1) rmax = fmaxf(rmax, __shfl_xor(rmax, m, 64));
      float mnew = fmaxf(mrow[r], rmax);
      float alpha = __expf(mrow[r] - mnew);
      float part = 0.f;
#pragma unroll
      for (int n = 0; n < 4; ++n) {
        float p = __expf(sf[n][r] - mnew);
        pbuf[n][r] = p;
        part += p;
      }
#pragma unroll
      for (int m = 1; m < 16; m <<= 1) part += __shfl_xor(part, m, 64);
      lrow[r] = lrow[r] * alpha + part;
      mrow[r] = mnew;
#pragma unroll
      for (int n = 0; n < 4; ++n) o[n][r] *= alpha;
    }

    unsigned short* Pme = Pw[wq];
#pragma unroll
    for (int n = 0; n < 4; ++n) {
      int tb = (n * 16 + l15) >> 3, tr = l15 & 7;
#pragma unroll
      for (int r = 0; r < 4; ++r) {
        int q = l4 * 4 + r;
        Pme[q * 64 + ((tb ^ (q & 7)) << 3) + tr] = f2bf(pbuf[n][r]);
      }
    }

#pragma unroll
    for (int ks = 0; ks < 2; ++ks) {
      bf16x8 pf = *(const bf16x8*)(Pme + l15 * 64 + (((ks * 4 + l4) ^ (l15 & 7)) << 3));
#pragma unroll
      for (int n = 0; n < 4; ++n) {
        int e = n * 16 + l15;
        bf16x8 vf = *(const bf16x8*)(Vt + e * 64 + (((ks * 4 + l4) ^ (e & 7)) << 3));
        o[n] = __builtin_amdgcn_mfma_f32_16x16x32_bf16(pf, vf, o[n], 0, 0, 0);
      }
    }
  }

#pragma unroll
  for (int r = 0; r < 4; ++r) {
    float inv = 1.0f / lrow[r];
    size_t base = (size_t)(b * SEQ + s0 + wq * 16 + l4 * 4 + r) * D_MODEL + h * 64;
#pragma unroll
    for (int n = 0; n < 4; ++n)
      attn[base + n * 16 + l15] = f2bf(o[n][r] * inv);
  }
}

// ---------- logits: out[b,v] = dot(normed[b,:], unembed[v,:]) ----------
__global__ __launch_bounds__(256) void logits_kernel(
    const float* __restrict__ normed, const float* __restrict__ unemb,
    float* __restrict__ out)
{
  __shared__ __align__(16) float ns[BATCH][D_MODEL];
  for (int d = threadIdx.x; d < BATCH * D_MODEL; d += 256)
    ((float*)ns)[d] = normed[d];
  __syncthreads();
  int g = threadIdx.x >> 4, li = threadIdx.x & 15;
  int v = blockIdx.x * 16 + g;
  const float* up = unemb + (size_t)v * D_MODEL;
  float s0 = 0.f, s1 = 0.f, s2 = 0.f, s3 = 0.f;
#pragma unroll
  for (int it = 0; it < D_MODEL / 64; ++it) {
    int e = it * 64 + li * 4;
    float4 u = *(const float4*)(up + e);
    float4 n0 = *(const float4*)&ns[0][e];
    float4 n1 = *(const float4*)&ns[1][e];
    float4 n2 = *(const float4*)&ns[2][e];
    float4 n3 = *(const float4*)&ns[3][e];
    s0 += u.x*n0.x + u.y*n0.y + u.z*n0.z + u.w*n0.w;
    s1 += u.x*n1.x + u.y*n1.y + u.z*n1.z + u.w*n1.w;
    s2 += u.x*n2.x + u.y*n2.y + u.z*n2.z + u.w*n2.w;
    s3 += u.x*n3.x + u.y*n3.y + u.z*n3.z + u.w*n3.w;
  }
#pragma unroll
  for (int msk = 1; msk < 16; msk <<= 1) {
    s0 += __shfl_xor(s0, msk, 64); s1 += __shfl_xor(s1, msk, 64);
    s2 += __shfl_xor(s2, msk, 64); s3 += __shfl_xor(s3, msk, 64);
  }
  if (li == 0) {
    out[(size_t)0 * VOCAB + v] = s0;
    out[(size_t)1 * VOCAB + v] = s1;
    out[(size_t)2 * VOCAB + v] = s2;
    out[(size_t)3 * VOCAB + v] = s3;
  }
}

// ---------- launcher ----------
extern "C" void kernel_launch(void* const* d_in, const int* in_sizes, int n_in,
                              void* d_out, int out_size, void* d_ws, size_t ws_size,
                              hipStream_t stream) {
  const int*   tokens = (const int*)d_in[0];
  const int*   pidx   = (const int*)d_in[1];
  const float* emb    = (const float*)d_in[2];
  const float* ln1_g  = (const float*)d_in[3];
  const float* ln1_b  = (const float*)d_in[4];
  const float* wq     = (const float*)d_in[5];
  const float* wk     = (const float*)d_in[6];
  const float* wv     = (const float*)d_in[7];
  const float* wo     = (const float*)d_in[8];
  const float* ln2_g  = (const float*)d_in[9];
  const float* ln2_b  = (const float*)d_in[10];
  const float* fc1    = (const float*)d_in[11];
  const float* fc2    = (const float*)d_in[12];
  const float* lnf_g  = (const float*)d_in[13];
  const float* lnf_b  = (const float*)d_in[14];
  const float* unemb  = (const float*)d_in[15];
  float* out = (float*)d_out;

  char* wp = (char*)d_ws;
  const size_t NX = (size_t)NROWS * D_MODEL;        // 3,145,728
  float* x = (float*)wp;                  wp += NX * 4;
  float* normed = (float*)wp;             wp += BATCH * D_MODEL * 4;
  __hip_bfloat16* h    = (__hip_bfloat16*)wp; wp += NX * 2;
  __hip_bfloat16* attn = (__hip_bfloat16*)wp; wp += NX * 2;
  __hip_bfloat16* qkvb = (__hip_bfloat16*)wp; wp += (size_t)NROWS * 2304 * 2;
  __hip_bfloat16* ffn  = (__hip_bfloat16*)wp; wp += (size_t)NROWS * D_FF * 2;
  __hip_bfloat16* wqkvb = (__hip_bfloat16*)wp; wp += (size_t)N_LAYERS * 2304 * D_MODEL * 2;
  __hip_bfloat16* wob   = (__hip_bfloat16*)wp; wp += (size_t)N_LAYERS * D_MODEL * D_MODEL * 2;
  __hip_bfloat16* fc1b  = (__hip_bfloat16*)wp; wp += (size_t)N_LAYERS * D_FF * D_MODEL * 2;
  __hip_bfloat16* fc2b  = (__hip_bfloat16*)wp; wp += (size_t)N_LAYERS * D_MODEL * D_FF * 2;

  const int WMAT = D_MODEL * D_MODEL;     // 589824
  const int FMAT = D_FF * D_MODEL;        // 2359296

  qkv_pack_kernel<<<N_LAYERS * 3 * WMAT / 2048, 256, 0, stream>>>(wq, wk, wv, wqkvb);
  convert_kernel<<<N_LAYERS * WMAT / 2048, 256, 0, stream>>>(wo,  wob,  N_LAYERS * WMAT);
  convert_kernel<<<N_LAYERS * FMAT / 2048, 256, 0, stream>>>(fc1, fc1b, N_LAYERS * FMAT);
  convert_kernel<<<N_LAYERS * FMAT / 2048, 256, 0, stream>>>(fc2, fc2b, N_LAYERS * FMAT);

  embed_kernel<<<NROWS, 256, 0, stream>>>(tokens, emb, x);

  for (int l = 0; l < N_LAYERS; ++l) {
    const size_t qofs = (size_t)l * 3 * WMAT;
    const size_t wofs = (size_t)l * WMAT;
    const size_t fofs = (size_t)l * FMAT;

    ln_kernel<<<NROWS, 256, 0, stream>>>(x, h, ln1_g + l * D_MODEL, ln1_b + l * D_MODEL);

    // fused QKV: [4096 x 2304] bf16 out
    gemm_bf16_kernel<<<dim3(2304 / 128, NROWS / 128), 256, 0, stream>>>(
        h, wqkvb + qofs, qkvb, nullptr, 2304, D_MODEL, 2);

    flash_attn_kernel<<<dim3(SEQ / 64, N_HEADS, BATCH), 256, 0, stream>>>(qkvb, attn);

    // x += attn @ wo^T  (64-tile: 768 blocks)
    gemm64_bf16_kernel<<<dim3(D_MODEL / 64, NROWS / 64), 256, 0, stream>>>(
        attn, wob + wofs, x, x, D_MODEL, D_MODEL, 1);

    ln_kernel<<<NROWS, 256, 0, stream>>>(x, h, ln2_g + l * D_MODEL, ln2_b + l * D_MODEL);

    // ffn = gelu(h @ fc1^T) (bf16)
    gemm_bf16_kernel<<<dim3(D_FF / 128, NROWS / 128), 256, 0, stream>>>(
        h, fc1b + fofs, ffn, nullptr, D_FF, D_MODEL, 3);

    // x += ffn @ fc2^T  (64-tile: 768 blocks)
    gemm64_bf16_kernel<<<dim3(D_MODEL / 64, NROWS / 64), 256, 0, stream>>>(
        ffn, fc2b + fofs, x, x, D_MODEL, D_FF, 1);
  }

  final_ln_kernel<<<BATCH, 256, 0, stream>>>(x, pidx, lnf_g, lnf_b, normed);
  logits_kernel<<<VOCAB / 16, 256, 0, stream>>>(normed, unemb, out);
}

// Round 5
// 956.812 us; speedup vs baseline: 5.7367x; 1.0410x over previous
//
#include <hip/hip_runtime.h>
#include <hip/hip_bf16.h>

#define D_MODEL 768
#define N_HEADS 12
#define D_HEAD  64
#define D_FF    3072
#define N_LAYERS 4
#define VOCAB   32000
#define BATCH   4
#define SEQ     1024
#define NROWS   (BATCH*SEQ)      // 4096
#define NEGV    -1000000000.0f
#define LN_EPS  1e-5f

typedef __attribute__((ext_vector_type(8))) short bf16x8;
typedef __attribute__((ext_vector_type(4))) float f32x4;
typedef __attribute__((ext_vector_type(8))) unsigned short u16x8;

typedef __attribute__((address_space(1))) const unsigned int g_u32;
typedef __attribute__((address_space(3))) unsigned int l_u32;

__device__ __forceinline__ float bf2f(unsigned short u) {
  return __uint_as_float(((unsigned int)u) << 16);
}
__device__ __forceinline__ unsigned short f2bf(float f) {
  __hip_bfloat16 h = __float2bfloat16(f);
  return *reinterpret_cast<unsigned short*>(&h);
}

__device__ __forceinline__ float block_reduce_sum(float v, float* sbuf) {
#pragma unroll
  for (int off = 32; off > 0; off >>= 1) v += __shfl_down(v, off, 64);
  int lane = threadIdx.x & 63, wid = threadIdx.x >> 6;
  if (lane == 0) sbuf[wid] = v;
  __syncthreads();
  if (threadIdx.x == 0) sbuf[4] = sbuf[0] + sbuf[1] + sbuf[2] + sbuf[3];
  __syncthreads();
  return sbuf[4];
}

__device__ __forceinline__ float gelu_f(float x) {
  float c = x + 0.044715f * x * x * x;
  return x * (0.5f * (1.0f + tanhf(0.7978845608f * c)));
}

// ---------- fp32 -> bf16 weight conversion (8 elems / thread) ----------
__global__ __launch_bounds__(256) void convert_kernel(
    const float* __restrict__ src, __hip_bfloat16* __restrict__ dst, int n)
{
  int i = (blockIdx.x * 256 + threadIdx.x) * 8;
  if (i >= n) return;
  float4 a = *(const float4*)(src + i);
  float4 b = *(const float4*)(src + i + 4);
  struct bf8 { __hip_bfloat16 h[8]; } r;
  r.h[0] = __float2bfloat16(a.x); r.h[1] = __float2bfloat16(a.y);
  r.h[2] = __float2bfloat16(a.z); r.h[3] = __float2bfloat16(a.w);
  r.h[4] = __float2bfloat16(b.x); r.h[5] = __float2bfloat16(b.y);
  r.h[6] = __float2bfloat16(b.z); r.h[7] = __float2bfloat16(b.w);
  *(bf8*)(dst + i) = r;
}

// pack wq|wk|wv of all layers into wqkvb [l][3*WMAT] in one launch
__global__ __launch_bounds__(256) void qkv_pack_kernel(
    const float* __restrict__ wq, const float* __restrict__ wk,
    const float* __restrict__ wv, __hip_bfloat16* __restrict__ dst)
{
  const int WMAT = D_MODEL * D_MODEL;
  long long i = (long long)(blockIdx.x * 256 + threadIdx.x) * 8;
  long long l = i / (3LL * WMAT);
  long long rem = i - l * 3LL * WMAT;
  int which = (int)(rem / WMAT);
  long long off = rem - (long long)which * WMAT;
  const float* src = (which == 0 ? wq : which == 1 ? wk : wv) + l * WMAT + off;
  float4 a = *(const float4*)src;
  float4 b = *(const float4*)(src + 4);
  struct bf8 { __hip_bfloat16 h[8]; } r;
  r.h[0] = __float2bfloat16(a.x); r.h[1] = __float2bfloat16(a.y);
  r.h[2] = __float2bfloat16(a.z); r.h[3] = __float2bfloat16(a.w);
  r.h[4] = __float2bfloat16(b.x); r.h[5] = __float2bfloat16(b.y);
  r.h[6] = __float2bfloat16(b.z); r.h[7] = __float2bfloat16(b.w);
  *(bf8*)(dst + i) = r;
}

// ---------- embedding transpose: emb [768][32000] f32 -> embT [32000][768] bf16 ----------
// 64x64 tiles via LDS. Read coalesced along vocab; write coalesced along d.
__global__ __launch_bounds__(256) void transpose_emb_kernel(
    const float* __restrict__ emb, __hip_bfloat16* __restrict__ embT)
{
  __shared__ float tile[64][65];
  const int vb = blockIdx.x * 64;   // vocab block
  const int db = blockIdx.y * 64;   // d block
  const int tid = threadIdx.x;
  // read: 16 rows/pass x 16 threads x float4 (64 vocab)
  {
    int r = tid >> 4, c = (tid & 15) * 4;
#pragma unroll
    for (int p = 0; p < 4; ++p) {
      float4 v = *(const float4*)(emb + (size_t)(db + r + p * 16) * VOCAB + vb + c);
      tile[c + 0][r + p * 16] = v.x;  // store transposed into LDS
      tile[c + 1][r + p * 16] = v.y;
      tile[c + 2][r + p * 16] = v.z;
      tile[c + 3][r + p * 16] = v.w;
    }
  }
  __syncthreads();
  // write: thread -> vocab row v = tid>>2, d chunk (tid&3)*16
  {
    int v = tid >> 2, d0 = (tid & 3) * 16;
    unsigned short* op = (unsigned short*)embT + (size_t)(vb + v) * D_MODEL + db + d0;
    u16x8 o0, o1;
#pragma unroll
    for (int j = 0; j < 8; ++j) {
      o0[j] = f2bf(tile[v][d0 + j]);
      o1[j] = f2bf(tile[v][d0 + 8 + j]);
    }
    *(u16x8*)op = o0;
    *(u16x8*)(op + 8) = o1;
  }
}

// ---------- embedding gather (coalesced) + positional encoding ----------
__global__ __launch_bounds__(256) void embed_kernel(
    const int* __restrict__ tokens, const __hip_bfloat16* __restrict__ embT,
    float* __restrict__ x)
{
  int bs = blockIdx.x;
  int s = bs & (SEQ - 1);
  int tok = tokens[bs];
  const unsigned short* ep = (const unsigned short*)embT + (size_t)tok * D_MODEL;
  for (int d = threadIdx.x; d < D_MODEL; d += 256) {
    float ev = bf2f(ep[d]);
    int dpair = d & ~1;
    float expo = (float)dpair * (1.0f / (float)D_MODEL);
    float ang = (float)s / powf(10000.0f, expo);
    float pe = (d & 1) ? cosf(ang) : sinf(ang);
    x[(size_t)bs * D_MODEL + d] = ev + pe;
  }
}

// ---------- layer norm (fp32 in, bf16 out) ----------
__global__ __launch_bounds__(256) void ln_kernel(
    const float* __restrict__ in, __hip_bfloat16* __restrict__ out,
    const float* __restrict__ g, const float* __restrict__ bb)
{
  __shared__ float sbuf[8];
  size_t row = blockIdx.x;
  const float* rp = in + row * D_MODEL;
  int t = threadIdx.x;
  float x0 = rp[t], x1 = rp[t + 256], x2 = rp[t + 512];
  float mean = block_reduce_sum(x0 + x1 + x2, sbuf) * (1.0f / (float)D_MODEL);
  float d0 = x0 - mean, d1 = x1 - mean, d2 = x2 - mean;
  float var = block_reduce_sum(d0*d0 + d1*d1 + d2*d2, sbuf) * (1.0f / (float)D_MODEL);
  float rstd = rsqrtf(var + LN_EPS);
  __hip_bfloat16* op = out + row * D_MODEL;
  op[t]       = __float2bfloat16(g[t]       * (d0 * rstd) + bb[t]);
  op[t + 256] = __float2bfloat16(g[t + 256] * (d1 * rstd) + bb[t + 256]);
  op[t + 512] = __float2bfloat16(g[t + 512] * (d2 * rstd) + bb[t + 512]);
}

// final LN on x[b, predict_idx, :] (fp32 out)
__global__ __launch_bounds__(256) void final_ln_kernel(
    const float* __restrict__ x, const int* __restrict__ pidx,
    const float* __restrict__ g, const float* __restrict__ bb,
    float* __restrict__ out)
{
  __shared__ float sbuf[8];
  int p = pidx[0];
  const float* rp = x + ((size_t)blockIdx.x * SEQ + p) * D_MODEL;
  int t = threadIdx.x;
  float x0 = rp[t], x1 = rp[t + 256], x2 = rp[t + 512];
  float mean = block_reduce_sum(x0 + x1 + x2, sbuf) * (1.0f / (float)D_MODEL);
  float d0 = x0 - mean, d1 = x1 - mean, d2 = x2 - mean;
  float var = block_reduce_sum(d0*d0 + d1*d1 + d2*d2, sbuf) * (1.0f / (float)D_MODEL);
  float rstd = rsqrtf(var + LN_EPS);
  float* op = out + (size_t)blockIdx.x * D_MODEL;
  op[t]       = g[t]       * (d0 * rstd) + bb[t];
  op[t + 256] = g[t + 256] * (d1 * rstd) + bb[t + 256];
  op[t + 512] = g[t + 512] * (d2 * rstd) + bb[t + 512];
}

// XCD-chunked bijective block swizzle (nwg % 8 == 0 for all our grids)
__device__ __forceinline__ int2 xcd_tile(int gx, int gy) {
  int flat = blockIdx.y * gx + blockIdx.x;
  int cpx = (gx * gy) >> 3;
  int logical = (flat & 7) * cpx + (flat >> 3);
  return make_int2(logical % gx, logical / gx);   // (col, row)
}

// ---------- bf16 MFMA NT GEMM, 2-phase pipelined ----------
// 128x128 tile, BK=64, double-buffered LDS (2x32 KB), XOR-swizzled layout,
// per tile: { sync; STAGE(next tile, other buf); ds_read+MFMA this buf }.
// mode: 0 = fp32 out, 1 = fp32 + resid, 2 = bf16 out, 3 = bf16 + gelu
__global__ __launch_bounds__(256) void gemm_bf16_kernel(
    const __hip_bfloat16* __restrict__ A, const __hip_bfloat16* __restrict__ W,
    void* __restrict__ Cv, const float* __restrict__ resid,
    int N, int K, int mode)
{
  __shared__ __align__(16) unsigned short As[2][128 * 64];   // 32 KB
  __shared__ __align__(16) unsigned short Bs[2][128 * 64];   // 32 KB
  const unsigned short* Au = (const unsigned short*)A;
  const unsigned short* Wu = (const unsigned short*)W;
  const int tid = threadIdx.x;
  const int wv = tid >> 6, ln = tid & 63;
  const int l15 = ln & 15, l4 = ln >> 4;
  int2 tc = xcd_tile(N >> 7, gridDim.y);
  const int bm = tc.y * 128, bn = tc.x * 128;
  const int wr = wv >> 1, wc = wv & 1;

  // staging geometry: slot = r*256+tid -> row slot/8, LDS chunk ln&7,
  // source chunk (ln&7)^(row&7) with row&7 == ln>>3
  const int srow = wv * 8 + (ln >> 3);
  const int scg  = (ln & 7) ^ (ln >> 3);
  const size_t gofs_a = (size_t)(bm + srow) * K + scg * 8;
  const size_t gofs_b = (size_t)(bn + srow) * K + scg * 8;
  const size_t rstride = (size_t)32 * K;

#define STAGE128(buf, k0)                                                    \
  {                                                                          \
    _Pragma("unroll")                                                        \
    for (int r = 0; r < 4; ++r) {                                            \
      const unsigned short* ga = Au + gofs_a + r * rstride + (k0);           \
      const unsigned short* gb = Wu + gofs_b + r * rstride + (k0);           \
      unsigned short* la = As[buf] + (size_t)(r * 256 + wv * 64) * 8;        \
      unsigned short* lb = Bs[buf] + (size_t)(r * 256 + wv * 64) * 8;        \
      __builtin_amdgcn_global_load_lds((g_u32*)ga, (l_u32*)la, 16, 0, 0);    \
      __builtin_amdgcn_global_load_lds((g_u32*)gb, (l_u32*)lb, 16, 0, 0);    \
    }                                                                        \
  }

  f32x4 acc[4][4];
#pragma unroll
  for (int m = 0; m < 4; ++m)
#pragma unroll
    for (int n = 0; n < 4; ++n) acc[m][n] = (f32x4){0.f, 0.f, 0.f, 0.f};

  const int NT = K >> 6;
  STAGE128(0, 0);
  int cur = 0;
  for (int t = 0; t < NT; ++t) {
    __syncthreads();   // drains own vmcnt: tile t landed; prev reads done
    if (t + 1 < NT) STAGE128(cur ^ 1, (t + 1) << 6);
#pragma unroll
    for (int ks = 0; ks < 2; ++ks) {
      const int cl = (ks * 4 + l4) ^ (l15 & 7);
      bf16x8 af[4], bfr[4];
#pragma unroll
      for (int m = 0; m < 4; ++m)
        af[m] = *(const bf16x8*)(As[cur] + (size_t)(wr * 64 + m * 16 + l15) * 64 + cl * 8);
#pragma unroll
      for (int n = 0; n < 4; ++n)
        bfr[n] = *(const bf16x8*)(Bs[cur] + (size_t)(wc * 64 + n * 16 + l15) * 64 + cl * 8);
#pragma unroll
      for (int m = 0; m < 4; ++m)
#pragma unroll
        for (int n = 0; n < 4; ++n)
          acc[m][n] = __builtin_amdgcn_mfma_f32_16x16x32_bf16(af[m], bfr[n], acc[m][n], 0, 0, 0);
    }
    cur ^= 1;
  }

  float* Cf = (float*)Cv;
  __hip_bfloat16* Cb = (__hip_bfloat16*)Cv;
#pragma unroll
  for (int m = 0; m < 4; ++m) {
#pragma unroll
    for (int n = 0; n < 4; ++n) {
#pragma unroll
      for (int r = 0; r < 4; ++r) {
        int row = bm + wr * 64 + m * 16 + l4 * 4 + r;
        int col = bn + wc * 64 + n * 16 + l15;
        size_t off = (size_t)row * N + col;
        float v = acc[m][n][r];
        if (mode == 0)      Cf[off] = v;
        else if (mode == 1) Cf[off] = v + resid[off];
        else if (mode == 2) Cb[off] = __float2bfloat16(v);
        else                Cb[off] = __float2bfloat16(gelu_f(v));
      }
    }
  }
}

// ---------- 64x64-tile variant (N=768 GEMMs: wo, fc2), 2-phase pipelined ----------
__global__ __launch_bounds__(256) void gemm64_bf16_kernel(
    const __hip_bfloat16* __restrict__ A, const __hip_bfloat16* __restrict__ W,
    void* __restrict__ Cv, const float* __restrict__ resid,
    int N, int K, int mode)
{
  __shared__ __align__(16) unsigned short As[2][64 * 64];   // 16 KB
  __shared__ __align__(16) unsigned short Bs[2][64 * 64];   // 16 KB
  const unsigned short* Au = (const unsigned short*)A;
  const unsigned short* Wu = (const unsigned short*)W;
  const int tid = threadIdx.x;
  const int wv = tid >> 6, ln = tid & 63;
  const int l15 = ln & 15, l4 = ln >> 4;
  int2 tc = xcd_tile(N >> 6, gridDim.y);
  const int bm = tc.y * 64, bn = tc.x * 64;
  const int wr = wv >> 1, wc = wv & 1;

  const int srow = wv * 8 + (ln >> 3);
  const int scg  = (ln & 7) ^ (ln >> 3);
  const size_t gofs_a = (size_t)(bm + srow) * K + scg * 8;
  const size_t gofs_b = (size_t)(bn + srow) * K + scg * 8;
  const size_t rstride = (size_t)32 * K;

#define STAGE64(buf, k0)                                                     \
  {                                                                          \
    _Pragma("unroll")                                                        \
    for (int r = 0; r < 2; ++r) {                                            \
      const unsigned short* ga = Au + gofs_a + r * rstride + (k0);           \
      const unsigned short* gb = Wu + gofs_b + r * rstride + (k0);           \
      unsigned short* la = As[buf] + (size_t)(r * 256 + wv * 64) * 8;        \
      unsigned short* lb = Bs[buf] + (size_t)(r * 256 + wv * 64) * 8;        \
      __builtin_amdgcn_global_load_lds((g_u32*)ga, (l_u32*)la, 16, 0, 0);    \
      __builtin_amdgcn_global_load_lds((g_u32*)gb, (l_u32*)lb, 16, 0, 0);    \
    }                                                                        \
  }

  f32x4 acc[2][2];
#pragma unroll
  for (int m = 0; m < 2; ++m)
#pragma unroll
    for (int n = 0; n < 2; ++n) acc[m][n] = (f32x4){0.f, 0.f, 0.f, 0.f};

  const int NT = K >> 6;
  STAGE64(0, 0);
  int cur = 0;
  for (int t = 0; t < NT; ++t) {
    __syncthreads();
    if (t + 1 < NT) STAGE64(cur ^ 1, (t + 1) << 6);
#pragma unroll
    for (int ks = 0; ks < 2; ++ks) {
      const int cl = (ks * 4 + l4) ^ (l15 & 7);
      bf16x8 af[2], bfr[2];
#pragma unroll
      for (int m = 0; m < 2; ++m)
        af[m] = *(const bf16x8*)(As[cur] + (size_t)(wr * 32 + m * 16 + l15) * 64 + cl * 8);
#pragma unroll
      for (int n = 0; n < 2; ++n)
        bfr[n] = *(const bf16x8*)(Bs[cur] + (size_t)(wc * 32 + n * 16 + l15) * 64 + cl * 8);
#pragma unroll
      for (int m = 0; m < 2; ++m)
#pragma unroll
        for (int n = 0; n < 2; ++n)
          acc[m][n] = __builtin_amdgcn_mfma_f32_16x16x32_bf16(af[m], bfr[n], acc[m][n], 0, 0, 0);
    }
    cur ^= 1;
  }

  float* Cf = (float*)Cv;
  __hip_bfloat16* Cb = (__hip_bfloat16*)Cv;
#pragma unroll
  for (int m = 0; m < 2; ++m) {
#pragma unroll
    for (int n = 0; n < 2; ++n) {
#pragma unroll
      for (int r = 0; r < 4; ++r) {
        int row = bm + wr * 32 + m * 16 + l4 * 4 + r;
        int col = bn + wc * 32 + n * 16 + l15;
        size_t off = (size_t)row * N + col;
        float v = acc[m][n][r];
        if (mode == 0)      Cf[off] = v;
        else if (mode == 1) Cf[off] = v + resid[off];
        else if (mode == 2) Cb[off] = __float2bfloat16(v);
        else                Cb[off] = __float2bfloat16(gelu_f(v));
      }
    }
  }
}

// ---------- MFMA flash attention (bf16 MFMA, fp32 softmax/accum) ----------
__global__ __launch_bounds__(256) void flash_attn_kernel(
    const __hip_bfloat16* __restrict__ qkv_, __hip_bfloat16* __restrict__ attn_)
{
  const unsigned short* qkv = (const unsigned short*)qkv_;
  unsigned short* attn = (unsigned short*)attn_;
  const int s0 = blockIdx.x * 64;
  const int h  = blockIdx.y;
  const int b  = blockIdx.z;
  const int tid = threadIdx.x;
  const int wq = tid >> 6, ln = tid & 63;
  const int l15 = ln & 15, l4 = ln >> 4;

  __shared__ unsigned short Ks[64 * 64];      // 8 KB
  __shared__ unsigned short Vt[64 * 64];      // 8 KB (transposed: [e][t])
  __shared__ unsigned short Pw[4][16 * 64];   // 8 KB (per-wave P)

  bf16x8 qf[2];
  {
    const size_t qbase = (size_t)(b * SEQ + s0 + wq * 16 + l15) * 2304 + h * 64;
#pragma unroll
    for (int ks = 0; ks < 2; ++ks) {
      u16x8 raw = *(const u16x8*)(qkv + qbase + ks * 32 + l4 * 8);
      bf16x8 q;
#pragma unroll
      for (int j = 0; j < 8; ++j) q[j] = (short)f2bf(bf2f(raw[j]) * 0.125f);
      qf[ks] = q;
    }
  }

  float mrow[4], lrow[4];
  f32x4 o[4];
#pragma unroll
  for (int r = 0; r < 4; ++r) { mrow[r] = -1e30f; lrow[r] = 0.f; }
#pragma unroll
  for (int n = 0; n < 4; ++n) o[n] = (f32x4){0.f, 0.f, 0.f, 0.f};

  for (int t0 = 0; t0 <= s0; t0 += 64) {
    __syncthreads();

#pragma unroll
    for (int r = 0; r < 2; ++r) {
      int o128 = wq * 2 + r;
      int t = o128 * 8 + (ln >> 3);
      int db = (ln & 7) ^ (ln >> 3);
      const unsigned short* gk =
          qkv + (size_t)(b * SEQ + t0 + t) * 2304 + 768 + h * 64 + db * 8;
      __builtin_amdgcn_global_load_lds((g_u32*)gk, (l_u32*)(Ks + o128 * 512), 16, 0, 0);
    }

    {
      int vt = tid >> 2, ec = (tid & 3) * 16;
      const unsigned short* gv =
          qkv + (size_t)(b * SEQ + t0 + vt) * 2304 + 1536 + h * 64 + ec;
      u16x8 v0 = *(const u16x8*)gv;
      u16x8 v1 = *(const u16x8*)(gv + 8);
      int tb = vt >> 3, tr = vt & 7;
#pragma unroll
      for (int j = 0; j < 8; ++j) {
        int e0 = ec + j, e1 = ec + 8 + j;
        Vt[e0 * 64 + ((tb ^ (e0 & 7)) << 3) + tr] = (unsigned short)v0[j];
        Vt[e1 * 64 + ((tb ^ (e1 & 7)) << 3) + tr] = (unsigned short)v1[j];
      }
    }
    __syncthreads();

    f32x4 sf[4];
#pragma unroll
    for (int n = 0; n < 4; ++n) sf[n] = (f32x4){0.f, 0.f, 0.f, 0.f};
#pragma unroll
    for (int ks = 0; ks < 2; ++ks) {
#pragma unroll
      for (int n = 0; n < 4; ++n) {
        int t = n * 16 + l15;
        bf16x8 kf = *(const bf16x8*)(Ks + t * 64 + (((ks * 4 + l4) ^ (t & 7)) << 3));
        sf[n] = __builtin_amdgcn_mfma_f32_16x16x32_bf16(qf[ks], kf, sf[n], 0, 0, 0);
      }
    }

    if (t0 == s0) {
#pragma unroll
      for (int n = 0; n < 4; ++n) {
        int t = n * 16 + l15;
#pragma unroll
        for (int r = 0; r < 4; ++r) {
          int q = wq * 16 + l4 * 4 + r;
          if (t > q) sf[n][r] = NEGV;
        }
      }
    }

    float pbuf[4][4];
#pragma unroll
    for (int r = 0; r < 4; ++r) {
      float rmax = fmaxf(fmaxf(sf[0][r], sf[1][r]), fmaxf(sf[2][r], sf[3][r]));
#pragma unroll
      for (int m = 1; m < 16; m <<= 1) rmax = fmaxf(rmax, __shfl_xor(rmax, m, 64));
      float mnew = fmaxf(mrow[r], rmax);
      float alpha = __expf(mrow[r] - mnew);
      float part = 0.f;
#pragma unroll
      for (int n = 0; n < 4; ++n) {
        float p = __expf(sf[n][r] - mnew);
        pbuf[n][r] = p;
        part += p;
      }
#pragma unroll
      for (int m = 1; m < 16; m <<= 1) part += __shfl_xor(part, m, 64);
      lrow[r] = lrow[r] * alpha + part;
      mrow[r] = mnew;
#pragma unroll
      for (int n = 0; n < 4; ++n) o[n][r] *= alpha;
    }

    unsigned short* Pme = Pw[wq];
#pragma unroll
    for (int n = 0; n < 4; ++n) {
      int tb = (n * 16 + l15) >> 3, tr = l15 & 7;
#pragma unroll
      for (int r = 0; r < 4; ++r) {
        int q = l4 * 4 + r;
        Pme[q * 64 + ((tb ^ (q & 7)) << 3) + tr] = f2bf(pbuf[n][r]);
      }
    }

#pragma unroll
    for (int ks = 0; ks < 2; ++ks) {
      bf16x8 pf = *(const bf16x8*)(Pme + l15 * 64 + (((ks * 4 + l4) ^ (l15 & 7)) << 3));
#pragma unroll
      for (int n = 0; n < 4; ++n) {
        int e = n * 16 + l15;
        bf16x8 vf = *(const bf16x8*)(Vt + e * 64 + (((ks * 4 + l4) ^ (e & 7)) << 3));
        o[n] = __builtin_amdgcn_mfma_f32_16x16x32_bf16(pf, vf, o[n], 0, 0, 0);
      }
    }
  }

#pragma unroll
  for (int r = 0; r < 4; ++r) {
    float inv = 1.0f / lrow[r];
    size_t base = (size_t)(b * SEQ + s0 + wq * 16 + l4 * 4 + r) * D_MODEL + h * 64;
#pragma unroll
    for (int n = 0; n < 4; ++n)
      attn[base + n * 16 + l15] = f2bf(o[n][r] * inv);
  }
}

// ---------- logits: out[b,v] = dot(normed[b,:], unembed[v,:]) ----------
__global__ __launch_bounds__(256) void logits_kernel(
    const float* __restrict__ normed, const float* __restrict__ unemb,
    float* __restrict__ out)
{
  __shared__ __align__(16) float ns[BATCH][D_MODEL];
  for (int d = threadIdx.x; d < BATCH * D_MODEL; d += 256)
    ((float*)ns)[d] = normed[d];
  __syncthreads();
  int g = threadIdx.x >> 4, li = threadIdx.x & 15;
  int v = blockIdx.x * 16 + g;
  const float* up = unemb + (size_t)v * D_MODEL;
  float s0 = 0.f, s1 = 0.f, s2 = 0.f, s3 = 0.f;
#pragma unroll
  for (int it = 0; it < D_MODEL / 64; ++it) {
    int e = it * 64 + li * 4;
    float4 u = *(const float4*)(up + e);
    float4 n0 = *(const float4*)&ns[0][e];
    float4 n1 = *(const float4*)&ns[1][e];
    float4 n2 = *(const float4*)&ns[2][e];
    float4 n3 = *(const float4*)&ns[3][e];
    s0 += u.x*n0.x + u.y*n0.y + u.z*n0.z + u.w*n0.w;
    s1 += u.x*n1.x + u.y*n1.y + u.z*n1.z + u.w*n1.w;
    s2 += u.x*n2.x + u.y*n2.y + u.z*n2.z + u.w*n2.w;
    s3 += u.x*n3.x + u.y*n3.y + u.z*n3.z + u.w*n3.w;
  }
#pragma unroll
  for (int msk = 1; msk < 16; msk <<= 1) {
    s0 += __shfl_xor(s0, msk, 64); s1 += __shfl_xor(s1, msk, 64);
    s2 += __shfl_xor(s2, msk, 64); s3 += __shfl_xor(s3, msk, 64);
  }
  if (li == 0) {
    out[(size_t)0 * VOCAB + v] = s0;
    out[(size_t)1 * VOCAB + v] = s1;
    out[(size_t)2 * VOCAB + v] = s2;
    out[(size_t)3 * VOCAB + v] = s3;
  }
}

// ---------- launcher ----------
extern "C" void kernel_launch(void* const* d_in, const int* in_sizes, int n_in,
                              void* d_out, int out_size, void* d_ws, size_t ws_size,
                              hipStream_t stream) {
  const int*   tokens = (const int*)d_in[0];
  const int*   pidx   = (const int*)d_in[1];
  const float* emb    = (const float*)d_in[2];
  const float* ln1_g  = (const float*)d_in[3];
  const float* ln1_b  = (const float*)d_in[4];
  const float* wq     = (const float*)d_in[5];
  const float* wk     = (const float*)d_in[6];
  const float* wv     = (const float*)d_in[7];
  const float* wo     = (const float*)d_in[8];
  const float* ln2_g  = (const float*)d_in[9];
  const float* ln2_b  = (const float*)d_in[10];
  const float* fc1    = (const float*)d_in[11];
  const float* fc2    = (const float*)d_in[12];
  const float* lnf_g  = (const float*)d_in[13];
  const float* lnf_b  = (const float*)d_in[14];
  const float* unemb  = (const float*)d_in[15];
  float* out = (float*)d_out;

  char* wp = (char*)d_ws;
  const size_t NX = (size_t)NROWS * D_MODEL;        // 3,145,728
  float* x = (float*)wp;                  wp += NX * 4;
  float* normed = (float*)wp;             wp += BATCH * D_MODEL * 4;
  __hip_bfloat16* h    = (__hip_bfloat16*)wp; wp += NX * 2;
  __hip_bfloat16* attn = (__hip_bfloat16*)wp; wp += NX * 2;
  __hip_bfloat16* qkvb = (__hip_bfloat16*)wp; wp += (size_t)NROWS * 2304 * 2;
  __hip_bfloat16* ffn  = (__hip_bfloat16*)wp; wp += (size_t)NROWS * D_FF * 2;
  __hip_bfloat16* wqkvb = (__hip_bfloat16*)wp; wp += (size_t)N_LAYERS * 2304 * D_MODEL * 2;
  __hip_bfloat16* wob   = (__hip_bfloat16*)wp; wp += (size_t)N_LAYERS * D_MODEL * D_MODEL * 2;
  __hip_bfloat16* fc1b  = (__hip_bfloat16*)wp; wp += (size_t)N_LAYERS * D_FF * D_MODEL * 2;
  __hip_bfloat16* fc2b  = (__hip_bfloat16*)wp; wp += (size_t)N_LAYERS * D_MODEL * D_FF * 2;

  // embT [VOCAB][D_MODEL] bf16 (49.2 MB) aliased onto attn..ffn scratch
  // (50.4 MB): only live before the layer loop.
  __hip_bfloat16* embT = attn;

  const int WMAT = D_MODEL * D_MODEL;     // 589824
  const int FMAT = D_FF * D_MODEL;        // 2359296

  // embedding path first (embT dies before attention buffers are written)
  transpose_emb_kernel<<<dim3(VOCAB / 64, D_MODEL / 64), 256, 0, stream>>>(emb, embT);
  embed_kernel<<<NROWS, 256, 0, stream>>>(tokens, embT, x);

  qkv_pack_kernel<<<N_LAYERS * 3 * WMAT / 2048, 256, 0, stream>>>(wq, wk, wv, wqkvb);
  convert_kernel<<<N_LAYERS * WMAT / 2048, 256, 0, stream>>>(wo,  wob,  N_LAYERS * WMAT);
  convert_kernel<<<N_LAYERS * FMAT / 2048, 256, 0, stream>>>(fc1, fc1b, N_LAYERS * FMAT);
  convert_kernel<<<N_LAYERS * FMAT / 2048, 256, 0, stream>>>(fc2, fc2b, N_LAYERS * FMAT);

  for (int l = 0; l < N_LAYERS; ++l) {
    const size_t qofs = (size_t)l * 3 * WMAT;
    const size_t wofs = (size_t)l * WMAT;
    const size_t fofs = (size_t)l * FMAT;

    ln_kernel<<<NROWS, 256, 0, stream>>>(x, h, ln1_g + l * D_MODEL, ln1_b + l * D_MODEL);

    // fused QKV: [4096 x 2304] bf16 out
    gemm_bf16_kernel<<<dim3(2304 / 128, NROWS / 128), 256, 0, stream>>>(
        h, wqkvb + qofs, qkvb, nullptr, 2304, D_MODEL, 2);

    flash_attn_kernel<<<dim3(SEQ / 64, N_HEADS, BATCH), 256, 0, stream>>>(qkvb, attn);

    // x += attn @ wo^T  (64-tile: 768 blocks)
    gemm64_bf16_kernel<<<dim3(D_MODEL / 64, NROWS / 64), 256, 0, stream>>>(
        attn, wob + wofs, x, x, D_MODEL, D_MODEL, 1);

    ln_kernel<<<NROWS, 256, 0, stream>>>(x, h, ln2_g + l * D_MODEL, ln2_b + l * D_MODEL);

    // ffn = gelu(h @ fc1^T) (bf16)
    gemm_bf16_kernel<<<dim3(D_FF / 128, NROWS / 128), 256, 0, stream>>>(
        h, fc1b + fofs, ffn, nullptr, D_FF, D_MODEL, 3);

    // x += ffn @ fc2^T  (64-tile: 768 blocks)
    gemm64_bf16_kernel<<<dim3(D_MODEL / 64, NROWS / 64), 256, 0, stream>>>(
        ffn, fc2b + fofs, x, x, D_MODEL, D_FF, 1);
  }

  final_ln_kernel<<<BATCH, 256, 0, stream>>>(x, pidx, lnf_g, lnf_b, normed);
  logits_kernel<<<VOCAB / 16, 256, 0, stream>>>(normed, unemb, out);
}

// Round 6
// 925.502 us; speedup vs baseline: 5.9308x; 1.0338x over previous
//
#include <hip/hip_runtime.h>
#include <hip/hip_bf16.h>

#define D_MODEL 768
#define N_HEADS 12
#define D_HEAD  64
#define D_FF    3072
#define N_LAYERS 4
#define VOCAB   32000
#define BATCH   4
#define SEQ     1024
#define NROWS   (BATCH*SEQ)      // 4096
#define NEGV    -1000000000.0f
#define LN_EPS  1e-5f

typedef __attribute__((ext_vector_type(8))) short bf16x8;
typedef __attribute__((ext_vector_type(4))) float f32x4;
typedef __attribute__((ext_vector_type(8))) unsigned short u16x8;

typedef __attribute__((address_space(1))) const unsigned int g_u32;
typedef __attribute__((address_space(3))) unsigned int l_u32;

__device__ __forceinline__ float bf2f(unsigned short u) {
  return __uint_as_float(((unsigned int)u) << 16);
}
__device__ __forceinline__ unsigned short f2bf(float f) {
  __hip_bfloat16 h = __float2bfloat16(f);
  return *reinterpret_cast<unsigned short*>(&h);
}

__device__ __forceinline__ float block_reduce_sum(float v, float* sbuf) {
#pragma unroll
  for (int off = 32; off > 0; off >>= 1) v += __shfl_down(v, off, 64);
  int lane = threadIdx.x & 63, wid = threadIdx.x >> 6;
  if (lane == 0) sbuf[wid] = v;
  __syncthreads();
  if (threadIdx.x == 0) sbuf[4] = sbuf[0] + sbuf[1] + sbuf[2] + sbuf[3];
  __syncthreads();
  return sbuf[4];
}

__device__ __forceinline__ float gelu_f(float x) {
  float c = x + 0.044715f * x * x * x;
  return x * (0.5f * (1.0f + tanhf(0.7978845608f * c)));
}

// ---------- fp32 -> bf16 weight conversion (8 elems / thread) ----------
__global__ __launch_bounds__(256) void convert_kernel(
    const float* __restrict__ src, __hip_bfloat16* __restrict__ dst, int n)
{
  int i = (blockIdx.x * 256 + threadIdx.x) * 8;
  if (i >= n) return;
  float4 a = *(const float4*)(src + i);
  float4 b = *(const float4*)(src + i + 4);
  struct bf8 { __hip_bfloat16 h[8]; } r;
  r.h[0] = __float2bfloat16(a.x); r.h[1] = __float2bfloat16(a.y);
  r.h[2] = __float2bfloat16(a.z); r.h[3] = __float2bfloat16(a.w);
  r.h[4] = __float2bfloat16(b.x); r.h[5] = __float2bfloat16(b.y);
  r.h[6] = __float2bfloat16(b.z); r.h[7] = __float2bfloat16(b.w);
  *(bf8*)(dst + i) = r;
}

// pack wq|wk|wv of all layers into wqkvb [l][3*WMAT] in one launch
__global__ __launch_bounds__(256) void qkv_pack_kernel(
    const float* __restrict__ wq, const float* __restrict__ wk,
    const float* __restrict__ wv, __hip_bfloat16* __restrict__ dst)
{
  const int WMAT = D_MODEL * D_MODEL;
  long long i = (long long)(blockIdx.x * 256 + threadIdx.x) * 8;
  long long l = i / (3LL * WMAT);
  long long rem = i - l * 3LL * WMAT;
  int which = (int)(rem / WMAT);
  long long off = rem - (long long)which * WMAT;
  const float* src = (which == 0 ? wq : which == 1 ? wk : wv) + l * WMAT + off;
  float4 a = *(const float4*)src;
  float4 b = *(const float4*)(src + 4);
  struct bf8 { __hip_bfloat16 h[8]; } r;
  r.h[0] = __float2bfloat16(a.x); r.h[1] = __float2bfloat16(a.y);
  r.h[2] = __float2bfloat16(a.z); r.h[3] = __float2bfloat16(a.w);
  r.h[4] = __float2bfloat16(b.x); r.h[5] = __float2bfloat16(b.y);
  r.h[6] = __float2bfloat16(b.z); r.h[7] = __float2bfloat16(b.w);
  *(bf8*)(dst + i) = r;
}

// ---------- embedding transpose: emb [768][32000] f32 -> embT [32000][768] bf16 ----------
__global__ __launch_bounds__(256) void transpose_emb_kernel(
    const float* __restrict__ emb, __hip_bfloat16* __restrict__ embT)
{
  __shared__ float tile[64][65];
  const int vb = blockIdx.x * 64;   // vocab block
  const int db = blockIdx.y * 64;   // d block
  const int tid = threadIdx.x;
  {
    int r = tid >> 4, c = (tid & 15) * 4;
#pragma unroll
    for (int p = 0; p < 4; ++p) {
      float4 v = *(const float4*)(emb + (size_t)(db + r + p * 16) * VOCAB + vb + c);
      tile[c + 0][r + p * 16] = v.x;
      tile[c + 1][r + p * 16] = v.y;
      tile[c + 2][r + p * 16] = v.z;
      tile[c + 3][r + p * 16] = v.w;
    }
  }
  __syncthreads();
  {
    int v = tid >> 2, d0 = (tid & 3) * 16;
    unsigned short* op = (unsigned short*)embT + (size_t)(vb + v) * D_MODEL + db + d0;
    u16x8 o0, o1;
#pragma unroll
    for (int j = 0; j < 8; ++j) {
      o0[j] = f2bf(tile[v][d0 + j]);
      o1[j] = f2bf(tile[v][d0 + 8 + j]);
    }
    *(u16x8*)op = o0;
    *(u16x8*)(op + 8) = o1;
  }
}

// ---------- embedding gather (coalesced) + positional encoding ----------
__global__ __launch_bounds__(256) void embed_kernel(
    const int* __restrict__ tokens, const __hip_bfloat16* __restrict__ embT,
    float* __restrict__ x)
{
  int bs = blockIdx.x;
  int s = bs & (SEQ - 1);
  int tok = tokens[bs];
  const unsigned short* ep = (const unsigned short*)embT + (size_t)tok * D_MODEL;
  for (int d = threadIdx.x; d < D_MODEL; d += 256) {
    float ev = bf2f(ep[d]);
    int dpair = d & ~1;
    float expo = (float)dpair * (1.0f / (float)D_MODEL);
    float ang = (float)s / powf(10000.0f, expo);
    float pe = (d & 1) ? cosf(ang) : sinf(ang);
    x[(size_t)bs * D_MODEL + d] = ev + pe;
  }
}

// ---------- layer norm (fp32 in, bf16 out) ----------
__global__ __launch_bounds__(256) void ln_kernel(
    const float* __restrict__ in, __hip_bfloat16* __restrict__ out,
    const float* __restrict__ g, const float* __restrict__ bb)
{
  __shared__ float sbuf[8];
  size_t row = blockIdx.x;
  const float* rp = in + row * D_MODEL;
  int t = threadIdx.x;
  float x0 = rp[t], x1 = rp[t + 256], x2 = rp[t + 512];
  float mean = block_reduce_sum(x0 + x1 + x2, sbuf) * (1.0f / (float)D_MODEL);
  float d0 = x0 - mean, d1 = x1 - mean, d2 = x2 - mean;
  float var = block_reduce_sum(d0*d0 + d1*d1 + d2*d2, sbuf) * (1.0f / (float)D_MODEL);
  float rstd = rsqrtf(var + LN_EPS);
  __hip_bfloat16* op = out + row * D_MODEL;
  op[t]       = __float2bfloat16(g[t]       * (d0 * rstd) + bb[t]);
  op[t + 256] = __float2bfloat16(g[t + 256] * (d1 * rstd) + bb[t + 256]);
  op[t + 512] = __float2bfloat16(g[t + 512] * (d2 * rstd) + bb[t + 512]);
}

// final LN on x[b, predict_idx, :] (fp32 out)
__global__ __launch_bounds__(256) void final_ln_kernel(
    const float* __restrict__ x, const int* __restrict__ pidx,
    const float* __restrict__ g, const float* __restrict__ bb,
    float* __restrict__ out)
{
  __shared__ float sbuf[8];
  int p = pidx[0];
  const float* rp = x + ((size_t)blockIdx.x * SEQ + p) * D_MODEL;
  int t = threadIdx.x;
  float x0 = rp[t], x1 = rp[t + 256], x2 = rp[t + 512];
  float mean = block_reduce_sum(x0 + x1 + x2, sbuf) * (1.0f / (float)D_MODEL);
  float d0 = x0 - mean, d1 = x1 - mean, d2 = x2 - mean;
  float var = block_reduce_sum(d0*d0 + d1*d1 + d2*d2, sbuf) * (1.0f / (float)D_MODEL);
  float rstd = rsqrtf(var + LN_EPS);
  float* op = out + (size_t)blockIdx.x * D_MODEL;
  op[t]       = g[t]       * (d0 * rstd) + bb[t];
  op[t + 256] = g[t + 256] * (d1 * rstd) + bb[t + 256];
  op[t + 512] = g[t + 512] * (d2 * rstd) + bb[t + 512];
}

// XCD-chunked bijective block swizzle (nwg % 8 == 0 for all our grids)
__device__ __forceinline__ int2 xcd_tile(int gx, int gy) {
  int flat = blockIdx.y * gx + blockIdx.x;
  int cpx = (gx * gy) >> 3;
  int logical = (flat & 7) * cpx + (flat >> 3);
  return make_int2(logical % gx, logical / gx);   // (col, row)
}

#define WAITV4() asm volatile("s_waitcnt vmcnt(4)" ::: "memory")
#define WAITV2() asm volatile("s_waitcnt vmcnt(2)" ::: "memory")
#define WAITV0() asm volatile("s_waitcnt vmcnt(0)" ::: "memory")
#define MEMFENCE() asm volatile("" ::: "memory")

// ---------- bf16 MFMA NT GEMM, ring-3 counted-vmcnt pipeline ----------
// 128x128 tile, BK=32, 3 LDS buffers (48 KB total), depth-2 prefetch.
// LDS layout [row][4 slots of 8 bf16], slot = chunk ^ ((row>>1)&3) -> 2-way
// (free) bank aliasing on ds_read_b128 fragments; staged with pre-swizzled
// global source (rule #21). Counted vmcnt keeps 2 stages in flight across
// raw s_barrier (T3+T4). mode: 0 fp32, 1 fp32+resid, 2 bf16, 3 bf16+gelu.
__global__ __launch_bounds__(256) void gemm_bf16_kernel(
    const __hip_bfloat16* __restrict__ A, const __hip_bfloat16* __restrict__ W,
    void* __restrict__ Cv, const float* __restrict__ resid,
    int N, int K, int mode)
{
  __shared__ __align__(16) unsigned short As[3][128 * 32];   // 24 KB
  __shared__ __align__(16) unsigned short Bs[3][128 * 32];   // 24 KB
  const unsigned short* Au = (const unsigned short*)A;
  const unsigned short* Wu = (const unsigned short*)W;
  const int tid = threadIdx.x;
  const int wv = tid >> 6, ln = tid & 63;
  const int l15 = ln & 15, l4 = ln >> 4;
  int2 tc = xcd_tile(N >> 7, gridDim.y);
  const int bm = tc.y * 128, bn = tc.x * 128;
  const int wr = wv >> 1, wc = wv & 1;

  // staging: wave wv, lane ln -> LDS row p*64 + wv*16 + ln/4, slot ln&3;
  // source chunk = slot ^ f(row), f(row)=(row>>1)&3 = (ln>>3)&3 here.
  const int lrow = wv * 16 + (ln >> 2);
  const int schunk = (ln & 3) ^ ((ln >> 3) & 3);
  const size_t gA0 = (size_t)(bm + lrow) * K + schunk * 8;
  const size_t gA1 = (size_t)(bm + 64 + lrow) * K + schunk * 8;
  const size_t gB0 = (size_t)(bn + lrow) * K + schunk * 8;
  const size_t gB1 = (size_t)(bn + 64 + lrow) * K + schunk * 8;
  const int ldsb = wv * 512;   // + 2048 for second 64-row half

#define STAGE128(buf, k0)                                                          \
  {                                                                                \
    __builtin_amdgcn_global_load_lds((g_u32*)(Au + gA0 + (k0)), (l_u32*)(As[buf] + ldsb), 16, 0, 0);        \
    __builtin_amdgcn_global_load_lds((g_u32*)(Au + gA1 + (k0)), (l_u32*)(As[buf] + 2048 + ldsb), 16, 0, 0); \
    __builtin_amdgcn_global_load_lds((g_u32*)(Wu + gB0 + (k0)), (l_u32*)(Bs[buf] + ldsb), 16, 0, 0);        \
    __builtin_amdgcn_global_load_lds((g_u32*)(Wu + gB1 + (k0)), (l_u32*)(Bs[buf] + 2048 + ldsb), 16, 0, 0); \
  }

  const int rslot = (l4 ^ ((l15 >> 1) & 3)) * 8;

#define COMPUTE128(buf)                                                            \
  {                                                                                \
    bf16x8 af[4], bfr[4];                                                          \
    _Pragma("unroll")                                                              \
    for (int m = 0; m < 4; ++m)                                                    \
      af[m] = *(const bf16x8*)(As[buf] + (wr * 64 + m * 16 + l15) * 32 + rslot);   \
    _Pragma("unroll")                                                              \
    for (int n = 0; n < 4; ++n)                                                    \
      bfr[n] = *(const bf16x8*)(Bs[buf] + (wc * 64 + n * 16 + l15) * 32 + rslot);  \
    __builtin_amdgcn_s_setprio(1);                                                 \
    _Pragma("unroll")                                                              \
    for (int m = 0; m < 4; ++m)                                                    \
      _Pragma("unroll")                                                            \
      for (int n = 0; n < 4; ++n)                                                  \
        acc[m][n] = __builtin_amdgcn_mfma_f32_16x16x32_bf16(af[m], bfr[n], acc[m][n], 0, 0, 0); \
    __builtin_amdgcn_s_setprio(0);                                                 \
  }

  f32x4 acc[4][4];
#pragma unroll
  for (int m = 0; m < 4; ++m)
#pragma unroll
    for (int n = 0; n < 4; ++n) acc[m][n] = (f32x4){0.f, 0.f, 0.f, 0.f};

  const int NT = K >> 5;           // >= 24 for all our K
  STAGE128(0, 0);
  STAGE128(1, 32);
  int cur = 0;
  for (int t = 0; t < NT - 1; ++t) {
    WAITV4();                       // own tile-t loads landed (t+1 in flight)
    __builtin_amdgcn_s_barrier();   // all waves certified tile t
    MEMFENCE();
    if (t + 2 < NT) {
      int nxt = cur + 2; if (nxt >= 3) nxt -= 3;
      STAGE128(nxt, (t + 2) << 5);  // overwrites tile t-1's buffer: safe
    }
    COMPUTE128(cur);
    cur = (cur == 2) ? 0 : cur + 1;
  }
  WAITV0();
  __builtin_amdgcn_s_barrier();
  MEMFENCE();
  COMPUTE128(cur);

  float* Cf = (float*)Cv;
  __hip_bfloat16* Cb = (__hip_bfloat16*)Cv;
#pragma unroll
  for (int m = 0; m < 4; ++m) {
#pragma unroll
    for (int n = 0; n < 4; ++n) {
#pragma unroll
      for (int r = 0; r < 4; ++r) {
        int row = bm + wr * 64 + m * 16 + l4 * 4 + r;
        int col = bn + wc * 64 + n * 16 + l15;
        size_t off = (size_t)row * N + col;
        float v = acc[m][n][r];
        if (mode == 0)      Cf[off] = v;
        else if (mode == 1) Cf[off] = v + resid[off];
        else if (mode == 2) Cb[off] = __float2bfloat16(v);
        else                Cb[off] = __float2bfloat16(gelu_f(v));
      }
    }
  }
#undef STAGE128
#undef COMPUTE128
}

// ---------- 64x64-tile variant (N=768 GEMMs: wo, fc2), same pipeline ----------
// 3 x 8 KB LDS -> 6 blocks/CU.
__global__ __launch_bounds__(256) void gemm64_bf16_kernel(
    const __hip_bfloat16* __restrict__ A, const __hip_bfloat16* __restrict__ W,
    void* __restrict__ Cv, const float* __restrict__ resid,
    int N, int K, int mode)
{
  __shared__ __align__(16) unsigned short As[3][64 * 32];   // 12 KB
  __shared__ __align__(16) unsigned short Bs[3][64 * 32];   // 12 KB
  const unsigned short* Au = (const unsigned short*)A;
  const unsigned short* Wu = (const unsigned short*)W;
  const int tid = threadIdx.x;
  const int wv = tid >> 6, ln = tid & 63;
  const int l15 = ln & 15, l4 = ln >> 4;
  int2 tc = xcd_tile(N >> 6, gridDim.y);
  const int bm = tc.y * 64, bn = tc.x * 64;
  const int wr = wv >> 1, wc = wv & 1;

  const int lrow = wv * 16 + (ln >> 2);
  const int schunk = (ln & 3) ^ ((ln >> 3) & 3);
  const size_t gA0 = (size_t)(bm + lrow) * K + schunk * 8;
  const size_t gB0 = (size_t)(bn + lrow) * K + schunk * 8;
  const int ldsb = wv * 512;

#define STAGE64(buf, k0)                                                           \
  {                                                                                \
    __builtin_amdgcn_global_load_lds((g_u32*)(Au + gA0 + (k0)), (l_u32*)(As[buf] + ldsb), 16, 0, 0); \
    __builtin_amdgcn_global_load_lds((g_u32*)(Wu + gB0 + (k0)), (l_u32*)(Bs[buf] + ldsb), 16, 0, 0); \
  }

  const int rslot = (l4 ^ ((l15 >> 1) & 3)) * 8;

#define COMPUTE64(buf)                                                             \
  {                                                                                \
    bf16x8 af[2], bfr[2];                                                          \
    _Pragma("unroll")                                                              \
    for (int m = 0; m < 2; ++m)                                                    \
      af[m] = *(const bf16x8*)(As[buf] + (wr * 32 + m * 16 + l15) * 32 + rslot);   \
    _Pragma("unroll")                                                              \
    for (int n = 0; n < 2; ++n)                                                    \
      bfr[n] = *(const bf16x8*)(Bs[buf] + (wc * 32 + n * 16 + l15) * 32 + rslot);  \
    __builtin_amdgcn_s_setprio(1);                                                 \
    _Pragma("unroll")                                                              \
    for (int m = 0; m < 2; ++m)                                                    \
      _Pragma("unroll")                                                            \
      for (int n = 0; n < 2; ++n)                                                  \
        acc[m][n] = __builtin_amdgcn_mfma_f32_16x16x32_bf16(af[m], bfr[n], acc[m][n], 0, 0, 0); \
    __builtin_amdgcn_s_setprio(0);                                                 \
  }

  f32x4 acc[2][2];
#pragma unroll
  for (int m = 0; m < 2; ++m)
#pragma unroll
    for (int n = 0; n < 2; ++n) acc[m][n] = (f32x4){0.f, 0.f, 0.f, 0.f};

  const int NT = K >> 5;
  STAGE64(0, 0);
  STAGE64(1, 32);
  int cur = 0;
  for (int t = 0; t < NT - 1; ++t) {
    WAITV2();
    __builtin_amdgcn_s_barrier();
    MEMFENCE();
    if (t + 2 < NT) {
      int nxt = cur + 2; if (nxt >= 3) nxt -= 3;
      STAGE64(nxt, (t + 2) << 5);
    }
    COMPUTE64(cur);
    cur = (cur == 2) ? 0 : cur + 1;
  }
  WAITV0();
  __builtin_amdgcn_s_barrier();
  MEMFENCE();
  COMPUTE64(cur);

  float* Cf = (float*)Cv;
  __hip_bfloat16* Cb = (__hip_bfloat16*)Cv;
#pragma unroll
  for (int m = 0; m < 2; ++m) {
#pragma unroll
    for (int n = 0; n < 2; ++n) {
#pragma unroll
      for (int r = 0; r < 4; ++r) {
        int row = bm + wr * 32 + m * 16 + l4 * 4 + r;
        int col = bn + wc * 32 + n * 16 + l15;
        size_t off = (size_t)row * N + col;
        float v = acc[m][n][r];
        if (mode == 0)      Cf[off] = v;
        else if (mode == 1) Cf[off] = v + resid[off];
        else if (mode == 2) Cb[off] = __float2bfloat16(v);
        else                Cb[off] = __float2bfloat16(gelu_f(v));
      }
    }
  }
#undef STAGE64
#undef COMPUTE64
}

// ---------- MFMA flash attention (bf16 MFMA, fp32 softmax/accum) ----------
__global__ __launch_bounds__(256) void flash_attn_kernel(
    const __hip_bfloat16* __restrict__ qkv_, __hip_bfloat16* __restrict__ attn_)
{
  const unsigned short* qkv = (const unsigned short*)qkv_;
  unsigned short* attn = (unsigned short*)attn_;
  const int s0 = blockIdx.x * 64;
  const int h  = blockIdx.y;
  const int b  = blockIdx.z;
  const int tid = threadIdx.x;
  const int wq = tid >> 6, ln = tid & 63;
  const int l15 = ln & 15, l4 = ln >> 4;

  __shared__ unsigned short Ks[64 * 64];      // 8 KB
  __shared__ unsigned short Vt[64 * 64];      // 8 KB (transposed: [e][t])
  __shared__ unsigned short Pw[4][16 * 64];   // 8 KB (per-wave P)

  bf16x8 qf[2];
  {
    const size_t qbase = (size_t)(b * SEQ + s0 + wq * 16 + l15) * 2304 + h * 64;
#pragma unroll
    for (int ks = 0; ks < 2; ++ks) {
      u16x8 raw = *(const u16x8*)(qkv + qbase + ks * 32 + l4 * 8);
      bf16x8 q;
#pragma unroll
      for (int j = 0; j < 8; ++j) q[j] = (short)f2bf(bf2f(raw[j]) * 0.125f);
      qf[ks] = q;
    }
  }

  float mrow[4], lrow[4];
  f32x4 o[4];
#pragma unroll
  for (int r = 0; r < 4; ++r) { mrow[r] = -1e30f; lrow[r] = 0.f; }
#pragma unroll
  for (int n = 0; n < 4; ++n) o[n] = (f32x4){0.f, 0.f, 0.f, 0.f};

  for (int t0 = 0; t0 <= s0; t0 += 64) {
    __syncthreads();

#pragma unroll
    for (int r = 0; r < 2; ++r) {
      int o128 = wq * 2 + r;
      int t = o128 * 8 + (ln >> 3);
      int db = (ln & 7) ^ (ln >> 3);
      const unsigned short* gk =
          qkv + (size_t)(b * SEQ + t0 + t) * 2304 + 768 + h * 64 + db * 8;
      __builtin_amdgcn_global_load_lds((g_u32*)gk, (l_u32*)(Ks + o128 * 512), 16, 0, 0);
    }

    {
      int vt = tid >> 2, ec = (tid & 3) * 16;
      const unsigned short* gv =
          qkv + (size_t)(b * SEQ + t0 + vt) * 2304 + 1536 + h * 64 + ec;
      u16x8 v0 = *(const u16x8*)gv;
      u16x8 v1 = *(const u16x8*)(gv + 8);
      int tb = vt >> 3, tr = vt & 7;
#pragma unroll
      for (int j = 0; j < 8; ++j) {
        int e0 = ec + j, e1 = ec + 8 + j;
        Vt[e0 * 64 + ((tb ^ (e0 & 7)) << 3) + tr] = (unsigned short)v0[j];
        Vt[e1 * 64 + ((tb ^ (e1 & 7)) << 3) + tr] = (unsigned short)v1[j];
      }
    }
    __syncthreads();

    f32x4 sf[4];
#pragma unroll
    for (int n = 0; n < 4; ++n) sf[n] = (f32x4){0.f, 0.f, 0.f, 0.f};
#pragma unroll
    for (int ks = 0; ks < 2; ++ks) {
#pragma unroll
      for (int n = 0; n < 4; ++n) {
        int t = n * 16 + l15;
        bf16x8 kf = *(const bf16x8*)(Ks + t * 64 + (((ks * 4 + l4) ^ (t & 7)) << 3));
        sf[n] = __builtin_amdgcn_mfma_f32_16x16x32_bf16(qf[ks], kf, sf[n], 0, 0, 0);
      }
    }

    if (t0 == s0) {
#pragma unroll
      for (int n = 0; n < 4; ++n) {
        int t = n * 16 + l15;
#pragma unroll
        for (int r = 0; r < 4; ++r) {
          int q = wq * 16 + l4 * 4 + r;
          if (t > q) sf[n][r] = NEGV;
        }
      }
    }

    float pbuf[4][4];
#pragma unroll
    for (int r = 0; r < 4; ++r) {
      float rmax = fmaxf(fmaxf(sf[0][r], sf[1][r]), fmaxf(sf[2][r], sf[3][r]));
#pragma unroll
      for (int m = 1; m < 16; m <<= 1) rmax = fmaxf(rmax, __shfl_xor(rmax, m, 64));
      float mnew = fmaxf(mrow[r], rmax);
      float alpha = __expf(mrow[r] - mnew);
      float part = 0.f;
#pragma unroll
      for (int n = 0; n < 4; ++n) {
        float p = __expf(sf[n][r] - mnew);
        pbuf[n][r] = p;
        part += p;
      }
#pragma unroll
      for (int m = 1; m < 16; m <<= 1) part += __shfl_xor(part, m, 64);
      lrow[r] = lrow[r] * alpha + part;
      mrow[r] = mnew;
#pragma unroll
      for (int n = 0; n < 4; ++n) o[n][r] *= alpha;
    }

    unsigned short* Pme = Pw[wq];
#pragma unroll
    for (int n = 0; n < 4; ++n) {
      int tb = (n * 16 + l15) >> 3, tr = l15 & 7;
#pragma unroll
      for (int r = 0; r < 4; ++r) {
        int q = l4 * 4 + r;
        Pme[q * 64 + ((tb ^ (q & 7)) << 3) + tr] = f2bf(pbuf[n][r]);
      }
    }

#pragma unroll
    for (int ks = 0; ks < 2; ++ks) {
      bf16x8 pf = *(const bf16x8*)(Pme + l15 * 64 + (((ks * 4 + l4) ^ (l15 & 7)) << 3));
#pragma unroll
      for (int n = 0; n < 4; ++n) {
        int e = n * 16 + l15;
        bf16x8 vf = *(const bf16x8*)(Vt + e * 64 + (((ks * 4 + l4) ^ (e & 7)) << 3));
        o[n] = __builtin_amdgcn_mfma_f32_16x16x32_bf16(pf, vf, o[n], 0, 0, 0);
      }
    }
  }

#pragma unroll
  for (int r = 0; r < 4; ++r) {
    float inv = 1.0f / lrow[r];
    size_t base = (size_t)(b * SEQ + s0 + wq * 16 + l4 * 4 + r) * D_MODEL + h * 64;
#pragma unroll
    for (int n = 0; n < 4; ++n)
      attn[base + n * 16 + l15] = f2bf(o[n][r] * inv);
  }
}

// ---------- logits: out[b,v] = dot(normed[b,:], unembed[v,:]) ----------
__global__ __launch_bounds__(256) void logits_kernel(
    const float* __restrict__ normed, const float* __restrict__ unemb,
    float* __restrict__ out)
{
  __shared__ __align__(16) float ns[BATCH][D_MODEL];
  for (int d = threadIdx.x; d < BATCH * D_MODEL; d += 256)
    ((float*)ns)[d] = normed[d];
  __syncthreads();
  int g = threadIdx.x >> 4, li = threadIdx.x & 15;
  int v = blockIdx.x * 16 + g;
  const float* up = unemb + (size_t)v * D_MODEL;
  float s0 = 0.f, s1 = 0.f, s2 = 0.f, s3 = 0.f;
#pragma unroll
  for (int it = 0; it < D_MODEL / 64; ++it) {
    int e = it * 64 + li * 4;
    float4 u = *(const float4*)(up + e);
    float4 n0 = *(const float4*)&ns[0][e];
    float4 n1 = *(const float4*)&ns[1][e];
    float4 n2 = *(const float4*)&ns[2][e];
    float4 n3 = *(const float4*)&ns[3][e];
    s0 += u.x*n0.x + u.y*n0.y + u.z*n0.z + u.w*n0.w;
    s1 += u.x*n1.x + u.y*n1.y + u.z*n1.z + u.w*n1.w;
    s2 += u.x*n2.x + u.y*n2.y + u.z*n2.z + u.w*n2.w;
    s3 += u.x*n3.x + u.y*n3.y + u.z*n3.z + u.w*n3.w;
  }
#pragma unroll
  for (int msk = 1; msk < 16; msk <<= 1) {
    s0 += __shfl_xor(s0, msk, 64); s1 += __shfl_xor(s1, msk, 64);
    s2 += __shfl_xor(s2, msk, 64); s3 += __shfl_xor(s3, msk, 64);
  }
  if (li == 0) {
    out[(size_t)0 * VOCAB + v] = s0;
    out[(size_t)1 * VOCAB + v] = s1;
    out[(size_t)2 * VOCAB + v] = s2;
    out[(size_t)3 * VOCAB + v] = s3;
  }
}

// ---------- launcher ----------
extern "C" void kernel_launch(void* const* d_in, const int* in_sizes, int n_in,
                              void* d_out, int out_size, void* d_ws, size_t ws_size,
                              hipStream_t stream) {
  const int*   tokens = (const int*)d_in[0];
  const int*   pidx   = (const int*)d_in[1];
  const float* emb    = (const float*)d_in[2];
  const float* ln1_g  = (const float*)d_in[3];
  const float* ln1_b  = (const float*)d_in[4];
  const float* wq     = (const float*)d_in[5];
  const float* wk     = (const float*)d_in[6];
  const float* wv     = (const float*)d_in[7];
  const float* wo     = (const float*)d_in[8];
  const float* ln2_g  = (const float*)d_in[9];
  const float* ln2_b  = (const float*)d_in[10];
  const float* fc1    = (const float*)d_in[11];
  const float* fc2    = (const float*)d_in[12];
  const float* lnf_g  = (const float*)d_in[13];
  const float* lnf_b  = (const float*)d_in[14];
  const float* unemb  = (const float*)d_in[15];
  float* out = (float*)d_out;

  char* wp = (char*)d_ws;
  const size_t NX = (size_t)NROWS * D_MODEL;        // 3,145,728
  float* x = (float*)wp;                  wp += NX * 4;
  float* normed = (float*)wp;             wp += BATCH * D_MODEL * 4;
  __hip_bfloat16* h    = (__hip_bfloat16*)wp; wp += NX * 2;
  __hip_bfloat16* attn = (__hip_bfloat16*)wp; wp += NX * 2;
  __hip_bfloat16* qkvb = (__hip_bfloat16*)wp; wp += (size_t)NROWS * 2304 * 2;
  __hip_bfloat16* ffn  = (__hip_bfloat16*)wp; wp += (size_t)NROWS * D_FF * 2;
  __hip_bfloat16* wqkvb = (__hip_bfloat16*)wp; wp += (size_t)N_LAYERS * 2304 * D_MODEL * 2;
  __hip_bfloat16* wob   = (__hip_bfloat16*)wp; wp += (size_t)N_LAYERS * D_MODEL * D_MODEL * 2;
  __hip_bfloat16* fc1b  = (__hip_bfloat16*)wp; wp += (size_t)N_LAYERS * D_FF * D_MODEL * 2;
  __hip_bfloat16* fc2b  = (__hip_bfloat16*)wp; wp += (size_t)N_LAYERS * D_MODEL * D_FF * 2;

  // embT [VOCAB][D_MODEL] bf16 (49.2 MB) aliased onto attn..ffn scratch
  __hip_bfloat16* embT = attn;

  const int WMAT = D_MODEL * D_MODEL;     // 589824
  const int FMAT = D_FF * D_MODEL;        // 2359296

  transpose_emb_kernel<<<dim3(VOCAB / 64, D_MODEL / 64), 256, 0, stream>>>(emb, embT);
  embed_kernel<<<NROWS, 256, 0, stream>>>(tokens, embT, x);

  qkv_pack_kernel<<<N_LAYERS * 3 * WMAT / 2048, 256, 0, stream>>>(wq, wk, wv, wqkvb);
  convert_kernel<<<N_LAYERS * WMAT / 2048, 256, 0, stream>>>(wo,  wob,  N_LAYERS * WMAT);
  convert_kernel<<<N_LAYERS * FMAT / 2048, 256, 0, stream>>>(fc1, fc1b, N_LAYERS * FMAT);
  convert_kernel<<<N_LAYERS * FMAT / 2048, 256, 0, stream>>>(fc2, fc2b, N_LAYERS * FMAT);

  for (int l = 0; l < N_LAYERS; ++l) {
    const size_t qofs = (size_t)l * 3 * WMAT;
    const size_t wofs = (size_t)l * WMAT;
    const size_t fofs = (size_t)l * FMAT;

    ln_kernel<<<NROWS, 256, 0, stream>>>(x, h, ln1_g + l * D_MODEL, ln1_b + l * D_MODEL);

    // fused QKV: [4096 x 2304] bf16 out
    gemm_bf16_kernel<<<dim3(2304 / 128, NROWS / 128), 256, 0, stream>>>(
        h, wqkvb + qofs, qkvb, nullptr, 2304, D_MODEL, 2);

    flash_attn_kernel<<<dim3(SEQ / 64, N_HEADS, BATCH), 256, 0, stream>>>(qkvb, attn);

    // x += attn @ wo^T  (64-tile: 768 blocks)
    gemm64_bf16_kernel<<<dim3(D_MODEL / 64, NROWS / 64), 256, 0, stream>>>(
        attn, wob + wofs, x, x, D_MODEL, D_MODEL, 1);

    ln_kernel<<<NROWS, 256, 0, stream>>>(x, h, ln2_g + l * D_MODEL, ln2_b + l * D_MODEL);

    // ffn = gelu(h @ fc1^T) (bf16)
    gemm_bf16_kernel<<<dim3(D_FF / 128, NROWS / 128), 256, 0, stream>>>(
        h, fc1b + fofs, ffn, nullptr, D_FF, D_MODEL, 3);

    // x += ffn @ fc2^T  (64-tile: 768 blocks)
    gemm64_bf16_kernel<<<dim3(D_MODEL / 64, NROWS / 64), 256, 0, stream>>>(
        ffn, fc2b + fofs, x, x, D_MODEL, D_FF, 1);
  }

  final_ln_kernel<<<BATCH, 256, 0, stream>>>(x, pidx, lnf_g, lnf_b, normed);
  logits_kernel<<<VOCAB / 16, 256, 0, stream>>>(normed, unemb, out);
}

// Round 7
// 871.453 us; speedup vs baseline: 6.2987x; 1.0620x over previous
//
#include <hip/hip_runtime.h>
#include <hip/hip_bf16.h>

#define D_MODEL 768
#define N_HEADS 12
#define D_HEAD  64
#define D_FF    3072
#define N_LAYERS 4
#define VOCAB   32000
#define BATCH   4
#define SEQ     1024
#define NROWS   (BATCH*SEQ)      // 4096
#define NEGV    -1000000000.0f
#define LN_EPS  1e-5f

typedef __attribute__((ext_vector_type(8))) short bf16x8;
typedef __attribute__((ext_vector_type(4))) float f32x4;
typedef __attribute__((ext_vector_type(8))) unsigned short u16x8;
typedef __attribute__((ext_vector_type(4))) unsigned short u16x4;

typedef __attribute__((address_space(1))) const unsigned int g_u32;
typedef __attribute__((address_space(3))) unsigned int l_u32;

__device__ __forceinline__ float bf2f(unsigned short u) {
  return __uint_as_float(((unsigned int)u) << 16);
}
__device__ __forceinline__ unsigned short f2bf(float f) {
  __hip_bfloat16 h = __float2bfloat16(f);
  return *reinterpret_cast<unsigned short*>(&h);
}

__device__ __forceinline__ float block_reduce_sum(float v, float* sbuf) {
#pragma unroll
  for (int off = 32; off > 0; off >>= 1) v += __shfl_down(v, off, 64);
  int lane = threadIdx.x & 63, wid = threadIdx.x >> 6;
  if (lane == 0) sbuf[wid] = v;
  __syncthreads();
  if (threadIdx.x == 0) sbuf[4] = sbuf[0] + sbuf[1] + sbuf[2] + sbuf[3];
  __syncthreads();
  return sbuf[4];
}

__device__ __forceinline__ float gelu_f(float x) {
  float c = x + 0.044715f * x * x * x;
  return x * (0.5f * (1.0f + tanhf(0.7978845608f * c)));
}

// ---------- fp32 -> bf16 weight conversion (8 elems / thread) ----------
__global__ __launch_bounds__(256) void convert_kernel(
    const float* __restrict__ src, __hip_bfloat16* __restrict__ dst, int n)
{
  int i = (blockIdx.x * 256 + threadIdx.x) * 8;
  if (i >= n) return;
  float4 a = *(const float4*)(src + i);
  float4 b = *(const float4*)(src + i + 4);
  struct bf8 { __hip_bfloat16 h[8]; } r;
  r.h[0] = __float2bfloat16(a.x); r.h[1] = __float2bfloat16(a.y);
  r.h[2] = __float2bfloat16(a.z); r.h[3] = __float2bfloat16(a.w);
  r.h[4] = __float2bfloat16(b.x); r.h[5] = __float2bfloat16(b.y);
  r.h[6] = __float2bfloat16(b.z); r.h[7] = __float2bfloat16(b.w);
  *(bf8*)(dst + i) = r;
}

// pack wq|wk|wv of all layers into wqkvb [l][3*WMAT] in one launch
__global__ __launch_bounds__(256) void qkv_pack_kernel(
    const float* __restrict__ wq, const float* __restrict__ wk,
    const float* __restrict__ wv, __hip_bfloat16* __restrict__ dst)
{
  const int WMAT = D_MODEL * D_MODEL;
  long long i = (long long)(blockIdx.x * 256 + threadIdx.x) * 8;
  long long l = i / (3LL * WMAT);
  long long rem = i - l * 3LL * WMAT;
  int which = (int)(rem / WMAT);
  long long off = rem - (long long)which * WMAT;
  const float* src = (which == 0 ? wq : which == 1 ? wk : wv) + l * WMAT + off;
  float4 a = *(const float4*)src;
  float4 b = *(const float4*)(src + 4);
  struct bf8 { __hip_bfloat16 h[8]; } r;
  r.h[0] = __float2bfloat16(a.x); r.h[1] = __float2bfloat16(a.y);
  r.h[2] = __float2bfloat16(a.z); r.h[3] = __float2bfloat16(a.w);
  r.h[4] = __float2bfloat16(b.x); r.h[5] = __float2bfloat16(b.y);
  r.h[6] = __float2bfloat16(b.z); r.h[7] = __float2bfloat16(b.w);
  *(bf8*)(dst + i) = r;
}

// ---------- embedding transpose: emb [768][32000] f32 -> embT [32000][768] bf16 ----------
__global__ __launch_bounds__(256) void transpose_emb_kernel(
    const float* __restrict__ emb, __hip_bfloat16* __restrict__ embT)
{
  __shared__ float tile[64][65];
  const int vb = blockIdx.x * 64;   // vocab block
  const int db = blockIdx.y * 64;   // d block
  const int tid = threadIdx.x;
  {
    int r = tid >> 4, c = (tid & 15) * 4;
#pragma unroll
    for (int p = 0; p < 4; ++p) {
      float4 v = *(const float4*)(emb + (size_t)(db + r + p * 16) * VOCAB + vb + c);
      tile[c + 0][r + p * 16] = v.x;
      tile[c + 1][r + p * 16] = v.y;
      tile[c + 2][r + p * 16] = v.z;
      tile[c + 3][r + p * 16] = v.w;
    }
  }
  __syncthreads();
  {
    int v = tid >> 2, d0 = (tid & 3) * 16;
    unsigned short* op = (unsigned short*)embT + (size_t)(vb + v) * D_MODEL + db + d0;
    u16x8 o0, o1;
#pragma unroll
    for (int j = 0; j < 8; ++j) {
      o0[j] = f2bf(tile[v][d0 + j]);
      o1[j] = f2bf(tile[v][d0 + 8 + j]);
    }
    *(u16x8*)op = o0;
    *(u16x8*)(op + 8) = o1;
  }
}

// ---------- embedding gather (coalesced) + positional encoding ----------
__global__ __launch_bounds__(256) void embed_kernel(
    const int* __restrict__ tokens, const __hip_bfloat16* __restrict__ embT,
    float* __restrict__ x)
{
  int bs = blockIdx.x;
  int s = bs & (SEQ - 1);
  int tok = tokens[bs];
  const unsigned short* ep = (const unsigned short*)embT + (size_t)tok * D_MODEL;
  for (int d = threadIdx.x; d < D_MODEL; d += 256) {
    float ev = bf2f(ep[d]);
    int dpair = d & ~1;
    float expo = (float)dpair * (1.0f / (float)D_MODEL);
    float ang = (float)s / powf(10000.0f, expo);
    float pe = (d & 1) ? cosf(ang) : sinf(ang);
    x[(size_t)bs * D_MODEL + d] = ev + pe;
  }
}

// ---------- layer norm (fp32 in, bf16 out) ----------
__global__ __launch_bounds__(256) void ln_kernel(
    const float* __restrict__ in, __hip_bfloat16* __restrict__ out,
    const float* __restrict__ g, const float* __restrict__ bb)
{
  __shared__ float sbuf[8];
  size_t row = blockIdx.x;
  const float* rp = in + row * D_MODEL;
  int t = threadIdx.x;
  float x0 = rp[t], x1 = rp[t + 256], x2 = rp[t + 512];
  float mean = block_reduce_sum(x0 + x1 + x2, sbuf) * (1.0f / (float)D_MODEL);
  float d0 = x0 - mean, d1 = x1 - mean, d2 = x2 - mean;
  float var = block_reduce_sum(d0*d0 + d1*d1 + d2*d2, sbuf) * (1.0f / (float)D_MODEL);
  float rstd = rsqrtf(var + LN_EPS);
  __hip_bfloat16* op = out + row * D_MODEL;
  op[t]       = __float2bfloat16(g[t]       * (d0 * rstd) + bb[t]);
  op[t + 256] = __float2bfloat16(g[t + 256] * (d1 * rstd) + bb[t + 256]);
  op[t + 512] = __float2bfloat16(g[t + 512] * (d2 * rstd) + bb[t + 512]);
}

// final LN on x[b, predict_idx, :] (fp32 out)
__global__ __launch_bounds__(256) void final_ln_kernel(
    const float* __restrict__ x, const int* __restrict__ pidx,
    const float* __restrict__ g, const float* __restrict__ bb,
    float* __restrict__ out)
{
  __shared__ float sbuf[8];
  int p = pidx[0];
  const float* rp = x + ((size_t)blockIdx.x * SEQ + p) * D_MODEL;
  int t = threadIdx.x;
  float x0 = rp[t], x1 = rp[t + 256], x2 = rp[t + 512];
  float mean = block_reduce_sum(x0 + x1 + x2, sbuf) * (1.0f / (float)D_MODEL);
  float d0 = x0 - mean, d1 = x1 - mean, d2 = x2 - mean;
  float var = block_reduce_sum(d0*d0 + d1*d1 + d2*d2, sbuf) * (1.0f / (float)D_MODEL);
  float rstd = rsqrtf(var + LN_EPS);
  float* op = out + (size_t)blockIdx.x * D_MODEL;
  op[t]       = g[t]       * (d0 * rstd) + bb[t];
  op[t + 256] = g[t + 256] * (d1 * rstd) + bb[t + 256];
  op[t + 512] = g[t + 512] * (d2 * rstd) + bb[t + 512];
}

// XCD-chunked bijective block swizzle (nwg % 8 == 0 for all our grids)
__device__ __forceinline__ int2 xcd_tile(int gx, int gy) {
  int flat = blockIdx.y * gx + blockIdx.x;
  int cpx = (gx * gy) >> 3;
  int logical = (flat & 7) * cpx + (flat >> 3);
  return make_int2(logical % gx, logical / gx);   // (col, row)
}

#define WAITV4() asm volatile("s_waitcnt vmcnt(4)" ::: "memory")
#define WAITV2() asm volatile("s_waitcnt vmcnt(2)" ::: "memory")
#define WAITV0() asm volatile("s_waitcnt vmcnt(0)" ::: "memory")
#define MEMFENCE() asm volatile("" ::: "memory")

// ---------- bf16 MFMA NT GEMM, ring-3 counted-vmcnt pipeline ----------
// 128x128 tile, BK=32, 3 LDS buffers, depth-2 prefetch (proven round 6).
__global__ __launch_bounds__(256) void gemm_bf16_kernel(
    const __hip_bfloat16* __restrict__ A, const __hip_bfloat16* __restrict__ W,
    void* __restrict__ Cv, const float* __restrict__ resid,
    int N, int K, int mode)
{
  __shared__ __align__(16) unsigned short As[3][128 * 32];   // 24 KB
  __shared__ __align__(16) unsigned short Bs[3][128 * 32];   // 24 KB
  const unsigned short* Au = (const unsigned short*)A;
  const unsigned short* Wu = (const unsigned short*)W;
  const int tid = threadIdx.x;
  const int wv = tid >> 6, ln = tid & 63;
  const int l15 = ln & 15, l4 = ln >> 4;
  int2 tc = xcd_tile(N >> 7, gridDim.y);
  const int bm = tc.y * 128, bn = tc.x * 128;
  const int wr = wv >> 1, wc = wv & 1;

  const int lrow = wv * 16 + (ln >> 2);
  const int schunk = (ln & 3) ^ ((ln >> 3) & 3);
  const size_t gA0 = (size_t)(bm + lrow) * K + schunk * 8;
  const size_t gA1 = (size_t)(bm + 64 + lrow) * K + schunk * 8;
  const size_t gB0 = (size_t)(bn + lrow) * K + schunk * 8;
  const size_t gB1 = (size_t)(bn + 64 + lrow) * K + schunk * 8;
  const int ldsb = wv * 512;

#define STAGE128(buf, k0)                                                          \
  {                                                                                \
    __builtin_amdgcn_global_load_lds((g_u32*)(Au + gA0 + (k0)), (l_u32*)(As[buf] + ldsb), 16, 0, 0);        \
    __builtin_amdgcn_global_load_lds((g_u32*)(Au + gA1 + (k0)), (l_u32*)(As[buf] + 2048 + ldsb), 16, 0, 0); \
    __builtin_amdgcn_global_load_lds((g_u32*)(Wu + gB0 + (k0)), (l_u32*)(Bs[buf] + ldsb), 16, 0, 0);        \
    __builtin_amdgcn_global_load_lds((g_u32*)(Wu + gB1 + (k0)), (l_u32*)(Bs[buf] + 2048 + ldsb), 16, 0, 0); \
  }

  const int rslot = (l4 ^ ((l15 >> 1) & 3)) * 8;

#define COMPUTE128(buf)                                                            \
  {                                                                                \
    bf16x8 af[4], bfr[4];                                                          \
    _Pragma("unroll")                                                              \
    for (int m = 0; m < 4; ++m)                                                    \
      af[m] = *(const bf16x8*)(As[buf] + (wr * 64 + m * 16 + l15) * 32 + rslot);   \
    _Pragma("unroll")                                                              \
    for (int n = 0; n < 4; ++n)                                                    \
      bfr[n] = *(const bf16x8*)(Bs[buf] + (wc * 64 + n * 16 + l15) * 32 + rslot);  \
    __builtin_amdgcn_s_setprio(1);                                                 \
    _Pragma("unroll")                                                              \
    for (int m = 0; m < 4; ++m)                                                    \
      _Pragma("unroll")                                                            \
      for (int n = 0; n < 4; ++n)                                                  \
        acc[m][n] = __builtin_amdgcn_mfma_f32_16x16x32_bf16(af[m], bfr[n], acc[m][n], 0, 0, 0); \
    __builtin_amdgcn_s_setprio(0);                                                 \
  }

  f32x4 acc[4][4];
#pragma unroll
  for (int m = 0; m < 4; ++m)
#pragma unroll
    for (int n = 0; n < 4; ++n) acc[m][n] = (f32x4){0.f, 0.f, 0.f, 0.f};

  const int NT = K >> 5;
  STAGE128(0, 0);
  STAGE128(1, 32);
  int cur = 0;
  for (int t = 0; t < NT - 1; ++t) {
    WAITV4();
    __builtin_amdgcn_s_barrier();
    MEMFENCE();
    if (t + 2 < NT) {
      int nxt = cur + 2; if (nxt >= 3) nxt -= 3;
      STAGE128(nxt, (t + 2) << 5);
    }
    COMPUTE128(cur);
    cur = (cur == 2) ? 0 : cur + 1;
  }
  WAITV0();
  __builtin_amdgcn_s_barrier();
  MEMFENCE();
  COMPUTE128(cur);

  float* Cf = (float*)Cv;
  __hip_bfloat16* Cb = (__hip_bfloat16*)Cv;
#pragma unroll
  for (int m = 0; m < 4; ++m) {
#pragma unroll
    for (int n = 0; n < 4; ++n) {
#pragma unroll
      for (int r = 0; r < 4; ++r) {
        int row = bm + wr * 64 + m * 16 + l4 * 4 + r;
        int col = bn + wc * 64 + n * 16 + l15;
        size_t off = (size_t)row * N + col;
        float v = acc[m][n][r];
        if (mode == 0)      Cf[off] = v;
        else if (mode == 1) Cf[off] = v + resid[off];
        else if (mode == 2) Cb[off] = __float2bfloat16(v);
        else                Cb[off] = __float2bfloat16(gelu_f(v));
      }
    }
  }
#undef STAGE128
#undef COMPUTE128
}

// ---------- 64x64-tile variant (N=768 GEMMs: wo, fc2), ring-3 pipeline ----------
__global__ __launch_bounds__(256) void gemm64_bf16_kernel(
    const __hip_bfloat16* __restrict__ A, const __hip_bfloat16* __restrict__ W,
    void* __restrict__ Cv, const float* __restrict__ resid,
    int N, int K, int mode)
{
  __shared__ __align__(16) unsigned short As[3][64 * 32];   // 12 KB
  __shared__ __align__(16) unsigned short Bs[3][64 * 32];   // 12 KB
  const unsigned short* Au = (const unsigned short*)A;
  const unsigned short* Wu = (const unsigned short*)W;
  const int tid = threadIdx.x;
  const int wv = tid >> 6, ln = tid & 63;
  const int l15 = ln & 15, l4 = ln >> 4;
  int2 tc = xcd_tile(N >> 6, gridDim.y);
  const int bm = tc.y * 64, bn = tc.x * 64;
  const int wr = wv >> 1, wc = wv & 1;

  const int lrow = wv * 16 + (ln >> 2);
  const int schunk = (ln & 3) ^ ((ln >> 3) & 3);
  const size_t gA0 = (size_t)(bm + lrow) * K + schunk * 8;
  const size_t gB0 = (size_t)(bn + lrow) * K + schunk * 8;
  const int ldsb = wv * 512;

#define STAGE64(buf, k0)                                                           \
  {                                                                                \
    __builtin_amdgcn_global_load_lds((g_u32*)(Au + gA0 + (k0)), (l_u32*)(As[buf] + ldsb), 16, 0, 0); \
    __builtin_amdgcn_global_load_lds((g_u32*)(Wu + gB0 + (k0)), (l_u32*)(Bs[buf] + ldsb), 16, 0, 0); \
  }

  const int rslot = (l4 ^ ((l15 >> 1) & 3)) * 8;

#define COMPUTE64(buf)                                                             \
  {                                                                                \
    bf16x8 af[2], bfr[2];                                                          \
    _Pragma("unroll")                                                              \
    for (int m = 0; m < 2; ++m)                                                    \
      af[m] = *(const bf16x8*)(As[buf] + (wr * 32 + m * 16 + l15) * 32 + rslot);   \
    _Pragma("unroll")                                                              \
    for (int n = 0; n < 2; ++n)                                                    \
      bfr[n] = *(const bf16x8*)(Bs[buf] + (wc * 32 + n * 16 + l15) * 32 + rslot);  \
    __builtin_amdgcn_s_setprio(1);                                                 \
    _Pragma("unroll")                                                              \
    for (int m = 0; m < 2; ++m)                                                    \
      _Pragma("unroll")                                                            \
      for (int n = 0; n < 2; ++n)                                                  \
        acc[m][n] = __builtin_amdgcn_mfma_f32_16x16x32_bf16(af[m], bfr[n], acc[m][n], 0, 0, 0); \
    __builtin_amdgcn_s_setprio(0);                                                 \
  }

  f32x4 acc[2][2];
#pragma unroll
  for (int m = 0; m < 2; ++m)
#pragma unroll
    for (int n = 0; n < 2; ++n) acc[m][n] = (f32x4){0.f, 0.f, 0.f, 0.f};

  const int NT = K >> 5;
  STAGE64(0, 0);
  STAGE64(1, 32);
  int cur = 0;
  for (int t = 0; t < NT - 1; ++t) {
    WAITV2();
    __builtin_amdgcn_s_barrier();
    MEMFENCE();
    if (t + 2 < NT) {
      int nxt = cur + 2; if (nxt >= 3) nxt -= 3;
      STAGE64(nxt, (t + 2) << 5);
    }
    COMPUTE64(cur);
    cur = (cur == 2) ? 0 : cur + 1;
  }
  WAITV0();
  __builtin_amdgcn_s_barrier();
  MEMFENCE();
  COMPUTE64(cur);

  float* Cf = (float*)Cv;
  __hip_bfloat16* Cb = (__hip_bfloat16*)Cv;
#pragma unroll
  for (int m = 0; m < 2; ++m) {
#pragma unroll
    for (int n = 0; n < 2; ++n) {
#pragma unroll
      for (int r = 0; r < 4; ++r) {
        int row = bm + wr * 32 + m * 16 + l4 * 4 + r;
        int col = bn + wc * 32 + n * 16 + l15;
        size_t off = (size_t)row * N + col;
        float v = acc[m][n][r];
        if (mode == 0)      Cf[off] = v;
        else if (mode == 1) Cf[off] = v + resid[off];
        else if (mode == 2) Cb[off] = __float2bfloat16(v);
        else                Cb[off] = __float2bfloat16(gelu_f(v));
      }
    }
  }
#undef STAGE64
#undef COMPUTE64
}

// ---------- MFMA flash attention v2 ----------
// 2 waves/block, QBLK=32 (wave wq: 16 q-rows), KVBLK=64, paired q-tiles
// (i, 31-i) -> every block = exactly 17 kv-tiles (perfect balance).
// Double-buffered K/V with prefetch: issue K(gl_lds)+V(reg loads) for t+1
// at the top of tile t, drain vmcnt(0) + write Vt at the bottom; one
// __syncthreads per tile. Swapped QK^T (mfma(K,Q)): lane owns one q-row
// (q = s0 + wq*16 + l15) -> softmax reduce = 2 shfl_xor(16/32); P written
// as 4x ds_write_b64. LDS 36 KB.
__global__ __launch_bounds__(128) void flash_attn_kernel(
    const __hip_bfloat16* __restrict__ qkv_, __hip_bfloat16* __restrict__ attn_)
{
  const unsigned short* qkv = (const unsigned short*)qkv_;
  unsigned short* attn = (unsigned short*)attn_;
  const int px = blockIdx.x;        // pair index 0..15
  const int h  = blockIdx.y;
  const int b  = blockIdx.z;
  const int tid = threadIdx.x;      // 0..127
  const int wq = tid >> 6, ln = tid & 63;
  const int l15 = ln & 15, l4 = ln >> 4;

  __shared__ unsigned short Ks[2][64 * 64];   // 16 KB, [t][d] XOR-swizzled
  __shared__ unsigned short Vt[2][64 * 64];   // 16 KB, [e][t] XOR-swizzled
  __shared__ unsigned short Pw[2][16 * 64];   // 4 KB, per-wave P [q][t]

  // K staging: thread covers row j*16 + (tid>>3), LDS chunk tid&7,
  // source chunk (tid&7) ^ ((tid>>3)&7)  [row&7 == (tid>>3)&7]
  const int krow = tid >> 3;
  const int kchunk = (tid & 7) ^ ((tid >> 3) & 7);
  const int kldsbase = (tid & 64) * 8;   // wave-uniform base (elems)

  // V staging: thread covers rows {2vp, 2vp+1, 2vp+32, 2vp+33} x 8 e
  const int vc = tid & 7;          // e-chunk
  const int vp = tid >> 3;         // 0..15
  const int vtr = (2 * vp) & 7;    // even within-chunk t offset
  const int vtb0 = vp >> 2;        // t-chunk of rows 2vp..

  u16x8 v0, v1, v2, v3;            // V prefetch registers

#define STAGE_K(buf, t0)                                                           \
  {                                                                                \
    _Pragma("unroll")                                                              \
    for (int j = 0; j < 4; ++j) {                                                  \
      const unsigned short* gk = qkv +                                             \
          (size_t)(b * SEQ + (t0) + j * 16 + krow) * 2304 + 768 + h * 64 + kchunk * 8; \
      __builtin_amdgcn_global_load_lds((g_u32*)gk,                                 \
          (l_u32*)(Ks[buf] + j * 1024 + kldsbase), 16, 0, 0);                      \
    }                                                                              \
  }

#define LOAD_V(t0)                                                                 \
  {                                                                                \
    const unsigned short* gv = qkv +                                               \
        (size_t)(b * SEQ + (t0) + 2 * vp) * 2304 + 1536 + h * 64 + vc * 8;         \
    v0 = *(const u16x8*)gv;                                                        \
    v1 = *(const u16x8*)(gv + 2304);                                               \
    v2 = *(const u16x8*)(gv + 32 * 2304);                                          \
    v3 = *(const u16x8*)(gv + 33 * 2304);                                          \
  }

#define WRITE_VT(buf)                                                              \
  {                                                                                \
    _Pragma("unroll")                                                              \
    for (int j = 0; j < 8; ++j) {                                                  \
      int e = vc * 8 + j;                                                          \
      unsigned int w01 = (unsigned int)(unsigned short)v0[j] |                     \
                         ((unsigned int)(unsigned short)v1[j] << 16);              \
      unsigned int w23 = (unsigned int)(unsigned short)v2[j] |                     \
                         ((unsigned int)(unsigned short)v3[j] << 16);              \
      *(unsigned int*)(Vt[buf] + e * 64 + ((vtb0 ^ (e & 7)) << 3) + vtr) = w01;    \
      *(unsigned int*)(Vt[buf] + e * 64 + (((vtb0 + 4) ^ (e & 7)) << 3) + vtr) = w23; \
    }                                                                              \
  }

  for (int pass = 0; pass < 2; ++pass) {
    const int qi = (pass == 0) ? px : 31 - px;
    const int s0 = qi * 32;
    const int ntiles = (qi >> 1) + 1;
    const int qg = s0 + wq * 16 + l15;   // this lane's q row

    // Q fragments (B-operand), pre-scaled by 0.125 (exact in bf16)
    bf16x8 qf[2];
    {
      const size_t qbase = (size_t)(b * SEQ + qg) * 2304 + h * 64;
#pragma unroll
      for (int ks = 0; ks < 2; ++ks) {
        u16x8 raw = *(const u16x8*)(qkv + qbase + ks * 32 + l4 * 8);
        bf16x8 q;
#pragma unroll
        for (int j = 0; j < 8; ++j) q[j] = (short)f2bf(bf2f(raw[j]) * 0.125f);
        qf[ks] = q;
      }
    }

    float mrow = -1e30f, lrow = 0.f;
    f32x4 o[4];
#pragma unroll
    for (int n = 0; n < 4; ++n) o[n] = (f32x4){0.f, 0.f, 0.f, 0.f};

    // prologue: stage tile 0
    STAGE_K(0, 0);
    LOAD_V(0);
    WAITV0();
    WRITE_VT(0);
    __syncthreads();

    for (int t = 0; t < ntiles; ++t) {
      const int cur = t & 1;
      const bool pfn = (t + 1 < ntiles);
      if (pfn) { STAGE_K(cur ^ 1, (t + 1) * 64); LOAD_V((t + 1) * 64); }

      // S^T = K Q^T : sf[n][r] = S[t = t*64 + n*16 + l4*4 + r][q = qg]
      f32x4 sf[4];
#pragma unroll
      for (int n = 0; n < 4; ++n) sf[n] = (f32x4){0.f, 0.f, 0.f, 0.f};
#pragma unroll
      for (int ks = 0; ks < 2; ++ks) {
#pragma unroll
        for (int n = 0; n < 4; ++n) {
          int tr = n * 16 + l15;
          bf16x8 kf = *(const bf16x8*)(Ks[cur] + tr * 64 + (((ks * 4 + l4) ^ (tr & 7)) << 3));
          sf[n] = __builtin_amdgcn_mfma_f32_16x16x32_bf16(kf, qf[ks], sf[n], 0, 0, 0);
        }
      }

      // causal mask (last tile of the pass only)
      if (t == ntiles - 1) {
#pragma unroll
        for (int n = 0; n < 4; ++n) {
#pragma unroll
          for (int r = 0; r < 4; ++r) {
            int tg = t * 64 + n * 16 + l4 * 4 + r;
            if (tg > qg) sf[n][r] = NEGV;
          }
        }
      }

      // online softmax: this lane's q-row spread across l4 groups
      float mx = sf[0][0];
#pragma unroll
      for (int n = 0; n < 4; ++n)
#pragma unroll
        for (int r = 0; r < 4; ++r) mx = fmaxf(mx, sf[n][r]);
      mx = fmaxf(mx, __shfl_xor(mx, 16));
      mx = fmaxf(mx, __shfl_xor(mx, 32));
      float mnew = fmaxf(mrow, mx);
      float alpha = __expf(mrow - mnew);
      float pb[4][4];
      float sum = 0.f;
#pragma unroll
      for (int n = 0; n < 4; ++n)
#pragma unroll
        for (int r = 0; r < 4; ++r) {
          float p = __expf(sf[n][r] - mnew);
          pb[n][r] = p;
          sum += p;
        }
      sum += __shfl_xor(sum, 16);
      sum += __shfl_xor(sum, 32);
      lrow = lrow * alpha + sum;
      mrow = mnew;

      // o-rescale: alpha for row q16 = l4*4+r lives at lane l15 = q16
      float ar[4];
#pragma unroll
      for (int r = 0; r < 4; ++r)
        ar[r] = __shfl(alpha, (ln & 48) | (l4 * 4 + r));
#pragma unroll
      for (int n = 0; n < 4; ++n)
#pragma unroll
        for (int r = 0; r < 4; ++r) o[n][r] *= ar[r];

      // P -> per-wave LDS: row q=l15, t = n*16 + l4*4 + r (4 consecutive)
      unsigned short* Pme = Pw[wq];
#pragma unroll
      for (int n = 0; n < 4; ++n) {
        int tb = 2 * n + (l4 >> 1);
        u16x4 w;
        w[0] = f2bf(pb[n][0]); w[1] = f2bf(pb[n][1]);
        w[2] = f2bf(pb[n][2]); w[3] = f2bf(pb[n][3]);
        *(u16x4*)(Pme + l15 * 64 + ((tb ^ (l15 & 7)) << 3) + (l4 & 1) * 4) = w;
      }

      // O += P V
#pragma unroll
      for (int ks = 0; ks < 2; ++ks) {
        bf16x8 pf = *(const bf16x8*)(Pme + l15 * 64 + (((ks * 4 + l4) ^ (l15 & 7)) << 3));
#pragma unroll
        for (int n = 0; n < 4; ++n) {
          int e = n * 16 + l15;
          bf16x8 vf = *(const bf16x8*)(Vt[cur] + e * 64 + (((ks * 4 + l4) ^ (e & 7)) << 3));
          o[n] = __builtin_amdgcn_mfma_f32_16x16x32_bf16(pf, vf, o[n], 0, 0, 0);
        }
      }

      if (pfn) { WAITV0(); WRITE_VT(cur ^ 1); }
      __syncthreads();
    }

    // epilogue: divide by l (broadcast per output row) and store
    float lr[4];
#pragma unroll
    for (int r = 0; r < 4; ++r)
      lr[r] = __shfl(lrow, (ln & 48) | (l4 * 4 + r));
#pragma unroll
    for (int r = 0; r < 4; ++r) {
      float inv = 1.0f / lr[r];
      size_t base = (size_t)(b * SEQ + s0 + wq * 16 + l4 * 4 + r) * D_MODEL + h * 64;
#pragma unroll
      for (int n = 0; n < 4; ++n)
        attn[base + n * 16 + l15] = f2bf(o[n][r] * inv);
    }
  }
#undef STAGE_K
#undef LOAD_V
#undef WRITE_VT
}

// ---------- logits: out[b,v] = dot(normed[b,:], unembed[v,:]) ----------
__global__ __launch_bounds__(256) void logits_kernel(
    const float* __restrict__ normed, const float* __restrict__ unemb,
    float* __restrict__ out)
{
  __shared__ __align__(16) float ns[BATCH][D_MODEL];
  for (int d = threadIdx.x; d < BATCH * D_MODEL; d += 256)
    ((float*)ns)[d] = normed[d];
  __syncthreads();
  int g = threadIdx.x >> 4, li = threadIdx.x & 15;
  int v = blockIdx.x * 16 + g;
  const float* up = unemb + (size_t)v * D_MODEL;
  float s0 = 0.f, s1 = 0.f, s2 = 0.f, s3 = 0.f;
#pragma unroll
  for (int it = 0; it < D_MODEL / 64; ++it) {
    int e = it * 64 + li * 4;
    float4 u = *(const float4*)(up + e);
    float4 n0 = *(const float4*)&ns[0][e];
    float4 n1 = *(const float4*)&ns[1][e];
    float4 n2 = *(const float4*)&ns[2][e];
    float4 n3 = *(const float4*)&ns[3][e];
    s0 += u.x*n0.x + u.y*n0.y + u.z*n0.z + u.w*n0.w;
    s1 += u.x*n1.x + u.y*n1.y + u.z*n1.z + u.w*n1.w;
    s2 += u.x*n2.x + u.y*n2.y + u.z*n2.z + u.w*n2.w;
    s3 += u.x*n3.x + u.y*n3.y + u.z*n3.z + u.w*n3.w;
  }
#pragma unroll
  for (int msk = 1; msk < 16; msk <<= 1) {
    s0 += __shfl_xor(s0, msk, 64); s1 += __shfl_xor(s1, msk, 64);
    s2 += __shfl_xor(s2, msk, 64); s3 += __shfl_xor(s3, msk, 64);
  }
  if (li == 0) {
    out[(size_t)0 * VOCAB + v] = s0;
    out[(size_t)1 * VOCAB + v] = s1;
    out[(size_t)2 * VOCAB + v] = s2;
    out[(size_t)3 * VOCAB + v] = s3;
  }
}

// ---------- launcher ----------
extern "C" void kernel_launch(void* const* d_in, const int* in_sizes, int n_in,
                              void* d_out, int out_size, void* d_ws, size_t ws_size,
                              hipStream_t stream) {
  const int*   tokens = (const int*)d_in[0];
  const int*   pidx   = (const int*)d_in[1];
  const float* emb    = (const float*)d_in[2];
  const float* ln1_g  = (const float*)d_in[3];
  const float* ln1_b  = (const float*)d_in[4];
  const float* wq     = (const float*)d_in[5];
  const float* wk     = (const float*)d_in[6];
  const float* wv     = (const float*)d_in[7];
  const float* wo     = (const float*)d_in[8];
  const float* ln2_g  = (const float*)d_in[9];
  const float* ln2_b  = (const float*)d_in[10];
  const float* fc1    = (const float*)d_in[11];
  const float* fc2    = (const float*)d_in[12];
  const float* lnf_g  = (const float*)d_in[13];
  const float* lnf_b  = (const float*)d_in[14];
  const float* unemb  = (const float*)d_in[15];
  float* out = (float*)d_out;

  char* wp = (char*)d_ws;
  const size_t NX = (size_t)NROWS * D_MODEL;        // 3,145,728
  float* x = (float*)wp;                  wp += NX * 4;
  float* normed = (float*)wp;             wp += BATCH * D_MODEL * 4;
  __hip_bfloat16* h    = (__hip_bfloat16*)wp; wp += NX * 2;
  __hip_bfloat16* attn = (__hip_bfloat16*)wp; wp += NX * 2;
  __hip_bfloat16* qkvb = (__hip_bfloat16*)wp; wp += (size_t)NROWS * 2304 * 2;
  __hip_bfloat16* ffn  = (__hip_bfloat16*)wp; wp += (size_t)NROWS * D_FF * 2;
  __hip_bfloat16* wqkvb = (__hip_bfloat16*)wp; wp += (size_t)N_LAYERS * 2304 * D_MODEL * 2;
  __hip_bfloat16* wob   = (__hip_bfloat16*)wp; wp += (size_t)N_LAYERS * D_MODEL * D_MODEL * 2;
  __hip_bfloat16* fc1b  = (__hip_bfloat16*)wp; wp += (size_t)N_LAYERS * D_FF * D_MODEL * 2;
  __hip_bfloat16* fc2b  = (__hip_bfloat16*)wp; wp += (size_t)N_LAYERS * D_MODEL * D_FF * 2;

  // embT [VOCAB][D_MODEL] bf16 (49.2 MB) aliased onto attn..ffn scratch
  __hip_bfloat16* embT = attn;

  const int WMAT = D_MODEL * D_MODEL;     // 589824
  const int FMAT = D_FF * D_MODEL;        // 2359296

  transpose_emb_kernel<<<dim3(VOCAB / 64, D_MODEL / 64), 256, 0, stream>>>(emb, embT);
  embed_kernel<<<NROWS, 256, 0, stream>>>(tokens, embT, x);

  qkv_pack_kernel<<<N_LAYERS * 3 * WMAT / 2048, 256, 0, stream>>>(wq, wk, wv, wqkvb);
  convert_kernel<<<N_LAYERS * WMAT / 2048, 256, 0, stream>>>(wo,  wob,  N_LAYERS * WMAT);
  convert_kernel<<<N_LAYERS * FMAT / 2048, 256, 0, stream>>>(fc1, fc1b, N_LAYERS * FMAT);
  convert_kernel<<<N_LAYERS * FMAT / 2048, 256, 0, stream>>>(fc2, fc2b, N_LAYERS * FMAT);

  for (int l = 0; l < N_LAYERS; ++l) {
    const size_t qofs = (size_t)l * 3 * WMAT;
    const size_t wofs = (size_t)l * WMAT;
    const size_t fofs = (size_t)l * FMAT;

    ln_kernel<<<NROWS, 256, 0, stream>>>(x, h, ln1_g + l * D_MODEL, ln1_b + l * D_MODEL);

    // fused QKV: [4096 x 2304] bf16 out
    gemm_bf16_kernel<<<dim3(2304 / 128, NROWS / 128), 256, 0, stream>>>(
        h, wqkvb + qofs, qkvb, nullptr, 2304, D_MODEL, 2);

    flash_attn_kernel<<<dim3(16, N_HEADS, BATCH), 128, 0, stream>>>(qkvb, attn);

    // x += attn @ wo^T  (64-tile: 768 blocks)
    gemm64_bf16_kernel<<<dim3(D_MODEL / 64, NROWS / 64), 256, 0, stream>>>(
        attn, wob + wofs, x, x, D_MODEL, D_MODEL, 1);

    ln_kernel<<<NROWS, 256, 0, stream>>>(x, h, ln2_g + l * D_MODEL, ln2_b + l * D_MODEL);

    // ffn = gelu(h @ fc1^T) (bf16)
    gemm_bf16_kernel<<<dim3(D_FF / 128, NROWS / 128), 256, 0, stream>>>(
        h, fc1b + fofs, ffn, nullptr, D_FF, D_MODEL, 3);

    // x += ffn @ fc2^T  (64-tile: 768 blocks)
    gemm64_bf16_kernel<<<dim3(D_MODEL / 64, NROWS / 64), 256, 0, stream>>>(
        ffn, fc2b + fofs, x, x, D_MODEL, D_FF, 1);
  }

  final_ln_kernel<<<BATCH, 256, 0, stream>>>(x, pidx, lnf_g, lnf_b, normed);
  logits_kernel<<<VOCAB / 16, 256, 0, stream>>>(normed, unemb, out);
}

// Round 8
// 807.548 us; speedup vs baseline: 6.7971x; 1.0791x over previous
//
#include <hip/hip_runtime.h>
#include <hip/hip_bf16.h>

#define D_MODEL 768
#define N_HEADS 12
#define D_HEAD  64
#define D_FF    3072
#define N_LAYERS 4
#define VOCAB   32000
#define BATCH   4
#define SEQ     1024
#define NROWS   (BATCH*SEQ)      // 4096
#define NEGV    -1000000000.0f
#define LN_EPS  1e-5f

typedef __attribute__((ext_vector_type(8))) short bf16x8;
typedef __attribute__((ext_vector_type(4))) float f32x4;
typedef __attribute__((ext_vector_type(8))) unsigned short u16x8;
typedef __attribute__((ext_vector_type(4))) unsigned short u16x4;

typedef __attribute__((address_space(1))) const unsigned int g_u32;
typedef __attribute__((address_space(3))) unsigned int l_u32;

__device__ __forceinline__ float bf2f(unsigned short u) {
  return __uint_as_float(((unsigned int)u) << 16);
}
__device__ __forceinline__ unsigned short f2bf(float f) {
  __hip_bfloat16 h = __float2bfloat16(f);
  return *reinterpret_cast<unsigned short*>(&h);
}

__device__ __forceinline__ float block_reduce_sum(float v, float* sbuf) {
#pragma unroll
  for (int off = 32; off > 0; off >>= 1) v += __shfl_down(v, off, 64);
  int lane = threadIdx.x & 63, wid = threadIdx.x >> 6;
  if (lane == 0) sbuf[wid] = v;
  __syncthreads();
  if (threadIdx.x == 0) sbuf[4] = sbuf[0] + sbuf[1] + sbuf[2] + sbuf[3];
  __syncthreads();
  return sbuf[4];
}

__device__ __forceinline__ float gelu_f(float x) {
  float c = x + 0.044715f * x * x * x;
  return x * (0.5f * (1.0f + tanhf(0.7978845608f * c)));
}

// ---------- fp32 -> bf16 weight conversion (8 elems / thread) ----------
__global__ __launch_bounds__(256) void convert_kernel(
    const float* __restrict__ src, __hip_bfloat16* __restrict__ dst, int n)
{
  int i = (blockIdx.x * 256 + threadIdx.x) * 8;
  if (i >= n) return;
  float4 a = *(const float4*)(src + i);
  float4 b = *(const float4*)(src + i + 4);
  struct bf8 { __hip_bfloat16 h[8]; } r;
  r.h[0] = __float2bfloat16(a.x); r.h[1] = __float2bfloat16(a.y);
  r.h[2] = __float2bfloat16(a.z); r.h[3] = __float2bfloat16(a.w);
  r.h[4] = __float2bfloat16(b.x); r.h[5] = __float2bfloat16(b.y);
  r.h[6] = __float2bfloat16(b.z); r.h[7] = __float2bfloat16(b.w);
  *(bf8*)(dst + i) = r;
}

// pack wq|wk|wv of all layers into wqkvb [l][3*WMAT] in one launch
__global__ __launch_bounds__(256) void qkv_pack_kernel(
    const float* __restrict__ wq, const float* __restrict__ wk,
    const float* __restrict__ wv, __hip_bfloat16* __restrict__ dst)
{
  const int WMAT = D_MODEL * D_MODEL;
  long long i = (long long)(blockIdx.x * 256 + threadIdx.x) * 8;
  long long l = i / (3LL * WMAT);
  long long rem = i - l * 3LL * WMAT;
  int which = (int)(rem / WMAT);
  long long off = rem - (long long)which * WMAT;
  const float* src = (which == 0 ? wq : which == 1 ? wk : wv) + l * WMAT + off;
  float4 a = *(const float4*)src;
  float4 b = *(const float4*)(src + 4);
  struct bf8 { __hip_bfloat16 h[8]; } r;
  r.h[0] = __float2bfloat16(a.x); r.h[1] = __float2bfloat16(a.y);
  r.h[2] = __float2bfloat16(a.z); r.h[3] = __float2bfloat16(a.w);
  r.h[4] = __float2bfloat16(b.x); r.h[5] = __float2bfloat16(b.y);
  r.h[6] = __float2bfloat16(b.z); r.h[7] = __float2bfloat16(b.w);
  *(bf8*)(dst + i) = r;
}

// ---------- embedding transpose: emb [768][32000] f32 -> embT [32000][768] bf16 ----------
__global__ __launch_bounds__(256) void transpose_emb_kernel(
    const float* __restrict__ emb, __hip_bfloat16* __restrict__ embT)
{
  __shared__ float tile[64][65];
  const int vb = blockIdx.x * 64;   // vocab block
  const int db = blockIdx.y * 64;   // d block
  const int tid = threadIdx.x;
  {
    int r = tid >> 4, c = (tid & 15) * 4;
#pragma unroll
    for (int p = 0; p < 4; ++p) {
      float4 v = *(const float4*)(emb + (size_t)(db + r + p * 16) * VOCAB + vb + c);
      tile[c + 0][r + p * 16] = v.x;
      tile[c + 1][r + p * 16] = v.y;
      tile[c + 2][r + p * 16] = v.z;
      tile[c + 3][r + p * 16] = v.w;
    }
  }
  __syncthreads();
  {
    int v = tid >> 2, d0 = (tid & 3) * 16;
    unsigned short* op = (unsigned short*)embT + (size_t)(vb + v) * D_MODEL + db + d0;
    u16x8 o0, o1;
#pragma unroll
    for (int j = 0; j < 8; ++j) {
      o0[j] = f2bf(tile[v][d0 + j]);
      o1[j] = f2bf(tile[v][d0 + 8 + j]);
    }
    *(u16x8*)op = o0;
    *(u16x8*)(op + 8) = o1;
  }
}

// ---------- embedding gather (coalesced) + positional encoding ----------
__global__ __launch_bounds__(256) void embed_kernel(
    const int* __restrict__ tokens, const __hip_bfloat16* __restrict__ embT,
    float* __restrict__ x)
{
  int bs = blockIdx.x;
  int s = bs & (SEQ - 1);
  int tok = tokens[bs];
  const unsigned short* ep = (const unsigned short*)embT + (size_t)tok * D_MODEL;
  for (int d = threadIdx.x; d < D_MODEL; d += 256) {
    float ev = bf2f(ep[d]);
    int dpair = d & ~1;
    float expo = (float)dpair * (1.0f / (float)D_MODEL);
    float ang = (float)s / powf(10000.0f, expo);
    float pe = (d & 1) ? cosf(ang) : sinf(ang);
    x[(size_t)bs * D_MODEL + d] = ev + pe;
  }
}

// ---------- layer norm (fp32 in, bf16 out) ----------
__global__ __launch_bounds__(256) void ln_kernel(
    const float* __restrict__ in, __hip_bfloat16* __restrict__ out,
    const float* __restrict__ g, const float* __restrict__ bb)
{
  __shared__ float sbuf[8];
  size_t row = blockIdx.x;
  const float* rp = in + row * D_MODEL;
  int t = threadIdx.x;
  float x0 = rp[t], x1 = rp[t + 256], x2 = rp[t + 512];
  float mean = block_reduce_sum(x0 + x1 + x2, sbuf) * (1.0f / (float)D_MODEL);
  float d0 = x0 - mean, d1 = x1 - mean, d2 = x2 - mean;
  float var = block_reduce_sum(d0*d0 + d1*d1 + d2*d2, sbuf) * (1.0f / (float)D_MODEL);
  float rstd = rsqrtf(var + LN_EPS);
  __hip_bfloat16* op = out + row * D_MODEL;
  op[t]       = __float2bfloat16(g[t]       * (d0 * rstd) + bb[t]);
  op[t + 256] = __float2bfloat16(g[t + 256] * (d1 * rstd) + bb[t + 256]);
  op[t + 512] = __float2bfloat16(g[t + 512] * (d2 * rstd) + bb[t + 512]);
}

// final LN on x[b, predict_idx, :] (fp32 out)
__global__ __launch_bounds__(256) void final_ln_kernel(
    const float* __restrict__ x, const int* __restrict__ pidx,
    const float* __restrict__ g, const float* __restrict__ bb,
    float* __restrict__ out)
{
  __shared__ float sbuf[8];
  int p = pidx[0];
  const float* rp = x + ((size_t)blockIdx.x * SEQ + p) * D_MODEL;
  int t = threadIdx.x;
  float x0 = rp[t], x1 = rp[t + 256], x2 = rp[t + 512];
  float mean = block_reduce_sum(x0 + x1 + x2, sbuf) * (1.0f / (float)D_MODEL);
  float d0 = x0 - mean, d1 = x1 - mean, d2 = x2 - mean;
  float var = block_reduce_sum(d0*d0 + d1*d1 + d2*d2, sbuf) * (1.0f / (float)D_MODEL);
  float rstd = rsqrtf(var + LN_EPS);
  float* op = out + (size_t)blockIdx.x * D_MODEL;
  op[t]       = g[t]       * (d0 * rstd) + bb[t];
  op[t + 256] = g[t + 256] * (d1 * rstd) + bb[t + 256];
  op[t + 512] = g[t + 512] * (d2 * rstd) + bb[t + 512];
}

// XCD-chunked bijective block swizzle (nwg % 8 == 0 for all our grids)
__device__ __forceinline__ int2 xcd_tile(int gx, int gy) {
  int flat = blockIdx.y * gx + blockIdx.x;
  int cpx = (gx * gy) >> 3;
  int logical = (flat & 7) * cpx + (flat >> 3);
  return make_int2(logical % gx, logical / gx);   // (col, row)
}

#define WAITV4() asm volatile("s_waitcnt vmcnt(4)" ::: "memory")
#define WAITV0() asm volatile("s_waitcnt vmcnt(0)" ::: "memory")
#define MEMFENCE() asm volatile("" ::: "memory")

// ---------- bf16 MFMA NT GEMM, ring-3 counted-vmcnt pipeline ----------
// 128x128 tile, BK=32, 3 LDS buffers, depth-2 prefetch (proven round 6).
__global__ __launch_bounds__(256) void gemm_bf16_kernel(
    const __hip_bfloat16* __restrict__ A, const __hip_bfloat16* __restrict__ W,
    void* __restrict__ Cv, const float* __restrict__ resid,
    int N, int K, int mode)
{
  __shared__ __align__(16) unsigned short As[3][128 * 32];   // 24 KB
  __shared__ __align__(16) unsigned short Bs[3][128 * 32];   // 24 KB
  const unsigned short* Au = (const unsigned short*)A;
  const unsigned short* Wu = (const unsigned short*)W;
  const int tid = threadIdx.x;
  const int wv = tid >> 6, ln = tid & 63;
  const int l15 = ln & 15, l4 = ln >> 4;
  int2 tc = xcd_tile(N >> 7, gridDim.y);
  const int bm = tc.y * 128, bn = tc.x * 128;
  const int wr = wv >> 1, wc = wv & 1;

  const int lrow = wv * 16 + (ln >> 2);
  const int schunk = (ln & 3) ^ ((ln >> 3) & 3);
  const size_t gA0 = (size_t)(bm + lrow) * K + schunk * 8;
  const size_t gA1 = (size_t)(bm + 64 + lrow) * K + schunk * 8;
  const size_t gB0 = (size_t)(bn + lrow) * K + schunk * 8;
  const size_t gB1 = (size_t)(bn + 64 + lrow) * K + schunk * 8;
  const int ldsb = wv * 512;

#define STAGE128(buf, k0)                                                          \
  {                                                                                \
    __builtin_amdgcn_global_load_lds((g_u32*)(Au + gA0 + (k0)), (l_u32*)(As[buf] + ldsb), 16, 0, 0);        \
    __builtin_amdgcn_global_load_lds((g_u32*)(Au + gA1 + (k0)), (l_u32*)(As[buf] + 2048 + ldsb), 16, 0, 0); \
    __builtin_amdgcn_global_load_lds((g_u32*)(Wu + gB0 + (k0)), (l_u32*)(Bs[buf] + ldsb), 16, 0, 0);        \
    __builtin_amdgcn_global_load_lds((g_u32*)(Wu + gB1 + (k0)), (l_u32*)(Bs[buf] + 2048 + ldsb), 16, 0, 0); \
  }

  const int rslot = (l4 ^ ((l15 >> 1) & 3)) * 8;

#define COMPUTE128(buf)                                                            \
  {                                                                                \
    bf16x8 af[4], bfr[4];                                                          \
    _Pragma("unroll")                                                              \
    for (int m = 0; m < 4; ++m)                                                    \
      af[m] = *(const bf16x8*)(As[buf] + (wr * 64 + m * 16 + l15) * 32 + rslot);   \
    _Pragma("unroll")                                                              \
    for (int n = 0; n < 4; ++n)                                                    \
      bfr[n] = *(const bf16x8*)(Bs[buf] + (wc * 64 + n * 16 + l15) * 32 + rslot);  \
    __builtin_amdgcn_s_setprio(1);                                                 \
    _Pragma("unroll")                                                              \
    for (int m = 0; m < 4; ++m)                                                    \
      _Pragma("unroll")                                                            \
      for (int n = 0; n < 4; ++n)                                                  \
        acc[m][n] = __builtin_amdgcn_mfma_f32_16x16x32_bf16(af[m], bfr[n], acc[m][n], 0, 0, 0); \
    __builtin_amdgcn_s_setprio(0);                                                 \
  }

  f32x4 acc[4][4];
#pragma unroll
  for (int m = 0; m < 4; ++m)
#pragma unroll
    for (int n = 0; n < 4; ++n) acc[m][n] = (f32x4){0.f, 0.f, 0.f, 0.f};

  const int NT = K >> 5;
  STAGE128(0, 0);
  STAGE128(1, 32);
  int cur = 0;
  for (int t = 0; t < NT - 1; ++t) {
    WAITV4();
    __builtin_amdgcn_s_barrier();
    MEMFENCE();
    if (t + 2 < NT) {
      int nxt = cur + 2; if (nxt >= 3) nxt -= 3;
      STAGE128(nxt, (t + 2) << 5);
    }
    COMPUTE128(cur);
    cur = (cur == 2) ? 0 : cur + 1;
  }
  WAITV0();
  __builtin_amdgcn_s_barrier();
  MEMFENCE();
  COMPUTE128(cur);

  float* Cf = (float*)Cv;
  __hip_bfloat16* Cb = (__hip_bfloat16*)Cv;
#pragma unroll
  for (int m = 0; m < 4; ++m) {
#pragma unroll
    for (int n = 0; n < 4; ++n) {
#pragma unroll
      for (int r = 0; r < 4; ++r) {
        int row = bm + wr * 64 + m * 16 + l4 * 4 + r;
        int col = bn + wc * 64 + n * 16 + l15;
        size_t off = (size_t)row * N + col;
        float v = acc[m][n][r];
        if (mode == 0)      Cf[off] = v;
        else if (mode == 1) Cf[off] = v + resid[off];
        else if (mode == 2) Cb[off] = __float2bfloat16(v);
        else                Cb[off] = __float2bfloat16(gelu_f(v));
      }
    }
  }
#undef STAGE128
#undef COMPUTE128
}

// ---------- 64x64-tile variant (N=768 GEMMs: wo, fc2) ----------
// BK=64 (round-4-proven staging/read geometry, 0 bank conflicts) + ring-3
// counted-vmcnt pipeline (round-6-proven). 48 KB LDS -> 3 blocks/CU.
// Per K-tile per wave: 8 MFMA + 8 ds_read_b128 + 4 gl_lds; NT = K/64.
__global__ __launch_bounds__(256) void gemm64_bf16_kernel(
    const __hip_bfloat16* __restrict__ A, const __hip_bfloat16* __restrict__ W,
    void* __restrict__ Cv, const float* __restrict__ resid,
    int N, int K, int mode)
{
  __shared__ __align__(16) unsigned short As[3][64 * 64];   // 24 KB
  __shared__ __align__(16) unsigned short Bs[3][64 * 64];   // 24 KB
  const unsigned short* Au = (const unsigned short*)A;
  const unsigned short* Wu = (const unsigned short*)W;
  const int tid = threadIdx.x;
  const int wv = tid >> 6, ln = tid & 63;
  const int l15 = ln & 15, l4 = ln >> 4;
  int2 tc = xcd_tile(N >> 6, gridDim.y);
  const int bm = tc.y * 64, bn = tc.x * 64;
  const int wr = wv >> 1, wc = wv & 1;

  // staging: round r (0,1) covers row r*32 + tid/8, LDS chunk tid&7,
  // source chunk (tid&7) ^ (row&7); row&7 == (tid>>3)&7 for both rounds.
  const int srow = tid >> 3;                       // 0..31
  const int schunk = (tid & 7) ^ ((tid >> 3) & 7);
  const size_t gA0 = (size_t)(bm + srow) * K + schunk * 8;
  const size_t gA1 = (size_t)(bm + 32 + srow) * K + schunk * 8;
  const size_t gB0 = (size_t)(bn + srow) * K + schunk * 8;
  const size_t gB1 = (size_t)(bn + 32 + srow) * K + schunk * 8;
  const int ldsb = wv * 512;   // wave-uniform base (elems); +2048 for round 1

#define STAGE64(buf, k0)                                                           \
  {                                                                                \
    __builtin_amdgcn_global_load_lds((g_u32*)(Au + gA0 + (k0)), (l_u32*)(As[buf] + ldsb), 16, 0, 0);        \
    __builtin_amdgcn_global_load_lds((g_u32*)(Au + gA1 + (k0)), (l_u32*)(As[buf] + 2048 + ldsb), 16, 0, 0); \
    __builtin_amdgcn_global_load_lds((g_u32*)(Wu + gB0 + (k0)), (l_u32*)(Bs[buf] + ldsb), 16, 0, 0);        \
    __builtin_amdgcn_global_load_lds((g_u32*)(Wu + gB1 + (k0)), (l_u32*)(Bs[buf] + 2048 + ldsb), 16, 0, 0); \
  }

#define COMPUTE64(buf)                                                             \
  {                                                                                \
    bf16x8 af[2][2], bfr[2][2];                                                    \
    _Pragma("unroll")                                                              \
    for (int ks = 0; ks < 2; ++ks) {                                               \
      _Pragma("unroll")                                                            \
      for (int m = 0; m < 2; ++m)                                                  \
        af[ks][m] = *(const bf16x8*)(As[buf] + (wr * 32 + m * 16 + l15) * 64 +     \
                                     (((ks * 4 + l4) ^ (l15 & 7)) << 3));          \
      _Pragma("unroll")                                                            \
      for (int n = 0; n < 2; ++n)                                                  \
        bfr[ks][n] = *(const bf16x8*)(Bs[buf] + (wc * 32 + n * 16 + l15) * 64 +    \
                                      (((ks * 4 + l4) ^ (l15 & 7)) << 3));         \
    }                                                                              \
    __builtin_amdgcn_s_setprio(1);                                                 \
    _Pragma("unroll")                                                              \
    for (int ks = 0; ks < 2; ++ks)                                                 \
      _Pragma("unroll")                                                            \
      for (int m = 0; m < 2; ++m)                                                  \
        _Pragma("unroll")                                                          \
        for (int n = 0; n < 2; ++n)                                                \
          acc[m][n] = __builtin_amdgcn_mfma_f32_16x16x32_bf16(af[ks][m], bfr[ks][n], acc[m][n], 0, 0, 0); \
    __builtin_amdgcn_s_setprio(0);                                                 \
  }

  f32x4 acc[2][2];
#pragma unroll
  for (int m = 0; m < 2; ++m)
#pragma unroll
    for (int n = 0; n < 2; ++n) acc[m][n] = (f32x4){0.f, 0.f, 0.f, 0.f};

  const int NT = K >> 6;            // wo: 12, fc2: 48
  STAGE64(0, 0);
  STAGE64(1, 64);
  int cur = 0;
  for (int t = 0; t < NT - 1; ++t) {
    WAITV4();                        // own tile-t loads landed (t+1 in flight)
    __builtin_amdgcn_s_barrier();
    MEMFENCE();
    if (t + 2 < NT) {
      int nxt = cur + 2; if (nxt >= 3) nxt -= 3;
      STAGE64(nxt, (t + 2) << 6);    // overwrites tile t-1's buffer: safe
    }
    COMPUTE64(cur);
    cur = (cur == 2) ? 0 : cur + 1;
  }
  WAITV0();
  __builtin_amdgcn_s_barrier();
  MEMFENCE();
  COMPUTE64(cur);

  float* Cf = (float*)Cv;
  __hip_bfloat16* Cb = (__hip_bfloat16*)Cv;
#pragma unroll
  for (int m = 0; m < 2; ++m) {
#pragma unroll
    for (int n = 0; n < 2; ++n) {
#pragma unroll
      for (int r = 0; r < 4; ++r) {
        int row = bm + wr * 32 + m * 16 + l4 * 4 + r;
        int col = bn + wc * 32 + n * 16 + l15;
        size_t off = (size_t)row * N + col;
        float v = acc[m][n][r];
        if (mode == 0)      Cf[off] = v;
        else if (mode == 1) Cf[off] = v + resid[off];
        else if (mode == 2) Cb[off] = __float2bfloat16(v);
        else                Cb[off] = __float2bfloat16(gelu_f(v));
      }
    }
  }
#undef STAGE64
#undef COMPUTE64
}

// ---------- MFMA flash attention v2 (proven round 7) ----------
__global__ __launch_bounds__(128) void flash_attn_kernel(
    const __hip_bfloat16* __restrict__ qkv_, __hip_bfloat16* __restrict__ attn_)
{
  const unsigned short* qkv = (const unsigned short*)qkv_;
  unsigned short* attn = (unsigned short*)attn_;
  const int px = blockIdx.x;        // pair index 0..15
  const int h  = blockIdx.y;
  const int b  = blockIdx.z;
  const int tid = threadIdx.x;      // 0..127
  const int wq = tid >> 6, ln = tid & 63;
  const int l15 = ln & 15, l4 = ln >> 4;

  __shared__ unsigned short Ks[2][64 * 64];   // 16 KB, [t][d] XOR-swizzled
  __shared__ unsigned short Vt[2][64 * 64];   // 16 KB, [e][t] XOR-swizzled
  __shared__ unsigned short Pw[2][16 * 64];   // 4 KB, per-wave P [q][t]

  const int krow = tid >> 3;
  const int kchunk = (tid & 7) ^ ((tid >> 3) & 7);
  const int kldsbase = (tid & 64) * 8;   // wave-uniform base (elems)

  const int vc = tid & 7;          // e-chunk
  const int vp = tid >> 3;         // 0..15
  const int vtr = (2 * vp) & 7;    // even within-chunk t offset
  const int vtb0 = vp >> 2;        // t-chunk of rows 2vp..

  u16x8 v0, v1, v2, v3;            // V prefetch registers

#define STAGE_K(buf, t0)                                                           \
  {                                                                                \
    _Pragma("unroll")                                                              \
    for (int j = 0; j < 4; ++j) {                                                  \
      const unsigned short* gk = qkv +                                             \
          (size_t)(b * SEQ + (t0) + j * 16 + krow) * 2304 + 768 + h * 64 + kchunk * 8; \
      __builtin_amdgcn_global_load_lds((g_u32*)gk,                                 \
          (l_u32*)(Ks[buf] + j * 1024 + kldsbase), 16, 0, 0);                      \
    }                                                                              \
  }

#define LOAD_V(t0)                                                                 \
  {                                                                                \
    const unsigned short* gv = qkv +                                               \
        (size_t)(b * SEQ + (t0) + 2 * vp) * 2304 + 1536 + h * 64 + vc * 8;         \
    v0 = *(const u16x8*)gv;                                                        \
    v1 = *(const u16x8*)(gv + 2304);                                               \
    v2 = *(const u16x8*)(gv + 32 * 2304);                                          \
    v3 = *(const u16x8*)(gv + 33 * 2304);                                          \
  }

#define WRITE_VT(buf)                                                              \
  {                                                                                \
    _Pragma("unroll")                                                              \
    for (int j = 0; j < 8; ++j) {                                                  \
      int e = vc * 8 + j;                                                          \
      unsigned int w01 = (unsigned int)(unsigned short)v0[j] |                     \
                         ((unsigned int)(unsigned short)v1[j] << 16);              \
      unsigned int w23 = (unsigned int)(unsigned short)v2[j] |                     \
                         ((unsigned int)(unsigned short)v3[j] << 16);              \
      *(unsigned int*)(Vt[buf] + e * 64 + ((vtb0 ^ (e & 7)) << 3) + vtr) = w01;    \
      *(unsigned int*)(Vt[buf] + e * 64 + (((vtb0 + 4) ^ (e & 7)) << 3) + vtr) = w23; \
    }                                                                              \
  }

  for (int pass = 0; pass < 2; ++pass) {
    const int qi = (pass == 0) ? px : 31 - px;
    const int s0 = qi * 32;
    const int ntiles = (qi >> 1) + 1;
    const int qg = s0 + wq * 16 + l15;   // this lane's q row

    bf16x8 qf[2];
    {
      const size_t qbase = (size_t)(b * SEQ + qg) * 2304 + h * 64;
#pragma unroll
      for (int ks = 0; ks < 2; ++ks) {
        u16x8 raw = *(const u16x8*)(qkv + qbase + ks * 32 + l4 * 8);
        bf16x8 q;
#pragma unroll
        for (int j = 0; j < 8; ++j) q[j] = (short)f2bf(bf2f(raw[j]) * 0.125f);
        qf[ks] = q;
      }
    }

    float mrow = -1e30f, lrow = 0.f;
    f32x4 o[4];
#pragma unroll
    for (int n = 0; n < 4; ++n) o[n] = (f32x4){0.f, 0.f, 0.f, 0.f};

    STAGE_K(0, 0);
    LOAD_V(0);
    WAITV0();
    WRITE_VT(0);
    __syncthreads();

    for (int t = 0; t < ntiles; ++t) {
      const int cur = t & 1;
      const bool pfn = (t + 1 < ntiles);
      if (pfn) { STAGE_K(cur ^ 1, (t + 1) * 64); LOAD_V((t + 1) * 64); }

      f32x4 sf[4];
#pragma unroll
      for (int n = 0; n < 4; ++n) sf[n] = (f32x4){0.f, 0.f, 0.f, 0.f};
#pragma unroll
      for (int ks = 0; ks < 2; ++ks) {
#pragma unroll
        for (int n = 0; n < 4; ++n) {
          int tr = n * 16 + l15;
          bf16x8 kf = *(const bf16x8*)(Ks[cur] + tr * 64 + (((ks * 4 + l4) ^ (tr & 7)) << 3));
          sf[n] = __builtin_amdgcn_mfma_f32_16x16x32_bf16(kf, qf[ks], sf[n], 0, 0, 0);
        }
      }

      if (t == ntiles - 1) {
#pragma unroll
        for (int n = 0; n < 4; ++n) {
#pragma unroll
          for (int r = 0; r < 4; ++r) {
            int tg = t * 64 + n * 16 + l4 * 4 + r;
            if (tg > qg) sf[n][r] = NEGV;
          }
        }
      }

      float mx = sf[0][0];
#pragma unroll
      for (int n = 0; n < 4; ++n)
#pragma unroll
        for (int r = 0; r < 4; ++r) mx = fmaxf(mx, sf[n][r]);
      mx = fmaxf(mx, __shfl_xor(mx, 16));
      mx = fmaxf(mx, __shfl_xor(mx, 32));
      float mnew = fmaxf(mrow, mx);
      float alpha = __expf(mrow - mnew);
      float pb[4][4];
      float sum = 0.f;
#pragma unroll
      for (int n = 0; n < 4; ++n)
#pragma unroll
        for (int r = 0; r < 4; ++r) {
          float p = __expf(sf[n][r] - mnew);
          pb[n][r] = p;
          sum += p;
        }
      sum += __shfl_xor(sum, 16);
      sum += __shfl_xor(sum, 32);
      lrow = lrow * alpha + sum;
      mrow = mnew;

      float ar[4];
#pragma unroll
      for (int r = 0; r < 4; ++r)
        ar[r] = __shfl(alpha, (ln & 48) | (l4 * 4 + r));
#pragma unroll
      for (int n = 0; n < 4; ++n)
#pragma unroll
        for (int r = 0; r < 4; ++r) o[n][r] *= ar[r];

      unsigned short* Pme = Pw[wq];
#pragma unroll
      for (int n = 0; n < 4; ++n) {
        int tb = 2 * n + (l4 >> 1);
        u16x4 w;
        w[0] = f2bf(pb[n][0]); w[1] = f2bf(pb[n][1]);
        w[2] = f2bf(pb[n][2]); w[3] = f2bf(pb[n][3]);
        *(u16x4*)(Pme + l15 * 64 + ((tb ^ (l15 & 7)) << 3) + (l4 & 1) * 4) = w;
      }

#pragma unroll
      for (int ks = 0; ks < 2; ++ks) {
        bf16x8 pf = *(const bf16x8*)(Pme + l15 * 64 + (((ks * 4 + l4) ^ (l15 & 7)) << 3));
#pragma unroll
        for (int n = 0; n < 4; ++n) {
          int e = n * 16 + l15;
          bf16x8 vf = *(const bf16x8*)(Vt[cur] + e * 64 + (((ks * 4 + l4) ^ (e & 7)) << 3));
          o[n] = __builtin_amdgcn_mfma_f32_16x16x32_bf16(pf, vf, o[n], 0, 0, 0);
        }
      }

      if (pfn) { WAITV0(); WRITE_VT(cur ^ 1); }
      __syncthreads();
    }

    float lr[4];
#pragma unroll
    for (int r = 0; r < 4; ++r)
      lr[r] = __shfl(lrow, (ln & 48) | (l4 * 4 + r));
#pragma unroll
    for (int r = 0; r < 4; ++r) {
      float inv = 1.0f / lr[r];
      size_t base = (size_t)(b * SEQ + s0 + wq * 16 + l4 * 4 + r) * D_MODEL + h * 64;
#pragma unroll
      for (int n = 0; n < 4; ++n)
        attn[base + n * 16 + l15] = f2bf(o[n][r] * inv);
    }
  }
#undef STAGE_K
#undef LOAD_V
#undef WRITE_VT
}

// ---------- logits: out[b,v] = dot(normed[b,:], unembed[v,:]) ----------
__global__ __launch_bounds__(256) void logits_kernel(
    const float* __restrict__ normed, const float* __restrict__ unemb,
    float* __restrict__ out)
{
  __shared__ __align__(16) float ns[BATCH][D_MODEL];
  for (int d = threadIdx.x; d < BATCH * D_MODEL; d += 256)
    ((float*)ns)[d] = normed[d];
  __syncthreads();
  int g = threadIdx.x >> 4, li = threadIdx.x & 15;
  int v = blockIdx.x * 16 + g;
  const float* up = unemb + (size_t)v * D_MODEL;
  float s0 = 0.f, s1 = 0.f, s2 = 0.f, s3 = 0.f;
#pragma unroll
  for (int it = 0; it < D_MODEL / 64; ++it) {
    int e = it * 64 + li * 4;
    float4 u = *(const float4*)(up + e);
    float4 n0 = *(const float4*)&ns[0][e];
    float4 n1 = *(const float4*)&ns[1][e];
    float4 n2 = *(const float4*)&ns[2][e];
    float4 n3 = *(const float4*)&ns[3][e];
    s0 += u.x*n0.x + u.y*n0.y + u.z*n0.z + u.w*n0.w;
    s1 += u.x*n1.x + u.y*n1.y + u.z*n1.z + u.w*n1.w;
    s2 += u.x*n2.x + u.y*n2.y + u.z*n2.z + u.w*n2.w;
    s3 += u.x*n3.x + u.y*n3.y + u.z*n3.z + u.w*n3.w;
  }
#pragma unroll
  for (int msk = 1; msk < 16; msk <<= 1) {
    s0 += __shfl_xor(s0, msk, 64); s1 += __shfl_xor(s1, msk, 64);
    s2 += __shfl_xor(s2, msk, 64); s3 += __shfl_xor(s3, msk, 64);
  }
  if (li == 0) {
    out[(size_t)0 * VOCAB + v] = s0;
    out[(size_t)1 * VOCAB + v] = s1;
    out[(size_t)2 * VOCAB + v] = s2;
    out[(size_t)3 * VOCAB + v] = s3;
  }
}

// ---------- launcher ----------
extern "C" void kernel_launch(void* const* d_in, const int* in_sizes, int n_in,
                              void* d_out, int out_size, void* d_ws, size_t ws_size,
                              hipStream_t stream) {
  const int*   tokens = (const int*)d_in[0];
  const int*   pidx   = (const int*)d_in[1];
  const float* emb    = (const float*)d_in[2];
  const float* ln1_g  = (const float*)d_in[3];
  const float* ln1_b  = (const float*)d_in[4];
  const float* wq     = (const float*)d_in[5];
  const float* wk     = (const float*)d_in[6];
  const float* wv     = (const float*)d_in[7];
  const float* wo     = (const float*)d_in[8];
  const float* ln2_g  = (const float*)d_in[9];
  const float* ln2_b  = (const float*)d_in[10];
  const float* fc1    = (const float*)d_in[11];
  const float* fc2    = (const float*)d_in[12];
  const float* lnf_g  = (const float*)d_in[13];
  const float* lnf_b  = (const float*)d_in[14];
  const float* unemb  = (const float*)d_in[15];
  float* out = (float*)d_out;

  char* wp = (char*)d_ws;
  const size_t NX = (size_t)NROWS * D_MODEL;        // 3,145,728
  float* x = (float*)wp;                  wp += NX * 4;
  float* normed = (float*)wp;             wp += BATCH * D_MODEL * 4;
  __hip_bfloat16* h    = (__hip_bfloat16*)wp; wp += NX * 2;
  __hip_bfloat16* attn = (__hip_bfloat16*)wp; wp += NX * 2;
  __hip_bfloat16* qkvb = (__hip_bfloat16*)wp; wp += (size_t)NROWS * 2304 * 2;
  __hip_bfloat16* ffn  = (__hip_bfloat16*)wp; wp += (size_t)NROWS * D_FF * 2;
  __hip_bfloat16* wqkvb = (__hip_bfloat16*)wp; wp += (size_t)N_LAYERS * 2304 * D_MODEL * 2;
  __hip_bfloat16* wob   = (__hip_bfloat16*)wp; wp += (size_t)N_LAYERS * D_MODEL * D_MODEL * 2;
  __hip_bfloat16* fc1b  = (__hip_bfloat16*)wp; wp += (size_t)N_LAYERS * D_FF * D_MODEL * 2;
  __hip_bfloat16* fc2b  = (__hip_bfloat16*)wp; wp += (size_t)N_LAYERS * D_MODEL * D_FF * 2;

  // embT [VOCAB][D_MODEL] bf16 (49.2 MB) aliased onto attn..ffn scratch
  __hip_bfloat16* embT = attn;

  const int WMAT = D_MODEL * D_MODEL;     // 589824
  const int FMAT = D_FF * D_MODEL;        // 2359296

  transpose_emb_kernel<<<dim3(VOCAB / 64, D_MODEL / 64), 256, 0, stream>>>(emb, embT);
  embed_kernel<<<NROWS, 256, 0, stream>>>(tokens, embT, x);

  qkv_pack_kernel<<<N_LAYERS * 3 * WMAT / 2048, 256, 0, stream>>>(wq, wk, wv, wqkvb);
  convert_kernel<<<N_LAYERS * WMAT / 2048, 256, 0, stream>>>(wo,  wob,  N_LAYERS * WMAT);
  convert_kernel<<<N_LAYERS * FMAT / 2048, 256, 0, stream>>>(fc1, fc1b, N_LAYERS * FMAT);
  convert_kernel<<<N_LAYERS * FMAT / 2048, 256, 0, stream>>>(fc2, fc2b, N_LAYERS * FMAT);

  for (int l = 0; l < N_LAYERS; ++l) {
    const size_t qofs = (size_t)l * 3 * WMAT;
    const size_t wofs = (size_t)l * WMAT;
    const size_t fofs = (size_t)l * FMAT;

    ln_kernel<<<NROWS, 256, 0, stream>>>(x, h, ln1_g + l * D_MODEL, ln1_b + l * D_MODEL);

    // fused QKV: [4096 x 2304] bf16 out
    gemm_bf16_kernel<<<dim3(2304 / 128, NROWS / 128), 256, 0, stream>>>(
        h, wqkvb + qofs, qkvb, nullptr, 2304, D_MODEL, 2);

    flash_attn_kernel<<<dim3(16, N_HEADS, BATCH), 128, 0, stream>>>(qkvb, attn);

    // x += attn @ wo^T  (64-tile: 768 blocks)
    gemm64_bf16_kernel<<<dim3(D_MODEL / 64, NROWS / 64), 256, 0, stream>>>(
        attn, wob + wofs, x, x, D_MODEL, D_MODEL, 1);

    ln_kernel<<<NROWS, 256, 0, stream>>>(x, h, ln2_g + l * D_MODEL, ln2_b + l * D_MODEL);

    // ffn = gelu(h @ fc1^T) (bf16)
    gemm_bf16_kernel<<<dim3(D_FF / 128, NROWS / 128), 256, 0, stream>>>(
        h, fc1b + fofs, ffn, nullptr, D_FF, D_MODEL, 3);

    // x += ffn @ fc2^T  (64-tile: 768 blocks)
    gemm64_bf16_kernel<<<dim3(D_MODEL / 64, NROWS / 64), 256, 0, stream>>>(
        ffn, fc2b + fofs, x, x, D_MODEL, D_FF, 1);
  }

  final_ln_kernel<<<BATCH, 256, 0, stream>>>(x, pidx, lnf_g, lnf_b, normed);
  logits_kernel<<<VOCAB / 16, 256, 0, stream>>>(normed, unemb, out);
}